// Round 1
// baseline (2531.024 us; speedup 1.0000x reference)
//
#include <hip/hip_runtime.h>
#include <hip/hip_bf16.h>
#include <math.h>

// Problem constants
#define B_    2
#define FIN_  256
#define LIN_  250
#define F_    128      // F_OUT
#define K_    16       // KSIZE
#define ST_   8        // STRIDE
#define L_    2008     // L_OUT
#define DI_   256      // D_INNER
#define DS_   16       // D_STATE
#define RK_   8        // DT_RANK
#define CV_   4        // D_CONV
#define NBLK_ 2

__device__ __forceinline__ float silu_f(float x) {
    return x / (1.f + expf(-x));
}
__device__ __forceinline__ float softplus_f(float x) {
    return (x > 20.f) ? x : log1pf(expf(x));
}

// ---------------------------------------------------------------------------
// Kernel 1: conv_transpose1d (stride 8, K=16) + bias + silu
// x: (B, 256, 250)  w: (256, 128, 16)  -> h: (B, 128, 2008)
// h[b,o,t] = silu( b_o + sum_c sum_{i: k=t-8i in [0,16)} x[b,c,i]*w[c,o,k] )
// grid: B_*L_ blocks, 128 threads (o)
// ---------------------------------------------------------------------------
__global__ void convt_silu_k(const float* __restrict__ x,
                             const float* __restrict__ w,
                             const float* __restrict__ bias,
                             float* __restrict__ h) {
    int bt = blockIdx.x;
    int b = bt / L_, t = bt % L_;
    int o = threadIdx.x;

    __shared__ float xs[2][FIN_];

    int i_hi = t / ST_;            if (i_hi > LIN_ - 1) i_hi = LIN_ - 1;
    int i_lo = (t - (K_ - 1) + ST_ - 1) / ST_;  // ceil-ish; negatives clamp
    if (i_lo < 0) i_lo = 0;
    int ntap = i_hi - i_lo + 1;    // 1 or 2

    for (int idx = threadIdx.x; idx < ntap * FIN_; idx += blockDim.x) {
        int ii = idx / FIN_, c = idx % FIN_;
        xs[ii][c] = x[((size_t)b * FIN_ + c) * LIN_ + (i_lo + ii)];
    }
    __syncthreads();

    float acc = bias[o];
    for (int ii = 0; ii < ntap; ++ii) {
        int i = i_lo + ii;
        int k = t - ST_ * i;               // in [0,16)
        const float* wp = w + o * K_ + k;  // w[c*128*16 + o*16 + k]
        #pragma unroll 8
        for (int c = 0; c < FIN_; ++c)
            acc += xs[ii][c] * wp[(size_t)c * F_ * K_];
    }
    h[((size_t)b * F_ + o) * L_ + t] = silu_f(acc);
}

// ---------------------------------------------------------------------------
// Kernel 2: fuse = silu(fuse_w @ [skip; h] + fuse_b), write xs (fwd) and
// reversed copy (bwd). xs layout: [dir][b][l][f]
// grid: B_*L_ blocks, 128 threads (o)
// ---------------------------------------------------------------------------
__global__ void fuse_xs_k(const float* __restrict__ skip,
                          const float* __restrict__ h,
                          const float* __restrict__ fw,
                          const float* __restrict__ fb,
                          float* __restrict__ xs) {
    int bt = blockIdx.x;
    int b = bt / L_, l = bt % L_;
    __shared__ float s[2 * F_];
    for (int c = threadIdx.x; c < F_; c += blockDim.x) {
        s[c]       = skip[((size_t)b * F_ + c) * L_ + l];
        s[F_ + c]  = h   [((size_t)b * F_ + c) * L_ + l];
    }
    __syncthreads();
    int o = threadIdx.x;
    const float* wr = fw + (size_t)o * (2 * F_);
    float acc = fb[o];
    #pragma unroll 8
    for (int c = 0; c < 2 * F_; ++c) acc += s[c] * wr[c];
    float v = silu_f(acc);
    xs[((size_t)b * L_ + l) * F_ + o] = v;                                   // dir 0
    xs[((size_t)B_ * L_ + (size_t)b * L_ + (L_ - 1 - l)) * F_ + o] = v;      // dir 1 (flipped)
}

// ---------------------------------------------------------------------------
// Kernel 3: LayerNorm(resid) then in_proj GEMM row: xz[e] = sum_c u[c]*W[e,c]
// X: [dir][b*l][128]; W: in_proj_w[dir][blk][512][128]; XZ: [dir][row][512]
// grid: (B_*L_, 2), block 512
// ---------------------------------------------------------------------------
__global__ void ln_inproj_k(const float* __restrict__ X,
                            const float* __restrict__ nw,
                            const float* __restrict__ nb_,
                            const float* __restrict__ W,
                            float* __restrict__ XZ, int blk) {
    int d = blockIdx.y;
    size_t row = blockIdx.x;
    size_t ri = (size_t)d * B_ * L_ + row;
    int tid = threadIdx.x;

    __shared__ float us[F_];
    __shared__ float red[F_];

    float v = (tid < F_) ? X[ri * F_ + tid] : 0.f;
    if (tid < F_) red[tid] = v;
    __syncthreads();
    for (int s = 64; s > 0; s >>= 1) {
        if (tid < s) red[tid] += red[tid + s];
        __syncthreads();
    }
    float mu = red[0] * (1.f / F_);
    __syncthreads();
    if (tid < F_) { float dv = v - mu; red[tid] = dv * dv; }
    __syncthreads();
    for (int s = 64; s > 0; s >>= 1) {
        if (tid < s) red[tid] += red[tid + s];
        __syncthreads();
    }
    float rstd = rsqrtf(red[0] * (1.f / F_) + 1e-5f);
    __syncthreads();
    if (tid < F_) {
        int wi = (d * NBLK_ + blk) * F_ + tid;
        us[tid] = (v - mu) * rstd * nw[wi] + nb_[wi];
    }
    __syncthreads();

    int e = tid;  // 0..511
    const float* wr = W + ((size_t)(d * NBLK_ + blk) * (2 * DI_) + e) * F_;
    float acc = 0.f;
    #pragma unroll 8
    for (int c = 0; c < F_; ++c) acc += us[c] * wr[c];
    XZ[ri * (2 * DI_) + e] = acc;
}

// ---------------------------------------------------------------------------
// Kernel 4: depthwise causal conv (width 4) + bias + silu
// XZ first half is xc_pre. XC: [dir][row][256]
// grid: (B_*L_, 2), block 256 (ch)
// ---------------------------------------------------------------------------
__global__ void dwconv_k(const float* __restrict__ XZ,
                         const float* __restrict__ cw,
                         const float* __restrict__ cb,
                         float* __restrict__ XC, int blk) {
    int d = blockIdx.y;
    int row = blockIdx.x;
    int b = row / L_, l = row % L_;
    int ch = threadIdx.x;
    const float* base = XZ + ((size_t)d * B_ * L_ + (size_t)b * L_) * (2 * DI_);
    int wi = (d * NBLK_ + blk) * DI_ + ch;
    const float* w = cw + (size_t)wi * CV_;
    float acc = cb[wi];
    #pragma unroll
    for (int k = 0; k < CV_; ++k) {
        int ll = l - (CV_ - 1) + k;
        if (ll >= 0) acc += base[(size_t)ll * (2 * DI_) + ch] * w[k];
    }
    XC[((size_t)d * B_ * L_ + row) * DI_ + ch] = silu_f(acc);
}

// ---------------------------------------------------------------------------
// Kernel 5: x_proj (40 outs) + dt_proj (256) + softplus
// BCM: [dir][row][32] (B then C); DELTA: [dir][row][256]
// grid: (B_*L_, 2), block 256
// ---------------------------------------------------------------------------
__global__ void xdt_k(const float* __restrict__ XC,
                      const float* __restrict__ xpw,
                      const float* __restrict__ dtw,
                      const float* __restrict__ dtb,
                      float* __restrict__ BCM,
                      float* __restrict__ DELTA, int blk) {
    int d = blockIdx.y;
    size_t row = blockIdx.x;
    size_t ri = (size_t)d * B_ * L_ + row;
    int tid = threadIdx.x;

    __shared__ float xr[DI_];
    __shared__ float dt[RK_];

    xr[tid] = XC[ri * DI_ + tid];
    __syncthreads();

    if (tid < RK_ + 2 * DS_) {  // 40
        const float* wp = xpw + ((size_t)(d * NBLK_ + blk) * (RK_ + 2 * DS_) + tid) * DI_;
        float acc = 0.f;
        #pragma unroll 8
        for (int c = 0; c < DI_; ++c) acc += xr[c] * wp[c];
        if (tid < RK_) dt[tid] = acc;
        else BCM[ri * 32 + (tid - RK_)] = acc;
    }
    __syncthreads();

    int ch = tid;
    int wi = (d * NBLK_ + blk) * DI_ + ch;
    const float* dw = dtw + (size_t)wi * RK_;
    float acc = dtb[wi];
    #pragma unroll
    for (int r = 0; r < RK_; ++r) acc += dt[r] * dw[r];
    DELTA[ri * DI_ + ch] = softplus_f(acc);
}

// ---------------------------------------------------------------------------
// Kernel 6: selective scan. Lane layout: 16 lanes per channel (n = tid&15),
// 4 channels per wave, 16 channels per 256-thread block.
// grid: (32, 2), block 256
// ---------------------------------------------------------------------------
__global__ void scan_k(const float* __restrict__ DELTA,
                       const float* __restrict__ XC,
                       const float* __restrict__ BCM,
                       const float* __restrict__ A_log,
                       float* __restrict__ Y, int blk) {
    int d = blockIdx.y;
    int g = blockIdx.x * 16 + (threadIdx.x >> 4);  // global channel 0..511
    int n = threadIdx.x & 15;
    int b = g / DI_, ch = g % DI_;

    float A = -expf(A_log[((size_t)(d * NBLK_ + blk) * DI_ + ch) * DS_ + n]);

    const float* dbase = DELTA + ((size_t)d * B_ + b) * L_ * DI_ + ch;
    const float* ubase = XC    + ((size_t)d * B_ + b) * L_ * DI_ + ch;
    const float* bcb   = BCM   + ((size_t)d * B_ + b) * L_ * 32 + n;
    float* ybase       = Y     + ((size_t)d * B_ + b) * L_ * DI_ + ch;

    float h = 0.f;
    float dt = dbase[0], u = ubase[0], Bt = bcb[0], Ct = bcb[16];
    for (int t = 0; t < L_; ++t) {
        float dt_n = 0.f, u_n = 0.f, Bt_n = 0.f, Ct_n = 0.f;
        if (t + 1 < L_) {  // prefetch next step
            dt_n = dbase[(size_t)(t + 1) * DI_];
            u_n  = ubase[(size_t)(t + 1) * DI_];
            Bt_n = bcb[(size_t)(t + 1) * 32];
            Ct_n = bcb[(size_t)(t + 1) * 32 + 16];
        }
        h = expf(dt * A) * h + dt * u * Bt;
        float yp = h * Ct;
        yp += __shfl_xor(yp, 1);
        yp += __shfl_xor(yp, 2);
        yp += __shfl_xor(yp, 4);
        yp += __shfl_xor(yp, 8);
        if (n == 0) ybase[(size_t)t * DI_] = yp;
        dt = dt_n; u = u_n; Bt = Bt_n; Ct = Ct_n;
    }
}

// ---------------------------------------------------------------------------
// Kernel 7: gate (y + xc*D)*silu(z), then out_proj GEMM + optional residual
// grid: (B_*L_, 2), block 256; outputs cur[dir][row][128]
// ---------------------------------------------------------------------------
__global__ void gate_outproj_k(const float* __restrict__ Y,
                               const float* __restrict__ XC,
                               const float* __restrict__ XZ,
                               const float* __restrict__ Dsk,
                               const float* __restrict__ Wout,
                               const float* __restrict__ resid_in,
                               float* __restrict__ cur,
                               float* __restrict__ resid_out, int blk) {
    int d = blockIdx.y;
    size_t row = blockIdx.x;
    size_t ri = (size_t)d * B_ * L_ + row;
    int ch = threadIdx.x;

    __shared__ float yg[DI_];
    float z = XZ[ri * (2 * DI_) + DI_ + ch];
    float v = (Y[ri * DI_ + ch] + XC[ri * DI_ + ch] * Dsk[(d * NBLK_ + blk) * DI_ + ch]) * silu_f(z);
    yg[ch] = v;
    __syncthreads();

    if (ch < F_) {
        const float* w = Wout + ((size_t)(d * NBLK_ + blk) * F_ + ch) * DI_;
        float acc = 0.f;
        #pragma unroll 8
        for (int c = 0; c < DI_; ++c) acc += yg[c] * w[c];
        cur[ri * F_ + ch] = acc;
        if (resid_out) resid_out[ri * F_ + ch] = resid_in[ri * F_ + ch] + acc;
    }
}

// ---------------------------------------------------------------------------
// Kernel 8: combine: out[b,o,l] = (cur+resid)[d0,b,l,o] + (cur+resid)[d1,b,L-1-l,o]
// grid: B_*L_, block 128
// ---------------------------------------------------------------------------
__global__ void combine_k(const float* __restrict__ cur,
                          const float* __restrict__ resid,
                          float* __restrict__ out) {
    int bt = blockIdx.x;
    int b = bt / L_, l = bt % L_;
    int o = threadIdx.x;
    size_t rf = ((size_t)b * L_ + l) * F_ + o;
    size_t rb = ((size_t)B_ * L_ + (size_t)b * L_ + (L_ - 1 - l)) * F_ + o;
    out[((size_t)b * F_ + o) * L_ + l] = cur[rf] + resid[rf] + cur[rb] + resid[rb];
}

// ---------------------------------------------------------------------------
extern "C" void kernel_launch(void* const* d_in, const int* in_sizes, int n_in,
                              void* d_out, int out_size, void* d_ws, size_t ws_size,
                              hipStream_t stream) {
    const float* x        = (const float*)d_in[0];
    const float* skip     = (const float*)d_in[1];
    const float* convT_w  = (const float*)d_in[4];
    const float* convT_b  = (const float*)d_in[5];
    const float* fuse_w   = (const float*)d_in[6];
    const float* fuse_b   = (const float*)d_in[7];
    const float* norm_w   = (const float*)d_in[8];
    const float* norm_b   = (const float*)d_in[9];
    const float* in_proj  = (const float*)d_in[10];
    const float* conv_w   = (const float*)d_in[11];
    const float* conv_b   = (const float*)d_in[12];
    const float* x_proj   = (const float*)d_in[13];
    const float* dt_projw = (const float*)d_in[14];
    const float* dt_projb = (const float*)d_in[15];
    const float* A_log    = (const float*)d_in[16];
    const float* D_skip   = (const float*)d_in[17];
    const float* out_proj = (const float*)d_in[18];
    float* out = (float*)d_out;

    // workspace carve-up (floats)
    float* w = (float*)d_ws;
    size_t off = 0;
    auto alloc = [&](size_t n) { float* p = w + off; off += n; return p; };
    const size_t RL = (size_t)B_ * L_;      // rows per dir
    float* h    = alloc((size_t)B_ * F_ * L_);
    float* xs   = alloc(2 * RL * F_);
    float* cur  = alloc(2 * RL * F_);
    float* res1 = alloc(2 * RL * F_);
    float* xz   = alloc(2 * RL * (2 * DI_));
    float* xc   = alloc(2 * RL * DI_);
    float* dl   = alloc(2 * RL * DI_);
    float* bcm  = alloc(2 * RL * 32);
    float* yb   = alloc(2 * RL * DI_);
    (void)ws_size; (void)in_sizes; (void)n_in; (void)out_size;

    dim3 rows2(B_ * L_, 2);

    // Phase A
    convt_silu_k<<<B_ * L_, 128, 0, stream>>>(x, convT_w, convT_b, h);
    fuse_xs_k<<<B_ * L_, 128, 0, stream>>>(skip, h, fuse_w, fuse_b, xs);

    // Block 0 (resid = xs)
    ln_inproj_k<<<rows2, 512, 0, stream>>>(xs, norm_w, norm_b, in_proj, xz, 0);
    dwconv_k<<<rows2, 256, 0, stream>>>(xz, conv_w, conv_b, xc, 0);
    xdt_k<<<rows2, 256, 0, stream>>>(xc, x_proj, dt_projw, dt_projb, bcm, dl, 0);
    scan_k<<<dim3(32, 2), 256, 0, stream>>>(dl, xc, bcm, A_log, yb, 0);
    gate_outproj_k<<<rows2, 256, 0, stream>>>(yb, xc, xz, D_skip, out_proj,
                                              xs, cur, res1, 0);  // res1 = xs + cur

    // Block 1 (resid = res1)
    ln_inproj_k<<<rows2, 512, 0, stream>>>(res1, norm_w, norm_b, in_proj, xz, 1);
    dwconv_k<<<rows2, 256, 0, stream>>>(xz, conv_w, conv_b, xc, 1);
    xdt_k<<<rows2, 256, 0, stream>>>(xc, x_proj, dt_projw, dt_projb, bcm, dl, 1);
    scan_k<<<dim3(32, 2), 256, 0, stream>>>(dl, xc, bcm, A_log, yb, 1);
    gate_outproj_k<<<rows2, 256, 0, stream>>>(yb, xc, xz, D_skip, out_proj,
                                              nullptr, cur, nullptr, 1);

    // out = (cur + res1)[fwd] + flipped (cur + res1)[bwd]
    combine_k<<<B_ * L_, 128, 0, stream>>>(cur, res1, out);
}

// Round 2
// 868.502 us; speedup vs baseline: 2.9142x; 2.9142x over previous
//
#include <hip/hip_runtime.h>
#include <hip/hip_bf16.h>
#include <math.h>

// Problem constants
#define B_    2
#define FIN_  256
#define LIN_  250
#define F_    128      // F_OUT
#define K_    16       // KSIZE
#define ST_   8        // STRIDE
#define L_    2008     // L_OUT
#define DI_   256      // D_INNER
#define DS_   16       // D_STATE
#define RK_   8        // DT_RANK
#define CV_   4        // D_CONV
#define NBLK_ 2
#define NC_   16       // scan chunks
#define CL_   126      // chunk length (16*126 = 2016 >= 2008)
#define RL_   ((size_t)B_ * L_)   // rows per direction = 4016

__device__ __forceinline__ float silu_f(float x) {
    return x / (1.f + expf(-x));
}
__device__ __forceinline__ float softplus_f(float x) {
    return (x > 20.f) ? x : log1pf(expf(x));
}

// ---------------------------------------------------------------------------
// Weight transpose: wT[k][c][o] = convT_w[c][o][k]   (one shot, 2 MB)
// grid: 256 (c), block 256
// ---------------------------------------------------------------------------
__global__ void wt_k(const float* __restrict__ w, float* __restrict__ wT) {
    int c = blockIdx.x;
    for (int t = threadIdx.x; t < F_ * K_; t += blockDim.x) {
        int o = t >> 4, k = t & 15;
        wT[((size_t)k * FIN_ + c) * F_ + o] = w[(size_t)c * F_ * K_ + t];
    }
}

// ---------------------------------------------------------------------------
// convT+silu, phase-decomposed GEMM. t = 8j+p: taps k=p (x[j]), k=p+8 (x[j-1]).
// grid: (8 phases, B, 4 j-tiles of 64), block 256 (o=tid&127, jh=tid>>7)
// ---------------------------------------------------------------------------
#define CCT_ 32
__global__ void convt2_k(const float* __restrict__ x, const float* __restrict__ wT,
                         const float* __restrict__ bias, float* __restrict__ hout) {
    int p = blockIdx.x, b = blockIdx.y;
    int j0 = blockIdx.z * 64;
    int o = threadIdx.x & 127, jh = threadIdx.x >> 7;

    __shared__ float xsh[CCT_][66];     // [ci][jl], jl=0 <-> j0-1
    __shared__ float w1s[CCT_][128];
    __shared__ float w2s[CCT_][128];

    float acc[32];
    #pragma unroll
    for (int i = 0; i < 32; ++i) acc[i] = 0.f;

    for (int c0 = 0; c0 < FIN_; c0 += CCT_) {
        for (int idx = threadIdx.x; idx < CCT_ * 65; idx += 256) {
            int ci = idx / 65, jl = idx % 65;
            int i = j0 - 1 + jl;
            xsh[ci][jl] = (i >= 0 && i < LIN_) ? x[((size_t)b * FIN_ + c0 + ci) * LIN_ + i] : 0.f;
        }
        for (int idx = threadIdx.x; idx < CCT_ * 128; idx += 256) {
            int ci = idx >> 7, oo = idx & 127;
            w1s[ci][oo] = wT[((size_t)p       * FIN_ + c0 + ci) * F_ + oo];   // k=p
            w2s[ci][oo] = wT[((size_t)(p + 8) * FIN_ + c0 + ci) * F_ + oo];   // k=p+8
        }
        __syncthreads();
        #pragma unroll 4
        for (int ci = 0; ci < CCT_; ++ci) {
            float w1 = w1s[ci][o], w2 = w2s[ci][o];
            #pragma unroll
            for (int jj = 0; jj < 32; ++jj) {
                int jl = jh * 32 + jj;
                acc[jj] += xsh[ci][jl + 1] * w1 + xsh[ci][jl] * w2;
            }
        }
        __syncthreads();
    }
    float bo = bias[o];
    for (int jj = 0; jj < 32; ++jj) {
        int j = j0 + jh * 32 + jj;
        if (j <= 250) {
            int t = 8 * j + p;
            hout[((size_t)b * F_ + o) * L_ + t] = silu_f(acc[jj] + bo);
        }
    }
}

// ---------------------------------------------------------------------------
// fuse = silu(fuse_w @ [skip; h] + b); write xs fwd + flipped bwd.
// grid: (32 l-tiles of 64, B), block 256 (o=tid&127, lh=tid>>7)
// ---------------------------------------------------------------------------
__global__ void fuse2_k(const float* __restrict__ skip, const float* __restrict__ h,
                        const float* __restrict__ fw, const float* __restrict__ fb,
                        float* __restrict__ xs) {
    int l0 = blockIdx.x * 64, b = blockIdx.y;
    int o = threadIdx.x & 127, lh = threadIdx.x >> 7;

    __shared__ float ss[64][64];    // [ci][ll]
    __shared__ float ws[64][130];   // [ci][o]

    float acc[32];
    #pragma unroll
    for (int i = 0; i < 32; ++i) acc[i] = 0.f;

    for (int c0 = 0; c0 < 2 * F_; c0 += 64) {
        for (int idx = threadIdx.x; idx < 64 * 64; idx += 256) {
            int ci = idx >> 6, ll = idx & 63;
            int c = c0 + ci, l = l0 + ll;
            const float* src = (c < F_) ? (skip + ((size_t)b * F_ + c) * L_)
                                        : (h    + ((size_t)b * F_ + (c - F_)) * L_);
            ss[ci][ll] = (l < L_) ? src[l] : 0.f;
        }
        for (int idx = threadIdx.x; idx < 64 * 128; idx += 256) {
            int oo = idx >> 6, ci = idx & 63;
            ws[ci][oo] = fw[(size_t)oo * (2 * F_) + c0 + ci];
        }
        __syncthreads();
        for (int ci = 0; ci < 64; ++ci) {
            float wv = ws[ci][o];
            #pragma unroll
            for (int jj = 0; jj < 32; ++jj)
                acc[jj] += ss[ci][lh * 32 + jj] * wv;
        }
        __syncthreads();
    }
    float bo = fb[o];
    for (int jj = 0; jj < 32; ++jj) {
        int l = l0 + lh * 32 + jj;
        if (l < L_) {
            float v = silu_f(acc[jj] + bo);
            xs[((size_t)b * L_ + l) * F_ + o] = v;
            xs[(RL_ + (size_t)b * L_ + (L_ - 1 - l)) * F_ + o] = v;
        }
    }
}

// ---------------------------------------------------------------------------
// LayerNorm + in_proj GEMM (rows-tile 32, n-tile 128)
// grid: (126, 4, 2), block 256
// ---------------------------------------------------------------------------
__global__ void ln_inproj2_k(const float* __restrict__ X, const float* __restrict__ nw,
                             const float* __restrict__ nb_, const float* __restrict__ W,
                             float* __restrict__ XZ, int blk) {
    int rt = blockIdx.x;
    int n0 = blockIdx.y * 128;
    int d  = blockIdx.z;
    size_t rbase = (size_t)rt * 32;
    int tid = threadIdx.x;
    int lane = tid & 63, wid = tid >> 6;

    __shared__ float us[32][128];
    __shared__ float ws[64][130];

    int wi0 = (d * NBLK_ + blk) * F_;
    for (int rr = 0; rr < 8; ++rr) {
        int r = wid * 8 + rr;
        size_t row = rbase + r;
        float2 v = make_float2(0.f, 0.f);
        if (row < RL_)
            v = *(const float2*)(X + ((size_t)d * RL_ + row) * F_ + lane * 2);
        float s1 = v.x + v.y, s2 = v.x * v.x + v.y * v.y;
        for (int off = 32; off; off >>= 1) {
            s1 += __shfl_xor(s1, off);
            s2 += __shfl_xor(s2, off);
        }
        float mu = s1 * (1.f / F_);
        float var = s2 * (1.f / F_) - mu * mu;
        float rstd = rsqrtf(var + 1e-5f);
        int c = lane * 2;
        us[r][c]     = (v.x - mu) * rstd * nw[wi0 + c]     + nb_[wi0 + c];
        us[r][c + 1] = (v.y - mu) * rstd * nw[wi0 + c + 1] + nb_[wi0 + c + 1];
    }
    __syncthreads();

    int o = tid & 127, rh = tid >> 7;
    float acc[16];
    #pragma unroll
    for (int i = 0; i < 16; ++i) acc[i] = 0.f;
    const float* Wp = W + ((size_t)(d * NBLK_ + blk) * (2 * DI_) + n0) * F_;

    for (int c0 = 0; c0 < F_; c0 += 64) {
        for (int idx = tid; idx < 64 * 128; idx += 256) {
            int oo = idx >> 6, ci = idx & 63;
            ws[ci][oo] = Wp[(size_t)oo * F_ + c0 + ci];
        }
        __syncthreads();
        for (int ci = 0; ci < 64; ++ci) {
            float wv = ws[ci][o];
            int c = c0 + ci;
            #pragma unroll
            for (int rr2 = 0; rr2 < 16; ++rr2)
                acc[rr2] += us[rh * 16 + rr2][c] * wv;
        }
        __syncthreads();
    }
    for (int rr2 = 0; rr2 < 16; ++rr2) {
        size_t row = rbase + rh * 16 + rr2;
        if (row < RL_)
            XZ[((size_t)d * RL_ + row) * (2 * DI_) + n0 + o] = acc[rr2];
    }
}

// ---------------------------------------------------------------------------
// depthwise causal conv(4) + silu; 4 rows per block
// grid: (1004, 2), block 256
// ---------------------------------------------------------------------------
__global__ void dwconv2_k(const float* __restrict__ XZ, const float* __restrict__ cw,
                          const float* __restrict__ cb, float* __restrict__ XC, int blk) {
    int d = blockIdx.y;
    int ch = threadIdx.x;
    int wi = (d * NBLK_ + blk) * DI_ + ch;
    float w0 = cw[(size_t)wi * CV_ + 0], w1 = cw[(size_t)wi * CV_ + 1];
    float w2 = cw[(size_t)wi * CV_ + 2], w3 = cw[(size_t)wi * CV_ + 3];
    float bias = cb[wi];
    for (int r4 = 0; r4 < 4; ++r4) {
        int row = blockIdx.x * 4 + r4;
        int b = row / L_, l = row % L_;
        const float* base = XZ + ((size_t)d * RL_ + (size_t)b * L_) * (2 * DI_);
        float acc = bias;
        if (l - 3 >= 0) acc += base[(size_t)(l - 3) * (2 * DI_) + ch] * w0;
        if (l - 2 >= 0) acc += base[(size_t)(l - 2) * (2 * DI_) + ch] * w1;
        if (l - 1 >= 0) acc += base[(size_t)(l - 1) * (2 * DI_) + ch] * w2;
        acc += base[(size_t)l * (2 * DI_) + ch] * w3;
        XC[((size_t)d * RL_ + row) * DI_ + ch] = silu_f(acc);
    }
}

// ---------------------------------------------------------------------------
// x_proj (40) + dt_proj (256) + softplus; rows-tile 32
// grid: (126, 2), block 256
// ---------------------------------------------------------------------------
__global__ void xdt2_k(const float* __restrict__ XC, const float* __restrict__ xpw,
                       const float* __restrict__ dtw, const float* __restrict__ dtb,
                       float* __restrict__ BCM, float* __restrict__ DELTA, int blk) {
    int rt = blockIdx.x, d = blockIdx.y;
    int tid = threadIdx.x;
    size_t rbase = (size_t)rt * 32;

    __shared__ float xr[32][258];
    __shared__ float dts[32][8];

    for (int idx = tid; idx < 32 * 256; idx += 256) {
        int r = idx >> 8, c = idx & 255;
        size_t row = rbase + r;
        xr[r][c] = (row < RL_) ? XC[((size_t)d * RL_ + row) * DI_ + c] : 0.f;
    }
    __syncthreads();

    int r = tid & 31, eg = tid >> 5;
    const float* wb = xpw + (size_t)(d * NBLK_ + blk) * (RK_ + 2 * DS_) * DI_;
    for (int ee = 0; ee < 5; ++ee) {
        int e = eg * 5 + ee;
        const float* wp = wb + (size_t)e * DI_;
        float acc = 0.f;
        #pragma unroll 8
        for (int c = 0; c < DI_; ++c) acc += xr[r][c] * wp[c];
        size_t row = rbase + r;
        if (e < RK_) dts[r][e] = acc;
        else if (row < RL_) BCM[((size_t)d * RL_ + row) * 32 + (e - RK_)] = acc;
    }
    __syncthreads();

    int ch = tid;
    int wi = (d * NBLK_ + blk) * DI_ + ch;
    float dwv[RK_];
    #pragma unroll
    for (int k = 0; k < RK_; ++k) dwv[k] = dtw[(size_t)wi * RK_ + k];
    float bias = dtb[wi];
    for (int rr = 0; rr < 32; ++rr) {
        size_t row = rbase + rr;
        if (row >= RL_) break;
        float acc = bias;
        #pragma unroll
        for (int k = 0; k < RK_; ++k) acc += dts[rr][k] * dwv[k];
        DELTA[((size_t)d * RL_ + row) * DI_ + ch] = softplus_f(acc);
    }
}

// ---------------------------------------------------------------------------
// scan pass A: chunk-local scan h0=0 -> hpart, dtsum
// grid: (32, NC_, 2), block 256 (16 ch x 16 n)
// ---------------------------------------------------------------------------
__global__ void scanA_k(const float* __restrict__ DELTA, const float* __restrict__ XC,
                        const float* __restrict__ BCM, const float* __restrict__ A_log,
                        float* __restrict__ hpart, float* __restrict__ dsum, int blk) {
    int d = blockIdx.z, cnk = blockIdx.y;
    int g = blockIdx.x * 16 + (threadIdx.x >> 4);
    int n = threadIdx.x & 15;
    int b = g >> 8, ch = g & 255;
    int t0 = cnk * CL_;
    int t1 = t0 + CL_; if (t1 > L_) t1 = L_;

    float A = -expf(A_log[((size_t)(d * NBLK_ + blk) * DI_ + ch) * DS_ + n]);
    const float* db = DELTA + ((size_t)d * B_ + b) * L_ * DI_ + ch;
    const float* ub = XC    + ((size_t)d * B_ + b) * L_ * DI_ + ch;
    const float* bb = BCM   + ((size_t)d * B_ + b) * L_ * 32 + n;

    float h = 0.f, ds = 0.f;
    float dt = db[(size_t)t0 * DI_], u = ub[(size_t)t0 * DI_], Bt = bb[(size_t)t0 * 32];
    for (int t = t0; t < t1; ++t) {
        float dtn = 0.f, un = 0.f, Btn = 0.f;
        if (t + 1 < t1) {
            dtn = db[(size_t)(t + 1) * DI_];
            un  = ub[(size_t)(t + 1) * DI_];
            Btn = bb[(size_t)(t + 1) * 32];
        }
        h = expf(dt * A) * h + dt * u * Bt;
        ds += dt;
        dt = dtn; u = un; Bt = Btn;
    }
    size_t cb = (size_t)(d * B_ + b) * NC_ + cnk;
    hpart[cb * (DI_ * DS_) + ch * DS_ + n] = h;
    if (n == 0) dsum[cb * DI_ + ch] = ds;
}

// ---------------------------------------------------------------------------
// scan pass B: cross-chunk scan -> hin per chunk
// grid: (32, 2), block 256
// ---------------------------------------------------------------------------
__global__ void scanB_k(const float* __restrict__ hpart, const float* __restrict__ dsum,
                        const float* __restrict__ A_log, float* __restrict__ hin, int blk) {
    int d = blockIdx.y;
    int idx = blockIdx.x * 256 + threadIdx.x;   // (b, ch, n)
    int b = idx >> 12, ch = (idx >> 4) & 255, n = idx & 15;
    float A = -expf(A_log[((size_t)(d * NBLK_ + blk) * DI_ + ch) * DS_ + n]);
    float h = 0.f;
    for (int c = 0; c < NC_; ++c) {
        size_t cb = (size_t)(d * B_ + b) * NC_ + c;
        hin[cb * (DI_ * DS_) + ch * DS_ + n] = h;
        h = expf(A * dsum[cb * DI_ + ch]) * h + hpart[cb * (DI_ * DS_) + ch * DS_ + n];
    }
}

// ---------------------------------------------------------------------------
// scan pass C: re-scan with hin, emit y
// grid: (32, NC_, 2), block 256
// ---------------------------------------------------------------------------
__global__ void scanC_k(const float* __restrict__ DELTA, const float* __restrict__ XC,
                        const float* __restrict__ BCM, const float* __restrict__ A_log,
                        const float* __restrict__ hin, float* __restrict__ Y, int blk) {
    int d = blockIdx.z, cnk = blockIdx.y;
    int g = blockIdx.x * 16 + (threadIdx.x >> 4);
    int n = threadIdx.x & 15;
    int b = g >> 8, ch = g & 255;
    int t0 = cnk * CL_;
    int t1 = t0 + CL_; if (t1 > L_) t1 = L_;

    float A = -expf(A_log[((size_t)(d * NBLK_ + blk) * DI_ + ch) * DS_ + n]);
    const float* db = DELTA + ((size_t)d * B_ + b) * L_ * DI_ + ch;
    const float* ub = XC    + ((size_t)d * B_ + b) * L_ * DI_ + ch;
    const float* bb = BCM   + ((size_t)d * B_ + b) * L_ * 32 + n;
    float* yb       = Y     + ((size_t)d * B_ + b) * L_ * DI_ + ch;

    size_t cb = (size_t)(d * B_ + b) * NC_ + cnk;
    float h = hin[cb * (DI_ * DS_) + ch * DS_ + n];

    float dt = db[(size_t)t0 * DI_], u = ub[(size_t)t0 * DI_];
    float Bt = bb[(size_t)t0 * 32], Ct = bb[(size_t)t0 * 32 + 16];
    for (int t = t0; t < t1; ++t) {
        float dtn = 0.f, un = 0.f, Btn = 0.f, Ctn = 0.f;
        if (t + 1 < t1) {
            dtn = db[(size_t)(t + 1) * DI_];
            un  = ub[(size_t)(t + 1) * DI_];
            Btn = bb[(size_t)(t + 1) * 32];
            Ctn = bb[(size_t)(t + 1) * 32 + 16];
        }
        h = expf(dt * A) * h + dt * u * Bt;
        float yp = h * Ct;
        yp += __shfl_xor(yp, 1);
        yp += __shfl_xor(yp, 2);
        yp += __shfl_xor(yp, 4);
        yp += __shfl_xor(yp, 8);
        if (n == 0) yb[(size_t)t * DI_] = yp;
        dt = dtn; u = un; Bt = Btn; Ct = Ctn;
    }
}

// ---------------------------------------------------------------------------
// gate + out_proj GEMM (+ optional residual-in); rows-tile 32
// grid: (126, 2), block 256
// ---------------------------------------------------------------------------
__global__ void gate2_k(const float* __restrict__ Y, const float* __restrict__ XC,
                        const float* __restrict__ XZ, const float* __restrict__ Dsk,
                        const float* __restrict__ Wout, const float* __restrict__ resid_in,
                        float* __restrict__ outp, int blk) {
    int rt = blockIdx.x, d = blockIdx.y;
    int tid = threadIdx.x;
    size_t rbase = (size_t)rt * 32;

    __shared__ float yg[32][256];
    __shared__ float ws[32][130];

    const float* Dp = Dsk + (size_t)(d * NBLK_ + blk) * DI_;
    for (int idx = tid; idx < 32 * 256; idx += 256) {
        int r = idx >> 8, c = idx & 255;
        size_t row = rbase + r;
        float v = 0.f;
        if (row < RL_) {
            size_t ri = (size_t)d * RL_ + row;
            float z = XZ[ri * (2 * DI_) + DI_ + c];
            v = (Y[ri * DI_ + c] + XC[ri * DI_ + c] * Dp[c]) * silu_f(z);
        }
        yg[r][c] = v;
    }

    int o = tid & 127, rh = tid >> 7;
    float acc[16];
    #pragma unroll
    for (int i = 0; i < 16; ++i) acc[i] = 0.f;
    const float* Wp = Wout + (size_t)(d * NBLK_ + blk) * F_ * DI_;

    for (int c0 = 0; c0 < DI_; c0 += 32) {
        for (int idx = tid; idx < 32 * 128; idx += 256) {
            int oo = idx >> 5, ci = idx & 31;
            ws[ci][oo] = Wp[(size_t)oo * DI_ + c0 + ci];
        }
        __syncthreads();
        for (int ci = 0; ci < 32; ++ci) {
            float wv = ws[ci][o];
            int c = c0 + ci;
            #pragma unroll
            for (int rr = 0; rr < 16; ++rr)
                acc[rr] += yg[rh * 16 + rr][c] * wv;
        }
        __syncthreads();
    }
    for (int rr = 0; rr < 16; ++rr) {
        size_t row = rbase + rh * 16 + rr;
        if (row < RL_) {
            size_t ri = (size_t)d * RL_ + row;
            float v = acc[rr];
            if (resid_in) v += resid_in[ri * F_ + o];
            outp[ri * F_ + o] = v;
        }
    }
}

// ---------------------------------------------------------------------------
// combine with LDS transpose for coalesced (b,o,l) writes
// grid: (32 l-tiles, B), block 256
// ---------------------------------------------------------------------------
__global__ void combine2_k(const float* __restrict__ cur, const float* __restrict__ res1,
                           float* __restrict__ out) {
    int l0 = blockIdx.x * 64, b = blockIdx.y;
    int tid = threadIdx.x;
    __shared__ float s[64][129];
    for (int idx = tid; idx < 64 * 128; idx += 256) {
        int ll = idx >> 7, o = idx & 127;
        int l = l0 + ll;
        if (l < L_) {
            size_t rf = ((size_t)b * L_ + l) * F_ + o;
            size_t rb = (RL_ + (size_t)b * L_ + (L_ - 1 - l)) * F_ + o;
            s[ll][o] = cur[rf] + res1[rf] + cur[rb] + res1[rb];
        }
    }
    __syncthreads();
    for (int idx = tid; idx < 64 * 128; idx += 256) {
        int o = idx >> 6, ll = idx & 63;
        int l = l0 + ll;
        if (l < L_) out[((size_t)b * F_ + o) * L_ + l] = s[ll][o];
    }
}

// ---------------------------------------------------------------------------
extern "C" void kernel_launch(void* const* d_in, const int* in_sizes, int n_in,
                              void* d_out, int out_size, void* d_ws, size_t ws_size,
                              hipStream_t stream) {
    const float* x        = (const float*)d_in[0];
    const float* skip     = (const float*)d_in[1];
    const float* convT_w  = (const float*)d_in[4];
    const float* convT_b  = (const float*)d_in[5];
    const float* fuse_w   = (const float*)d_in[6];
    const float* fuse_b   = (const float*)d_in[7];
    const float* norm_w   = (const float*)d_in[8];
    const float* norm_b   = (const float*)d_in[9];
    const float* in_proj  = (const float*)d_in[10];
    const float* conv_w   = (const float*)d_in[11];
    const float* conv_b   = (const float*)d_in[12];
    const float* x_proj   = (const float*)d_in[13];
    const float* dt_projw = (const float*)d_in[14];
    const float* dt_projb = (const float*)d_in[15];
    const float* A_log    = (const float*)d_in[16];
    const float* D_skip   = (const float*)d_in[17];
    const float* out_proj = (const float*)d_in[18];
    float* out = (float*)d_out;

    float* w = (float*)d_ws;
    size_t off = 0;
    auto alloc = [&](size_t n) { float* p = w + off; off += n; return p; };
    float* h    = alloc((size_t)B_ * F_ * L_);        // 514048
    float* wT   = alloc((size_t)K_ * FIN_ * F_);      // 524288 (dead after convt2)
    float* xs   = alloc(2 * RL_ * F_);
    float* cur  = alloc(2 * RL_ * F_);
    float* res1 = alloc(2 * RL_ * F_);
    float* xz   = alloc(2 * RL_ * (2 * DI_));
    float* xc   = alloc(2 * RL_ * DI_);
    float* dl   = alloc(2 * RL_ * DI_);
    float* bcm  = alloc(2 * RL_ * 32);
    float* yb   = alloc(2 * RL_ * DI_);
    // scan scratch aliases h+wT (both dead by scan time): needs 540672 <= 1038336
    float* hp   = h;                                   // 2*2*16*4096 = 262144
    float* hin  = h + 262144;                          // 262144
    float* dsum = h + 524288;                          // 16384
    (void)ws_size; (void)in_sizes; (void)n_in; (void)out_size;

    // Phase A
    wt_k<<<FIN_, 256, 0, stream>>>(convT_w, wT);
    convt2_k<<<dim3(8, B_, 4), 256, 0, stream>>>(x, wT, convT_b, h);
    fuse2_k<<<dim3(32, B_), 256, 0, stream>>>(skip, h, fuse_w, fuse_b, xs);

    for (int blk = 0; blk < NBLK_; ++blk) {
        const float* Xin = (blk == 0) ? xs : res1;
        ln_inproj2_k<<<dim3(126, 4, 2), 256, 0, stream>>>(Xin, norm_w, norm_b, in_proj, xz, blk);
        dwconv2_k<<<dim3(1004, 2), 256, 0, stream>>>(xz, conv_w, conv_b, xc, blk);
        xdt2_k<<<dim3(126, 2), 256, 0, stream>>>(xc, x_proj, dt_projw, dt_projb, bcm, dl, blk);
        scanA_k<<<dim3(32, NC_, 2), 256, 0, stream>>>(dl, xc, bcm, A_log, hp, dsum, blk);
        scanB_k<<<dim3(32, 2), 256, 0, stream>>>(hp, dsum, A_log, hin, blk);
        scanC_k<<<dim3(32, NC_, 2), 256, 0, stream>>>(dl, xc, bcm, A_log, hin, yb, blk);
        if (blk == 0)
            gate2_k<<<dim3(126, 2), 256, 0, stream>>>(yb, xc, xz, D_skip, out_proj, xs, res1, 0);
        else
            gate2_k<<<dim3(126, 2), 256, 0, stream>>>(yb, xc, xz, D_skip, out_proj, nullptr, cur, 1);
    }

    combine2_k<<<dim3(32, B_), 256, 0, stream>>>(cur, res1, out);
}

// Round 3
// 589.919 us; speedup vs baseline: 4.2905x; 1.4722x over previous
//
#include <hip/hip_runtime.h>
#include <hip/hip_bf16.h>
#include <math.h>

// Problem constants
#define B_    2
#define FIN_  256
#define LIN_  250
#define F_    128      // F_OUT
#define K_    16       // KSIZE
#define ST_   8        // STRIDE
#define L_    2008     // L_OUT
#define DI_   256      // D_INNER
#define DS_   16       // D_STATE
#define RK_   8        // DT_RANK
#define CV_   4        // D_CONV
#define NBLK_ 2
#define NC_   32       // scan chunks
#define CL_   63       // chunk length (32*63 = 2016 >= 2008)
#define RL_   ((size_t)B_ * L_)   // rows per direction = 4016

__device__ __forceinline__ float silu_f(float x) {
    return x / (1.f + __expf(-x));
}
__device__ __forceinline__ float softplus_f(float x) {
    return (x > 20.f) ? x : log1pf(__expf(x));
}

// ---------------------------------------------------------------------------
// prep: build transposed weight buffers (one-time, ~4.6 MB)
//  W2     [512][1024]: W2[cc][p*128+o] = convT_w[c][o][k], k=p (cc<256) else p+8
//  fwT    [256][128] : fuse_w^T
//  inprojT[db][128][512]
//  opT    [db][256][128]
//  xpwT   [db][256][64] (e<40 valid, else 0)
// ---------------------------------------------------------------------------
#define PREP_N (524288 + 32768 + 262144 + 262144 + 65536)
__global__ void prep_k(const float* __restrict__ convT_w, const float* __restrict__ fuse_w,
                       const float* __restrict__ in_proj, const float* __restrict__ out_proj,
                       const float* __restrict__ x_proj,
                       float* __restrict__ W2, float* __restrict__ fwT,
                       float* __restrict__ inprojT, float* __restrict__ opT,
                       float* __restrict__ xpwT) {
    size_t g = (size_t)blockIdx.x * 256 + threadIdx.x;
    if (g >= PREP_N) return;
    if (g < 524288) {
        int cc = g >> 10, po = g & 1023;
        int p = po >> 7, o = po & 127;
        int c = cc & 255, k = (cc < 256) ? p : p + 8;
        W2[g] = convT_w[(size_t)c * 2048 + o * 16 + k];
        return;
    }
    g -= 524288;
    if (g < 32768) {
        int c = g >> 7, o = g & 127;
        fwT[g] = fuse_w[(size_t)o * 256 + c];
        return;
    }
    g -= 32768;
    if (g < 262144) {
        int db = g >> 16, r = g & 65535;
        int c = r >> 9, e = r & 511;
        inprojT[g] = in_proj[(size_t)db * 65536 + e * 128 + c];
        return;
    }
    g -= 262144;
    if (g < 262144) {
        int db = g >> 15, r = g & 32767;
        int c = r >> 7, o = r & 127;
        opT[g] = out_proj[(size_t)db * 32768 + o * 256 + c];
        return;
    }
    g -= 262144;
    {
        int db = g >> 14, r = g & 16383;
        int c = r >> 6, e = r & 63;
        xpwT[g] = (e < 40) ? x_proj[(size_t)db * 10240 + e * 256 + c] : 0.f;
    }
}

// ---------------------------------------------------------------------------
// convT+silu as GEMM: out(j, po) = sum_cc W2[cc][po] * xin[j][cc]
// xin[j][cc] = x[b][cc][j] (cc<256), x[b][cc-256][j-1] (cc>=256)
// grid (32 jt of 8 j, 4 po-tiles of 256, B), block 256. Output hT[b][t][o].
// ---------------------------------------------------------------------------
__global__ void convt3_k(const float* __restrict__ x, const float* __restrict__ W2,
                         const float* __restrict__ bias, float* __restrict__ hT) {
    int jt = blockIdx.x, nt = blockIdx.y, b = blockIdx.z;
    int j0 = jt * 8;
    int po = nt * 256 + threadIdx.x;
    int p = po >> 7, o = po & 127;

    __shared__ float xr[9][264];   // rows j0-1 .. j0+7

    for (int idx = threadIdx.x; idx < 9 * 256; idx += 256) {
        int i = idx >> 8, c = idx & 255;
        int j = j0 - 1 + i;
        xr[i][c] = (j >= 0 && j < LIN_) ? x[((size_t)b * FIN_ + c) * LIN_ + j] : 0.f;
    }
    __syncthreads();

    float acc[8];
    #pragma unroll
    for (int i = 0; i < 8; ++i) acc[i] = 0.f;

    for (int c = 0; c < 256; c += 4) {
        float w1[4], w2[4];
        #pragma unroll
        for (int i = 0; i < 4; ++i) {
            w1[i] = W2[(size_t)(c + i) * 1024 + po];
            w2[i] = W2[(size_t)(c + i + 256) * 1024 + po];
        }
        float4 xv[9];
        #pragma unroll
        for (int i = 0; i < 9; ++i) xv[i] = *(const float4*)&xr[i][c];
        #pragma unroll
        for (int jj = 0; jj < 8; ++jj) {
            acc[jj] += xv[jj + 1].x * w1[0] + xv[jj].x * w2[0]
                     + xv[jj + 1].y * w1[1] + xv[jj].y * w2[1]
                     + xv[jj + 1].z * w1[2] + xv[jj].z * w2[2]
                     + xv[jj + 1].w * w1[3] + xv[jj].w * w2[3];
        }
    }
    float bo = bias[o];
    #pragma unroll
    for (int jj = 0; jj < 8; ++jj) {
        int j = j0 + jj;
        if (j <= 250) {
            int t = 8 * j + p;
            hT[((size_t)b * L_ + t) * F_ + o] = silu_f(acc[jj] + bo);
        }
    }
}

// ---------------------------------------------------------------------------
// fuse = silu(fuse_w @ [skip; h] + b); writes xs fwd + flipped bwd.
// grid (126 l-tiles of 16, B), block 256 (o=tid&127, lh=tid>>7 -> 8 l each)
// ---------------------------------------------------------------------------
__global__ void fuse3_k(const float* __restrict__ skip, const float* __restrict__ hT,
                        const float* __restrict__ fwT, const float* __restrict__ fb,
                        float* __restrict__ xs) {
    int l0 = blockIdx.x * 16, b = blockIdx.y;
    int tid = threadIdx.x;

    __shared__ float ss[16][264];

    // skip part (c<128): src (b, c, l) row-major in l
    for (int idx = tid; idx < 128 * 16; idx += 256) {
        int c = idx >> 4, ll = idx & 15;
        int l = l0 + ll;
        ss[ll][c] = (l < L_) ? skip[((size_t)b * F_ + c) * L_ + l] : 0.f;
    }
    // h part (c>=128): src hT (b, l, c) row-major in c
    for (int idx = tid; idx < 16 * 128; idx += 256) {
        int ll = idx >> 7, c = idx & 127;
        int l = l0 + ll;
        ss[ll][128 + c] = (l < L_) ? hT[((size_t)b * L_ + l) * F_ + c] : 0.f;
    }
    __syncthreads();

    int o = tid & 127, lh = tid >> 7;
    float acc[8];
    #pragma unroll
    for (int i = 0; i < 8; ++i) acc[i] = 0.f;

    for (int c = 0; c < 256; c += 4) {
        float w0 = fwT[(size_t)c * 128 + o];
        float w1 = fwT[(size_t)(c + 1) * 128 + o];
        float w2 = fwT[(size_t)(c + 2) * 128 + o];
        float w3 = fwT[(size_t)(c + 3) * 128 + o];
        #pragma unroll
        for (int rr = 0; rr < 8; ++rr) {
            float4 s = *(const float4*)&ss[lh * 8 + rr][c];
            acc[rr] += s.x * w0 + s.y * w1 + s.z * w2 + s.w * w3;
        }
    }
    float bo = fb[o];
    #pragma unroll
    for (int rr = 0; rr < 8; ++rr) {
        int l = l0 + lh * 8 + rr;
        if (l < L_) {
            float v = silu_f(acc[rr] + bo);
            xs[((size_t)b * L_ + l) * F_ + o] = v;
            xs[(RL_ + (size_t)b * L_ + (L_ - 1 - l)) * F_ + o] = v;
        }
    }
}

// ---------------------------------------------------------------------------
// LayerNorm + in_proj GEMM, weights streamed from L2 (inprojT [db][c][e])
// grid (126 row-tiles of 32, 4 n-tiles of 128, 2 dirs), block 256
// ---------------------------------------------------------------------------
__global__ void ln3_k(const float* __restrict__ X, const float* __restrict__ nw,
                      const float* __restrict__ nb_, const float* __restrict__ WT,
                      float* __restrict__ XZ, int blk) {
    int rt = blockIdx.x, nt = blockIdx.y, d = blockIdx.z;
    int n0 = nt * 128;
    size_t rbase = (size_t)rt * 32;
    int tid = threadIdx.x, lane = tid & 63, wid = tid >> 6;
    int db = d * NBLK_ + blk;

    __shared__ float us[32][132];

    int wi0 = db * F_;
    for (int rr = 0; rr < 8; ++rr) {
        int r = wid * 8 + rr;
        size_t row = rbase + r;
        float2 v = make_float2(0.f, 0.f);
        if (row < RL_)
            v = *(const float2*)(X + ((size_t)d * RL_ + row) * F_ + lane * 2);
        float s1 = v.x + v.y, s2 = v.x * v.x + v.y * v.y;
        for (int off = 32; off; off >>= 1) {
            s1 += __shfl_xor(s1, off);
            s2 += __shfl_xor(s2, off);
        }
        float mu = s1 * (1.f / F_);
        float var = s2 * (1.f / F_) - mu * mu;
        float rstd = rsqrtf(var + 1e-5f);
        int c = lane * 2;
        us[r][c]     = (v.x - mu) * rstd * nw[wi0 + c]     + nb_[wi0 + c];
        us[r][c + 1] = (v.y - mu) * rstd * nw[wi0 + c + 1] + nb_[wi0 + c + 1];
    }
    __syncthreads();

    int o = tid & 127, rh = tid >> 7;
    float acc[16];
    #pragma unroll
    for (int i = 0; i < 16; ++i) acc[i] = 0.f;
    const float* Wc = WT + (size_t)db * 65536 + n0 + o;

    for (int c = 0; c < 128; c += 4) {
        float w0 = Wc[(size_t)c * 512];
        float w1 = Wc[(size_t)(c + 1) * 512];
        float w2 = Wc[(size_t)(c + 2) * 512];
        float w3 = Wc[(size_t)(c + 3) * 512];
        #pragma unroll
        for (int rr = 0; rr < 16; ++rr) {
            float4 u = *(const float4*)&us[rh * 16 + rr][c];
            acc[rr] += u.x * w0 + u.y * w1 + u.z * w2 + u.w * w3;
        }
    }
    for (int rr = 0; rr < 16; ++rr) {
        size_t row = rbase + rh * 16 + rr;
        if (row < RL_)
            XZ[((size_t)d * RL_ + row) * (2 * DI_) + n0 + o] = acc[rr];
    }
}

// ---------------------------------------------------------------------------
// depthwise causal conv(4) + silu; 4 rows per block
// grid (1004, 2), block 256
// ---------------------------------------------------------------------------
__global__ void dwconv2_k(const float* __restrict__ XZ, const float* __restrict__ cw,
                          const float* __restrict__ cb, float* __restrict__ XC, int blk) {
    int d = blockIdx.y;
    int ch = threadIdx.x;
    int wi = (d * NBLK_ + blk) * DI_ + ch;
    float w0 = cw[(size_t)wi * CV_ + 0], w1 = cw[(size_t)wi * CV_ + 1];
    float w2 = cw[(size_t)wi * CV_ + 2], w3 = cw[(size_t)wi * CV_ + 3];
    float bias = cb[wi];
    for (int r4 = 0; r4 < 4; ++r4) {
        int row = blockIdx.x * 4 + r4;
        int b = row / L_, l = row % L_;
        const float* base = XZ + ((size_t)d * RL_ + (size_t)b * L_) * (2 * DI_);
        float acc = bias;
        if (l - 3 >= 0) acc += base[(size_t)(l - 3) * (2 * DI_) + ch] * w0;
        if (l - 2 >= 0) acc += base[(size_t)(l - 2) * (2 * DI_) + ch] * w1;
        if (l - 1 >= 0) acc += base[(size_t)(l - 1) * (2 * DI_) + ch] * w2;
        acc += base[(size_t)l * (2 * DI_) + ch] * w3;
        XC[((size_t)d * RL_ + row) * DI_ + ch] = silu_f(acc);
    }
}

// ---------------------------------------------------------------------------
// x_proj (40) + dt_proj (256) + softplus; rows-tile 32, streamed xpwT
// grid (126, 2), block 256
// ---------------------------------------------------------------------------
__global__ void xdt3_k(const float* __restrict__ XC, const float* __restrict__ xpwT,
                       const float* __restrict__ dtw, const float* __restrict__ dtb,
                       float* __restrict__ BCM, float* __restrict__ DELTA, int blk) {
    int rt = blockIdx.x, d = blockIdx.y;
    int tid = threadIdx.x;
    size_t rbase = (size_t)rt * 32;
    int db = d * NBLK_ + blk;

    __shared__ float xr[32][260];
    __shared__ float dts[32][8];

    for (int idx = tid; idx < 32 * 256; idx += 256) {
        int r = idx >> 8, c = idx & 255;
        size_t row = rbase + r;
        xr[r][c] = (row < RL_) ? XC[((size_t)d * RL_ + row) * DI_ + c] : 0.f;
    }
    __syncthreads();

    // phase 1: 40 outputs x 32 rows; e = tid&63 (e<40 active), rg = tid>>6
    {
        int e = tid & 63, rg = tid >> 6;
        float acc[8];
        #pragma unroll
        for (int i = 0; i < 8; ++i) acc[i] = 0.f;
        const float* Wc = xpwT + (size_t)db * 16384 + e;
        for (int c = 0; c < 256; c += 4) {
            float w0 = Wc[(size_t)c * 64];
            float w1 = Wc[(size_t)(c + 1) * 64];
            float w2 = Wc[(size_t)(c + 2) * 64];
            float w3 = Wc[(size_t)(c + 3) * 64];
            #pragma unroll
            for (int rr = 0; rr < 8; ++rr) {
                float4 xv = *(const float4*)&xr[rg * 8 + rr][c];
                acc[rr] += xv.x * w0 + xv.y * w1 + xv.z * w2 + xv.w * w3;
            }
        }
        if (e < RK_) {
            #pragma unroll
            for (int rr = 0; rr < 8; ++rr) dts[rg * 8 + rr][e] = acc[rr];
        } else if (e < RK_ + 2 * DS_) {
            #pragma unroll
            for (int rr = 0; rr < 8; ++rr) {
                size_t row = rbase + rg * 8 + rr;
                if (row < RL_)
                    BCM[((size_t)d * RL_ + row) * 32 + (e - RK_)] = acc[rr];
            }
        }
    }
    __syncthreads();

    // phase 2: delta
    int ch = tid;
    int wi = db * DI_ + ch;
    float dwv[RK_];
    #pragma unroll
    for (int k = 0; k < RK_; ++k) dwv[k] = dtw[(size_t)wi * RK_ + k];
    float bias = dtb[wi];
    for (int rr = 0; rr < 32; ++rr) {
        size_t row = rbase + rr;
        if (row >= RL_) break;
        float acc = bias;
        #pragma unroll
        for (int k = 0; k < RK_; ++k) acc += dts[rr][k] * dwv[k];
        DELTA[((size_t)d * RL_ + row) * DI_ + ch] = softplus_f(acc);
    }
}

// ---------------------------------------------------------------------------
// scan pass A: chunk-local scan h0=0 -> hpart, dtsum
// grid (32, NC_, 2), block 256 (16 ch x 16 n)
// ---------------------------------------------------------------------------
__global__ void scanA_k(const float* __restrict__ DELTA, const float* __restrict__ XC,
                        const float* __restrict__ BCM, const float* __restrict__ A_log,
                        float* __restrict__ hpart, float* __restrict__ dsum, int blk) {
    int d = blockIdx.z, cnk = blockIdx.y;
    int g = blockIdx.x * 16 + (threadIdx.x >> 4);
    int n = threadIdx.x & 15;
    int b = g >> 8, ch = g & 255;
    int t0 = cnk * CL_;
    int t1 = t0 + CL_; if (t1 > L_) t1 = L_;

    float A = -__expf(A_log[((size_t)(d * NBLK_ + blk) * DI_ + ch) * DS_ + n]);
    const float* db_ = DELTA + ((size_t)d * B_ + b) * L_ * DI_ + ch;
    const float* ub  = XC    + ((size_t)d * B_ + b) * L_ * DI_ + ch;
    const float* bb  = BCM   + ((size_t)d * B_ + b) * L_ * 32 + n;

    float h = 0.f, ds = 0.f;
    float dt = db_[(size_t)t0 * DI_], u = ub[(size_t)t0 * DI_], Bt = bb[(size_t)t0 * 32];
    for (int t = t0; t < t1; ++t) {
        float dtn = 0.f, un = 0.f, Btn = 0.f;
        if (t + 1 < t1) {
            dtn = db_[(size_t)(t + 1) * DI_];
            un  = ub[(size_t)(t + 1) * DI_];
            Btn = bb[(size_t)(t + 1) * 32];
        }
        h = __expf(dt * A) * h + dt * u * Bt;
        ds += dt;
        dt = dtn; u = un; Bt = Btn;
    }
    size_t cb = (size_t)(d * B_ + b) * NC_ + cnk;
    hpart[cb * (DI_ * DS_) + ch * DS_ + n] = h;
    if (n == 0) dsum[cb * DI_ + ch] = ds;
}

// ---------------------------------------------------------------------------
// scan pass B: cross-chunk scan, in-place (hpart becomes carry-in per chunk)
// grid (32, 2), block 256
// ---------------------------------------------------------------------------
__global__ void scanB_k(float* __restrict__ hpart, const float* __restrict__ dsum,
                        const float* __restrict__ A_log, int blk) {
    int d = blockIdx.y;
    int idx = blockIdx.x * 256 + threadIdx.x;   // (b, ch, n)
    int b = idx >> 12, ch = (idx >> 4) & 255, n = idx & 15;
    float A = -__expf(A_log[((size_t)(d * NBLK_ + blk) * DI_ + ch) * DS_ + n]);
    float h = 0.f;
    for (int c = 0; c < NC_; ++c) {
        size_t cb = (size_t)(d * B_ + b) * NC_ + c;
        size_t hi = cb * (DI_ * DS_) + ch * DS_ + n;
        float hc = hpart[hi];
        hpart[hi] = h;                       // carry-in for chunk c
        h = __expf(A * dsum[cb * DI_ + ch]) * h + hc;
    }
}

// ---------------------------------------------------------------------------
// scan pass C: re-scan with carry-in, emit y
// grid (32, NC_, 2), block 256
// ---------------------------------------------------------------------------
__global__ void scanC_k(const float* __restrict__ DELTA, const float* __restrict__ XC,
                        const float* __restrict__ BCM, const float* __restrict__ A_log,
                        const float* __restrict__ hin, float* __restrict__ Y, int blk) {
    int d = blockIdx.z, cnk = blockIdx.y;
    int g = blockIdx.x * 16 + (threadIdx.x >> 4);
    int n = threadIdx.x & 15;
    int b = g >> 8, ch = g & 255;
    int t0 = cnk * CL_;
    int t1 = t0 + CL_; if (t1 > L_) t1 = L_;

    float A = -__expf(A_log[((size_t)(d * NBLK_ + blk) * DI_ + ch) * DS_ + n]);
    const float* db_ = DELTA + ((size_t)d * B_ + b) * L_ * DI_ + ch;
    const float* ub  = XC    + ((size_t)d * B_ + b) * L_ * DI_ + ch;
    const float* bb  = BCM   + ((size_t)d * B_ + b) * L_ * 32 + n;
    float* yb        = Y     + ((size_t)d * B_ + b) * L_ * DI_ + ch;

    size_t cb = (size_t)(d * B_ + b) * NC_ + cnk;
    float h = hin[cb * (DI_ * DS_) + ch * DS_ + n];

    float dt = db_[(size_t)t0 * DI_], u = ub[(size_t)t0 * DI_];
    float Bt = bb[(size_t)t0 * 32], Ct = bb[(size_t)t0 * 32 + 16];
    for (int t = t0; t < t1; ++t) {
        float dtn = 0.f, un = 0.f, Btn = 0.f, Ctn = 0.f;
        if (t + 1 < t1) {
            dtn = db_[(size_t)(t + 1) * DI_];
            un  = ub[(size_t)(t + 1) * DI_];
            Btn = bb[(size_t)(t + 1) * 32];
            Ctn = bb[(size_t)(t + 1) * 32 + 16];
        }
        h = __expf(dt * A) * h + dt * u * Bt;
        float yp = h * Ct;
        yp += __shfl_xor(yp, 1);
        yp += __shfl_xor(yp, 2);
        yp += __shfl_xor(yp, 4);
        yp += __shfl_xor(yp, 8);
        if (n == 0) yb[(size_t)t * DI_] = yp;
        dt = dtn; u = un; Bt = Btn; Ct = Ctn;
    }
}

// ---------------------------------------------------------------------------
// gate + out_proj GEMM (+ optional residual-in); rows-tile 32, streamed opT
// grid (126, 2), block 256
// ---------------------------------------------------------------------------
__global__ void gate3_k(const float* __restrict__ Y, const float* __restrict__ XC,
                        const float* __restrict__ XZ, const float* __restrict__ Dsk,
                        const float* __restrict__ opT, const float* __restrict__ resid_in,
                        float* __restrict__ outp, int blk) {
    int rt = blockIdx.x, d = blockIdx.y;
    int tid = threadIdx.x;
    size_t rbase = (size_t)rt * 32;
    int db = d * NBLK_ + blk;

    __shared__ float yg[32][260];

    const float* Dp = Dsk + (size_t)db * DI_;
    for (int idx = tid; idx < 32 * 256; idx += 256) {
        int r = idx >> 8, c = idx & 255;
        size_t row = rbase + r;
        float v = 0.f;
        if (row < RL_) {
            size_t ri = (size_t)d * RL_ + row;
            float z = XZ[ri * (2 * DI_) + DI_ + c];
            v = (Y[ri * DI_ + c] + XC[ri * DI_ + c] * Dp[c]) * silu_f(z);
        }
        yg[r][c] = v;
    }
    __syncthreads();

    int o = tid & 127, rh = tid >> 7;
    float acc[16];
    #pragma unroll
    for (int i = 0; i < 16; ++i) acc[i] = 0.f;
    const float* Wc = opT + (size_t)db * 32768 + o;

    for (int c = 0; c < 256; c += 4) {
        float w0 = Wc[(size_t)c * 128];
        float w1 = Wc[(size_t)(c + 1) * 128];
        float w2 = Wc[(size_t)(c + 2) * 128];
        float w3 = Wc[(size_t)(c + 3) * 128];
        #pragma unroll
        for (int rr = 0; rr < 16; ++rr) {
            float4 u = *(const float4*)&yg[rh * 16 + rr][c];
            acc[rr] += u.x * w0 + u.y * w1 + u.z * w2 + u.w * w3;
        }
    }
    for (int rr = 0; rr < 16; ++rr) {
        size_t row = rbase + rh * 16 + rr;
        if (row < RL_) {
            size_t ri = (size_t)d * RL_ + row;
            float v = acc[rr];
            if (resid_in) v += resid_in[ri * F_ + o];
            outp[ri * F_ + o] = v;
        }
    }
}

// ---------------------------------------------------------------------------
// combine with LDS transpose for coalesced (b,o,l) writes
// grid (32 l-tiles, B), block 256
// ---------------------------------------------------------------------------
__global__ void combine2_k(const float* __restrict__ cur, const float* __restrict__ res1,
                           float* __restrict__ out) {
    int l0 = blockIdx.x * 64, b = blockIdx.y;
    int tid = threadIdx.x;
    __shared__ float s[64][129];
    for (int idx = tid; idx < 64 * 128; idx += 256) {
        int ll = idx >> 7, o = idx & 127;
        int l = l0 + ll;
        if (l < L_) {
            size_t rf = ((size_t)b * L_ + l) * F_ + o;
            size_t rb = (RL_ + (size_t)b * L_ + (L_ - 1 - l)) * F_ + o;
            s[ll][o] = cur[rf] + res1[rf] + cur[rb] + res1[rb];
        }
    }
    __syncthreads();
    for (int idx = tid; idx < 64 * 128; idx += 256) {
        int o = idx >> 6, ll = idx & 63;
        int l = l0 + ll;
        if (l < L_) out[((size_t)b * F_ + o) * L_ + l] = s[ll][o];
    }
}

// ---------------------------------------------------------------------------
extern "C" void kernel_launch(void* const* d_in, const int* in_sizes, int n_in,
                              void* d_out, int out_size, void* d_ws, size_t ws_size,
                              hipStream_t stream) {
    const float* x        = (const float*)d_in[0];
    const float* skip     = (const float*)d_in[1];
    const float* convT_w  = (const float*)d_in[4];
    const float* convT_b  = (const float*)d_in[5];
    const float* fuse_w   = (const float*)d_in[6];
    const float* fuse_b   = (const float*)d_in[7];
    const float* norm_w   = (const float*)d_in[8];
    const float* norm_b   = (const float*)d_in[9];
    const float* in_proj  = (const float*)d_in[10];
    const float* conv_w   = (const float*)d_in[11];
    const float* conv_b   = (const float*)d_in[12];
    const float* x_proj   = (const float*)d_in[13];
    const float* dt_projw = (const float*)d_in[14];
    const float* dt_projb = (const float*)d_in[15];
    const float* A_log    = (const float*)d_in[16];
    const float* D_skip   = (const float*)d_in[17];
    const float* out_proj = (const float*)d_in[18];
    float* out = (float*)d_out;

    float* w = (float*)d_ws;
    size_t off = 0;
    auto alloc = [&](size_t n) { float* p = w + off; off += n; return p; };
    float* hT      = alloc((size_t)B_ * L_ * F_);       // 514048 (dead after fuse)
    float* W2      = alloc(524288);                     // dead after convt3
    float* fwT     = alloc(32768);
    float* inprojT = alloc(262144);
    float* opT     = alloc(262144);
    float* xpwT    = alloc(65536);
    float* xs      = alloc(2 * RL_ * F_);
    float* cur     = alloc(2 * RL_ * F_);
    float* res1    = alloc(2 * RL_ * F_);
    float* xz      = alloc(2 * RL_ * (2 * DI_));
    float* xc      = alloc(2 * RL_ * DI_);
    float* dl      = alloc(2 * RL_ * DI_);
    float* bcm     = alloc(2 * RL_ * 32);
    float* yb      = alloc(2 * RL_ * DI_);
    // scan scratch aliases hT+W2 (contiguous 1038336 floats, both dead by scan)
    float* hp   = hT;                 // 2*2*32*4096 = 524288
    float* dsum = hT + 524288;        // 2*2*32*256  = 32768  (total 557056 OK)
    (void)ws_size; (void)in_sizes; (void)n_in; (void)out_size;

    prep_k<<<(PREP_N + 255) / 256, 256, 0, stream>>>(convT_w, fuse_w, in_proj, out_proj,
                                                     x_proj, W2, fwT, inprojT, opT, xpwT);
    convt3_k<<<dim3(32, 4, 2), 256, 0, stream>>>(x, W2, convT_b, hT);
    fuse3_k<<<dim3(126, 2), 256, 0, stream>>>(skip, hT, fwT, fuse_b, xs);

    for (int blk = 0; blk < NBLK_; ++blk) {
        const float* Xin = (blk == 0) ? xs : res1;
        ln3_k<<<dim3(126, 4, 2), 256, 0, stream>>>(Xin, norm_w, norm_b, inprojT, xz, blk);
        dwconv2_k<<<dim3(1004, 2), 256, 0, stream>>>(xz, conv_w, conv_b, xc, blk);
        xdt3_k<<<dim3(126, 2), 256, 0, stream>>>(xc, xpwT, dt_projw, dt_projb, bcm, dl, blk);
        scanA_k<<<dim3(32, NC_, 2), 256, 0, stream>>>(dl, xc, bcm, A_log, hp, dsum, blk);
        scanB_k<<<dim3(32, 2), 256, 0, stream>>>(hp, dsum, A_log, blk);
        scanC_k<<<dim3(32, NC_, 2), 256, 0, stream>>>(dl, xc, bcm, A_log, hp, yb, blk);
        if (blk == 0)
            gate3_k<<<dim3(126, 2), 256, 0, stream>>>(yb, xc, xz, D_skip, opT, xs, res1, 0);
        else
            gate3_k<<<dim3(126, 2), 256, 0, stream>>>(yb, xc, xz, D_skip, opT, nullptr, cur, 1);
    }

    combine2_k<<<dim3(32, 2), 256, 0, stream>>>(cur, res1, out);
}

// Round 4
// 493.547 us; speedup vs baseline: 5.1282x; 1.1953x over previous
//
#include <hip/hip_runtime.h>
#include <hip/hip_bf16.h>
#include <math.h>

// Problem constants
#define B_    2
#define FIN_  256
#define LIN_  250
#define F_    128      // F_OUT
#define K_    16       // KSIZE
#define ST_   8        // STRIDE
#define L_    2008     // L_OUT
#define DI_   256      // D_INNER
#define DS_   16       // D_STATE
#define RK_   8        // DT_RANK
#define CV_   4        // D_CONV
#define NBLK_ 2
#define NC_   32       // scan chunks
#define CL_   63       // chunk length (32*63 = 2016 >= 2008)
#define RL_   ((size_t)B_ * L_)   // rows per direction = 4016

__device__ __forceinline__ float silu_f(float x) {
    return x / (1.f + __expf(-x));
}
__device__ __forceinline__ float softplus_f(float x) {
    return (x > 20.f) ? x : log1pf(__expf(x));
}
__device__ __forceinline__ float dot4(float4 a, float4 b) {
    return a.x * b.x + a.y * b.y + a.z * b.z + a.w * b.w;
}

// ---------------------------------------------------------------------------
// prep: packed transposed weights, each as [c/4][out][4] so a thread's 4-c
// weight bundle is ONE coalesced dwordx4.
//  W2p  [128 ccq][1024 po][4]   (cc<256: tap k=p at x[j]; cc>=256: k=p+8 at x[j-1])
//  fwTp [64 cq][128 o][4]
//  ipTp [db][32 cq][512 e][4]
//  opTp [db][64 cq][128 o][4]
//  xpTp [db][64 cq][64 e][4]  (e<40 valid else 0)
// ---------------------------------------------------------------------------
#define PREP_N (524288 + 32768 + 262144 + 262144 + 65536)
__global__ void prep_k(const float* __restrict__ convT_w, const float* __restrict__ fuse_w,
                       const float* __restrict__ in_proj, const float* __restrict__ out_proj,
                       const float* __restrict__ x_proj,
                       float* __restrict__ W2p, float* __restrict__ fwTp,
                       float* __restrict__ ipTp, float* __restrict__ opTp,
                       float* __restrict__ xpTp) {
    size_t g = (size_t)blockIdx.x * 256 + threadIdx.x;
    if (g >= PREP_N) return;
    if (g < 524288) {
        int ccq = g >> 12, rr = g & 4095;
        int po = rr >> 2, i = rr & 3;
        int cc = ccq * 4 + i;
        int p = po >> 7, o = po & 127;
        int c = cc & 255, k = (cc < 256) ? p : p + 8;
        W2p[g] = convT_w[(size_t)c * 2048 + o * 16 + k];
        return;
    }
    g -= 524288;
    if (g < 32768) {
        int cq = g >> 9, rr = g & 511;
        int o = rr >> 2, i = rr & 3;
        fwTp[g] = fuse_w[(size_t)o * 256 + cq * 4 + i];
        return;
    }
    g -= 32768;
    if (g < 262144) {
        int db = g >> 16, r = g & 65535;
        int cq = r >> 11, rr = r & 2047;
        int e = rr >> 2, i = rr & 3;
        ipTp[g] = in_proj[(size_t)db * 65536 + e * 128 + cq * 4 + i];
        return;
    }
    g -= 262144;
    if (g < 262144) {
        int db = g >> 15, r = g & 32767;
        int cq = r >> 9, rr = r & 511;
        int o = rr >> 2, i = rr & 3;
        opTp[g] = out_proj[(size_t)db * 32768 + o * 256 + cq * 4 + i];
        return;
    }
    g -= 262144;
    {
        int db = g >> 14, r = g & 16383;
        int cq = r >> 8, rr = r & 255;
        int e = rr >> 2, i = rr & 3;
        xpTp[g] = (e < 40) ? x_proj[(size_t)db * 10240 + e * 256 + cq * 4 + i] : 0.f;
    }
}

// ---------------------------------------------------------------------------
// convT+silu GEMM: out(j, po) = sum_cc W2[cc][po]*xin[j][cc]
// grid (63 jt of 4, 4 nt, B), block 256. Output hT[b][t][o].
// ---------------------------------------------------------------------------
__global__ void __launch_bounds__(256) convt4_k(
        const float* __restrict__ x, const float* __restrict__ W2p,
        const float* __restrict__ bias, float* __restrict__ hT) {
    int j0 = blockIdx.x * 4, nt = blockIdx.y, b = blockIdx.z;
    int po = nt * 256 + threadIdx.x;
    int p = po >> 7, o = po & 127;

    __shared__ float xr[5][264];   // rows j0-1 .. j0+3

    for (int idx = threadIdx.x; idx < 5 * 256; idx += 256) {
        int i = idx >> 8, c = idx & 255;
        int j = j0 - 1 + i;
        xr[i][c] = (j >= 0 && j < LIN_) ? x[((size_t)b * FIN_ + c) * LIN_ + j] : 0.f;
    }
    __syncthreads();

    float acc[4] = {0.f, 0.f, 0.f, 0.f};
    const float4* W4 = (const float4*)W2p;

    for (int ccq = 0; ccq < 64; ++ccq) {
        float4 w1 = W4[(size_t)ccq * 1024 + po];
        float4 w2 = W4[(size_t)(ccq + 64) * 1024 + po];
        float4 xv[5];
        #pragma unroll
        for (int i = 0; i < 5; ++i) xv[i] = *(const float4*)&xr[i][ccq * 4];
        #pragma unroll
        for (int jj = 0; jj < 4; ++jj)
            acc[jj] += dot4(xv[jj + 1], w1) + dot4(xv[jj], w2);
    }
    float bo = bias[o];
    #pragma unroll
    for (int jj = 0; jj < 4; ++jj) {
        int j = j0 + jj;
        if (j <= 250) {
            int t = 8 * j + p;
            hT[((size_t)b * L_ + t) * F_ + o] = silu_f(acc[jj] + bo);
        }
    }
}

// ---------------------------------------------------------------------------
// fuse = silu(fuse_w @ [skip; h] + b); writes xs fwd + flipped bwd.
// grid (251 l-tiles of 8, B), block 256 (o=tid&127, lh=tid>>7 -> 4 l each)
// ---------------------------------------------------------------------------
__global__ void __launch_bounds__(256) fuse4_k(
        const float* __restrict__ skip, const float* __restrict__ hT,
        const float* __restrict__ fwTp, const float* __restrict__ fb,
        float* __restrict__ xs) {
    int l0 = blockIdx.x * 8, b = blockIdx.y;
    int tid = threadIdx.x;

    __shared__ float ss[8][264];

    for (int idx = tid; idx < 128 * 8; idx += 256) {   // skip part (c<128)
        int c = idx >> 3, ll = idx & 7;
        ss[ll][c] = skip[((size_t)b * F_ + c) * L_ + l0 + ll];
    }
    for (int idx = tid; idx < 8 * 128; idx += 256) {   // h part (c>=128)
        int ll = idx >> 7, c = idx & 127;
        ss[ll][128 + c] = hT[((size_t)b * L_ + l0 + ll) * F_ + c];
    }
    __syncthreads();

    int o = tid & 127, lh = tid >> 7;
    float acc[4] = {0.f, 0.f, 0.f, 0.f};
    const float4* W4 = (const float4*)fwTp;

    for (int cq = 0; cq < 64; ++cq) {
        float4 w = W4[cq * 128 + o];
        #pragma unroll
        for (int rr = 0; rr < 4; ++rr)
            acc[rr] += dot4(*(const float4*)&ss[lh * 4 + rr][cq * 4], w);
    }
    float bo = fb[o];
    #pragma unroll
    for (int rr = 0; rr < 4; ++rr) {
        int l = l0 + lh * 4 + rr;
        float v = silu_f(acc[rr] + bo);
        xs[((size_t)b * L_ + l) * F_ + o] = v;
        xs[(RL_ + (size_t)b * L_ + (L_ - 1 - l)) * F_ + o] = v;
    }
}

// ---------------------------------------------------------------------------
// LayerNorm + in_proj GEMM, packed weights. grid (126, 4 nt, 2 d), block 256
// ---------------------------------------------------------------------------
__global__ void __launch_bounds__(256) ln4_k(
        const float* __restrict__ X, const float* __restrict__ nw,
        const float* __restrict__ nb_, const float* __restrict__ ipTp,
        float* __restrict__ XZ, int blk) {
    int rt = blockIdx.x, nt = blockIdx.y, d = blockIdx.z;
    int n0 = nt * 128;
    size_t rbase = (size_t)rt * 32;
    int tid = threadIdx.x, lane = tid & 63, wid = tid >> 6;
    int db = d * NBLK_ + blk;

    __shared__ float us[32][132];

    int wi0 = db * F_;
    for (int rr = 0; rr < 8; ++rr) {
        int r = wid * 8 + rr;
        size_t row = rbase + r;
        float2 v = make_float2(0.f, 0.f);
        if (row < RL_)
            v = *(const float2*)(X + ((size_t)d * RL_ + row) * F_ + lane * 2);
        float s1 = v.x + v.y, s2 = v.x * v.x + v.y * v.y;
        for (int off = 32; off; off >>= 1) {
            s1 += __shfl_xor(s1, off);
            s2 += __shfl_xor(s2, off);
        }
        float mu = s1 * (1.f / F_);
        float var = s2 * (1.f / F_) - mu * mu;
        float rstd = rsqrtf(var + 1e-5f);
        int c = lane * 2;
        us[r][c]     = (v.x - mu) * rstd * nw[wi0 + c]     + nb_[wi0 + c];
        us[r][c + 1] = (v.y - mu) * rstd * nw[wi0 + c + 1] + nb_[wi0 + c + 1];
    }
    __syncthreads();

    int o = tid & 127, rh = tid >> 7;
    float acc[16];
    #pragma unroll
    for (int i = 0; i < 16; ++i) acc[i] = 0.f;
    const float4* W4 = (const float4*)(ipTp + (size_t)db * 65536);

    for (int cq = 0; cq < 32; ++cq) {
        float4 w = W4[cq * 512 + n0 + o];
        #pragma unroll
        for (int rr = 0; rr < 16; ++rr)
            acc[rr] += dot4(*(const float4*)&us[rh * 16 + rr][cq * 4], w);
    }
    for (int rr = 0; rr < 16; ++rr) {
        size_t row = rbase + rh * 16 + rr;
        if (row < RL_)
            XZ[((size_t)d * RL_ + row) * (2 * DI_) + n0 + o] = acc[rr];
    }
}

// ---------------------------------------------------------------------------
// fused depthwise conv(4)+silu -> xc, then x_proj(40)+dt_proj(256)+softplus
// rows-tile 16; grid (251, 2), block 256
// ---------------------------------------------------------------------------
__global__ void __launch_bounds__(256) dwxdt_k(
        const float* __restrict__ XZ, const float* __restrict__ cw,
        const float* __restrict__ cb, const float* __restrict__ xpTp,
        const float* __restrict__ dtw, const float* __restrict__ dtb,
        float* __restrict__ XC, float* __restrict__ BCM,
        float* __restrict__ DELTA, int blk) {
    int rt = blockIdx.x, d = blockIdx.y;
    int tid = threadIdx.x;
    size_t rbase = (size_t)rt * 16;
    int db = d * NBLK_ + blk;

    __shared__ float xzs[19][264];   // rows rbase-3 .. rbase+15, first half of XZ
    __shared__ float xcs[16][264];
    __shared__ float dts[16][8];

    for (int idx = tid; idx < 19 * 256; idx += 256) {
        int s = idx >> 8;                     // 0..18  (wait: 19*256/256=19 iters, s=idx/256)
        int c = idx & 255;
        long g = (long)rbase - 3 + s;
        xzs[s][c] = (g >= 0) ? XZ[((size_t)d * RL_ + g) * (2 * DI_) + c] : 0.f;
    }
    __syncthreads();

    // depthwise conv: thread's channel is fixed (ch = tid)
    {
        int ch = tid;
        int wi = db * DI_ + ch;
        float w0 = cw[(size_t)wi * CV_ + 0], w1 = cw[(size_t)wi * CV_ + 1];
        float w2 = cw[(size_t)wi * CV_ + 2], w3 = cw[(size_t)wi * CV_ + 3];
        float bias = cb[wi];
        #pragma unroll 4
        for (int r = 0; r < 16; ++r) {
            size_t row = rbase + r;
            int b = (row >= L_) ? 1 : 0;
            int l = (int)(row - (size_t)b * L_);
            int s = r + 3;
            float acc = bias + xzs[s][ch] * w3;
            if (l - 1 >= 0) acc += xzs[s - 1][ch] * w2;
            if (l - 2 >= 0) acc += xzs[s - 2][ch] * w1;
            if (l - 3 >= 0) acc += xzs[s - 3][ch] * w0;
            float v = silu_f(acc);
            xcs[r][ch] = v;
            XC[((size_t)d * RL_ + row) * DI_ + ch] = v;
        }
    }
    __syncthreads();

    // x_proj: e = tid&63 (e<40 active), rg = tid>>6 covers 4 rows each
    {
        int e = tid & 63, rg = tid >> 6;
        float acc[4] = {0.f, 0.f, 0.f, 0.f};
        const float4* W4 = (const float4*)(xpTp + (size_t)db * 16384);
        for (int cq = 0; cq < 64; ++cq) {
            float4 w = W4[cq * 64 + e];
            #pragma unroll
            for (int rr = 0; rr < 4; ++rr)
                acc[rr] += dot4(*(const float4*)&xcs[rg * 4 + rr][cq * 4], w);
        }
        if (e < RK_) {
            #pragma unroll
            for (int rr = 0; rr < 4; ++rr) dts[rg * 4 + rr][e] = acc[rr];
        } else if (e < RK_ + 2 * DS_) {
            #pragma unroll
            for (int rr = 0; rr < 4; ++rr) {
                size_t row = rbase + rg * 4 + rr;
                BCM[((size_t)d * RL_ + row) * 32 + (e - RK_)] = acc[rr];
            }
        }
    }
    __syncthreads();

    // dt_proj + softplus
    {
        int ch = tid;
        int wi = db * DI_ + ch;
        float dwv[RK_];
        #pragma unroll
        for (int k = 0; k < RK_; ++k) dwv[k] = dtw[(size_t)wi * RK_ + k];
        float bias = dtb[wi];
        #pragma unroll 4
        for (int rr = 0; rr < 16; ++rr) {
            size_t row = rbase + rr;
            float acc = bias;
            #pragma unroll
            for (int k = 0; k < RK_; ++k) acc += dts[rr][k] * dwv[k];
            DELTA[((size_t)d * RL_ + row) * DI_ + ch] = softplus_f(acc);
        }
    }
}

// ---------------------------------------------------------------------------
// scanA: LDS-staged chunk-local scan. Emits local y, inclusive cum(dt)
// (overwrites DELTA), chunk-final hpart and dtsum.
// grid (32 chgrp, NC_, 2), block 256 = 16 chl x 16 n
// ---------------------------------------------------------------------------
__global__ void __launch_bounds__(256) scanA_k(
        float* __restrict__ DELTA, const float* __restrict__ XC,
        const float* __restrict__ BCM, const float* __restrict__ A_log,
        float* __restrict__ Y, float* __restrict__ hpart,
        float* __restrict__ dsum, int blk) {
    int d = blockIdx.z, cnk = blockIdx.y;
    int chunit0 = blockIdx.x * 16;
    int chl = threadIdx.x >> 4, n = threadIdx.x & 15;
    int b = chunit0 >> 8, ch0 = chunit0 & 255;
    int ch = ch0 + chl;
    int t0 = cnk * CL_;
    int nt = L_ - t0 < CL_ ? L_ - t0 : CL_;

    __shared__ float dt_s[CL_][16];
    __shared__ float u_s[CL_][16];
    __shared__ float bc_s[CL_][32];

    size_t rowbase = (size_t)d * RL_ + (size_t)b * L_ + t0;
    for (int idx = threadIdx.x; idx < CL_ * 16; idx += 256) {
        int t = idx >> 4, c = idx & 15;
        float dv = 0.f, uv = 0.f;
        if (t < nt) {
            dv = DELTA[(rowbase + t) * DI_ + ch0 + c];
            uv = XC[(rowbase + t) * DI_ + ch0 + c];
        }
        dt_s[t][c] = dv; u_s[t][c] = uv;
    }
    for (int idx = threadIdx.x; idx < CL_ * 32; idx += 256) {
        int t = idx >> 5, m = idx & 31;
        bc_s[t][m] = (t < nt) ? BCM[(rowbase + t) * 32 + m] : 0.f;
    }
    __syncthreads();

    float A = -__expf(A_log[((size_t)(d * NBLK_ + blk) * DI_ + ch) * DS_ + n]);
    float h = 0.f, cum = 0.f;
    for (int t = 0; t < nt; ++t) {
        float dt = dt_s[t][chl];
        float u  = u_s[t][chl];
        float Bt = bc_s[t][n];
        float Ct = bc_s[t][16 + n];
        cum += dt;
        h = __expf(dt * A) * h + dt * u * Bt;
        float yp = h * Ct;
        yp += __shfl_xor(yp, 1);
        yp += __shfl_xor(yp, 2);
        yp += __shfl_xor(yp, 4);
        yp += __shfl_xor(yp, 8);
        if (n == 0) {
            Y[(rowbase + t) * DI_ + ch] = yp;
            DELTA[(rowbase + t) * DI_ + ch] = cum;   // inclusive prefix of dt
        }
    }
    size_t cb = (size_t)(d * B_ + b) * NC_ + cnk;
    hpart[cb * (DI_ * DS_) + ch * DS_ + n] = h;
    if (n == 0) dsum[cb * DI_ + ch] = cum;
}

// ---------------------------------------------------------------------------
// fixC: per chunk cnk>=1, recompute carry-in (serial over cnk chunk summaries,
// parallel across blocks), then y[t] += C_t . (h_in * exp(A*cum_t))  -- fully
// parallel over t (no recurrence).
// grid (32 chgrp, NC_-1, 2), block 256
// ---------------------------------------------------------------------------
__global__ void __launch_bounds__(256) fixC_k(
        const float* __restrict__ DELTA /*=cum*/, const float* __restrict__ BCM,
        const float* __restrict__ A_log, const float* __restrict__ hpart,
        const float* __restrict__ dsum, float* __restrict__ Y, int blk) {
    int d = blockIdx.z, cnk = blockIdx.y + 1;
    int chunit0 = blockIdx.x * 16;
    int chl = threadIdx.x >> 4, n = threadIdx.x & 15;
    int b = chunit0 >> 8, ch0 = chunit0 & 255;
    int ch = ch0 + chl;
    int t0 = cnk * CL_;
    int nt = L_ - t0 < CL_ ? L_ - t0 : CL_;

    __shared__ float cum_s[CL_][16];
    __shared__ float c_s[CL_][16];

    size_t rowbase = (size_t)d * RL_ + (size_t)b * L_ + t0;
    for (int idx = threadIdx.x; idx < CL_ * 16; idx += 256) {
        int t = idx >> 4, c = idx & 15;
        float cv = 0.f, Cv = 0.f;
        if (t < nt) {
            cv = DELTA[(rowbase + t) * DI_ + ch0 + c];
            Cv = BCM[(rowbase + t) * 32 + 16 + c];
        }
        cum_s[t][c] = cv; c_s[t][c] = Cv;
    }

    float A = -__expf(A_log[((size_t)(d * NBLK_ + blk) * DI_ + ch) * DS_ + n]);
    // carry-in: scan over preceding chunk summaries
    float h = 0.f;
    size_t cbb = (size_t)(d * B_ + b) * NC_;
    for (int c = 0; c < cnk; ++c) {
        float hp = hpart[(cbb + c) * (DI_ * DS_) + ch * DS_ + n];
        float ds = dsum[(cbb + c) * DI_ + ch];
        h = __expf(A * ds) * h + hp;
    }
    __syncthreads();

    for (int t = 0; t < nt; ++t) {
        float corr = c_s[t][n] * h * __expf(A * cum_s[t][chl]);
        corr += __shfl_xor(corr, 1);
        corr += __shfl_xor(corr, 2);
        corr += __shfl_xor(corr, 4);
        corr += __shfl_xor(corr, 8);
        if (n == 0) Y[(rowbase + t) * DI_ + ch] += corr;
    }
}

// ---------------------------------------------------------------------------
// gate + out_proj GEMM (+ optional residual-in); rows-tile 16, packed opTp
// grid (251, 2), block 256
// ---------------------------------------------------------------------------
__global__ void __launch_bounds__(256) gate4_k(
        const float* __restrict__ Y, const float* __restrict__ XC,
        const float* __restrict__ XZ, const float* __restrict__ Dsk,
        const float* __restrict__ opTp, const float* __restrict__ resid_in,
        float* __restrict__ outp, int blk) {
    int rt = blockIdx.x, d = blockIdx.y;
    int tid = threadIdx.x;
    size_t rbase = (size_t)rt * 16;
    int db = d * NBLK_ + blk;

    __shared__ float yg[16][264];

    {
        int c = tid;
        float Dc = Dsk[(size_t)db * DI_ + c];
        #pragma unroll 4
        for (int r = 0; r < 16; ++r) {
            size_t ri = (size_t)d * RL_ + rbase + r;
            float z = XZ[ri * (2 * DI_) + DI_ + c];
            yg[r][c] = (Y[ri * DI_ + c] + XC[ri * DI_ + c] * Dc) * silu_f(z);
        }
    }
    __syncthreads();

    int o = tid & 127, rh = tid >> 7;
    float acc[8];
    #pragma unroll
    for (int i = 0; i < 8; ++i) acc[i] = 0.f;
    const float4* W4 = (const float4*)(opTp + (size_t)db * 32768);

    for (int cq = 0; cq < 64; ++cq) {
        float4 w = W4[cq * 128 + o];
        #pragma unroll
        for (int rr = 0; rr < 8; ++rr)
            acc[rr] += dot4(*(const float4*)&yg[rh * 8 + rr][cq * 4], w);
    }
    for (int rr = 0; rr < 8; ++rr) {
        size_t row = rbase + rh * 8 + rr;
        size_t ri = (size_t)d * RL_ + row;
        float v = acc[rr];
        if (resid_in) v += resid_in[ri * F_ + o];
        outp[ri * F_ + o] = v;
    }
}

// ---------------------------------------------------------------------------
// combine with LDS transpose for coalesced (b,o,l) writes
// grid (32 l-tiles, B), block 256
// ---------------------------------------------------------------------------
__global__ void combine2_k(const float* __restrict__ cur, const float* __restrict__ res1,
                           float* __restrict__ out) {
    int l0 = blockIdx.x * 64, b = blockIdx.y;
    int tid = threadIdx.x;
    __shared__ float s[64][129];
    for (int idx = tid; idx < 64 * 128; idx += 256) {
        int ll = idx >> 7, o = idx & 127;
        int l = l0 + ll;
        if (l < L_) {
            size_t rf = ((size_t)b * L_ + l) * F_ + o;
            size_t rb = (RL_ + (size_t)b * L_ + (L_ - 1 - l)) * F_ + o;
            s[ll][o] = cur[rf] + res1[rf] + cur[rb] + res1[rb];
        }
    }
    __syncthreads();
    for (int idx = tid; idx < 64 * 128; idx += 256) {
        int o = idx >> 6, ll = idx & 63;
        int l = l0 + ll;
        if (l < L_) out[((size_t)b * F_ + o) * L_ + l] = s[ll][o];
    }
}

// ---------------------------------------------------------------------------
extern "C" void kernel_launch(void* const* d_in, const int* in_sizes, int n_in,
                              void* d_out, int out_size, void* d_ws, size_t ws_size,
                              hipStream_t stream) {
    const float* x        = (const float*)d_in[0];
    const float* skip     = (const float*)d_in[1];
    const float* convT_w  = (const float*)d_in[4];
    const float* convT_b  = (const float*)d_in[5];
    const float* fuse_w   = (const float*)d_in[6];
    const float* fuse_b   = (const float*)d_in[7];
    const float* norm_w   = (const float*)d_in[8];
    const float* norm_b   = (const float*)d_in[9];
    const float* in_proj  = (const float*)d_in[10];
    const float* conv_w   = (const float*)d_in[11];
    const float* conv_b   = (const float*)d_in[12];
    const float* x_proj   = (const float*)d_in[13];
    const float* dt_projw = (const float*)d_in[14];
    const float* dt_projb = (const float*)d_in[15];
    const float* A_log    = (const float*)d_in[16];
    const float* D_skip   = (const float*)d_in[17];
    const float* out_proj = (const float*)d_in[18];
    float* out = (float*)d_out;

    float* w = (float*)d_ws;
    size_t off = 0;
    auto alloc = [&](size_t n) { float* p = w + off; off += n; return p; };
    float* hT      = alloc((size_t)B_ * L_ * F_);       // 514048 (dead after fuse)
    float* W2p     = alloc(524288);                     // dead after convt4
    float* fwTp    = alloc(32768);
    float* ipTp    = alloc(262144);
    float* opTp    = alloc(262144);
    float* xpTp    = alloc(65536);
    float* xs      = alloc(2 * RL_ * F_);
    float* cur     = alloc(2 * RL_ * F_);
    float* res1    = alloc(2 * RL_ * F_);
    float* xz      = alloc(2 * RL_ * (2 * DI_));
    float* xc      = alloc(2 * RL_ * DI_);
    float* dl      = alloc(2 * RL_ * DI_);
    float* bcm     = alloc(2 * RL_ * 32);
    float* yb      = alloc(2 * RL_ * DI_);
    // scan chunk summaries alias hT+W2p (dead by scan time): 557056 <= 1038336
    float* hp   = hT;                 // 2*2*32*4096 = 524288
    float* dsum = hT + 524288;        // 2*2*32*256  = 32768
    (void)ws_size; (void)in_sizes; (void)n_in; (void)out_size;

    prep_k<<<(PREP_N + 255) / 256, 256, 0, stream>>>(convT_w, fuse_w, in_proj, out_proj,
                                                     x_proj, W2p, fwTp, ipTp, opTp, xpTp);
    convt4_k<<<dim3(63, 4, 2), 256, 0, stream>>>(x, W2p, convT_b, hT);
    fuse4_k<<<dim3(251, 2), 256, 0, stream>>>(skip, hT, fwTp, fuse_b, xs);

    for (int blk = 0; blk < NBLK_; ++blk) {
        const float* Xin = (blk == 0) ? xs : res1;
        ln4_k<<<dim3(126, 4, 2), 256, 0, stream>>>(Xin, norm_w, norm_b, ipTp, xz, blk);
        dwxdt_k<<<dim3(251, 2), 256, 0, stream>>>(xz, conv_w, conv_b, xpTp,
                                                  dt_projw, dt_projb, xc, bcm, dl, blk);
        scanA_k<<<dim3(32, NC_, 2), 256, 0, stream>>>(dl, xc, bcm, A_log, yb, hp, dsum, blk);
        fixC_k<<<dim3(32, NC_ - 1, 2), 256, 0, stream>>>(dl, bcm, A_log, hp, dsum, yb, blk);
        if (blk == 0)
            gate4_k<<<dim3(251, 2), 256, 0, stream>>>(yb, xc, xz, D_skip, opTp, xs, res1, 0);
        else
            gate4_k<<<dim3(251, 2), 256, 0, stream>>>(yb, xc, xz, D_skip, opTp, nullptr, cur, 1);
    }

    combine2_k<<<dim3(32, 2), 256, 0, stream>>>(cur, res1, out);
}

// Round 5
// 454.216 us; speedup vs baseline: 5.5723x; 1.0866x over previous
//
#include <hip/hip_runtime.h>
#include <hip/hip_bf16.h>
#include <math.h>

// Problem constants
#define B_    2
#define FIN_  256
#define LIN_  250
#define F_    128      // F_OUT
#define K_    16       // KSIZE
#define ST_   8        // STRIDE
#define L_    2008     // L_OUT
#define DI_   256      // D_INNER
#define DS_   16       // D_STATE
#define RK_   8        // DT_RANK
#define CV_   4        // D_CONV
#define NBLK_ 2
#define NC_   32       // scan chunks
#define CL_   63       // chunk length (32*63 = 2016 >= 2008)
#define RL_   ((size_t)B_ * L_)   // rows per direction = 4016

__device__ __forceinline__ float silu_f(float x) {
    return x / (1.f + __expf(-x));
}
__device__ __forceinline__ float softplus_f(float x) {
    return (x > 20.f) ? x : log1pf(__expf(x));
}
__device__ __forceinline__ float dot4(float4 a, float4 b) {
    return a.x * b.x + a.y * b.y + a.z * b.z + a.w * b.w;
}

// ---------------------------------------------------------------------------
// prep: packed transposed weights, each as [c/4][out][4] so a thread's 4-c
// weight bundle is ONE coalesced dwordx4.
// ---------------------------------------------------------------------------
#define PREP_N (524288 + 32768 + 262144 + 262144 + 65536)
__global__ void prep_k(const float* __restrict__ convT_w, const float* __restrict__ fuse_w,
                       const float* __restrict__ in_proj, const float* __restrict__ out_proj,
                       const float* __restrict__ x_proj,
                       float* __restrict__ W2p, float* __restrict__ fwTp,
                       float* __restrict__ ipTp, float* __restrict__ opTp,
                       float* __restrict__ xpTp) {
    size_t g = (size_t)blockIdx.x * 256 + threadIdx.x;
    if (g >= PREP_N) return;
    if (g < 524288) {
        int ccq = g >> 12, rr = g & 4095;
        int po = rr >> 2, i = rr & 3;
        int cc = ccq * 4 + i;
        int p = po >> 7, o = po & 127;
        int c = cc & 255, k = (cc < 256) ? p : p + 8;
        W2p[g] = convT_w[(size_t)c * 2048 + o * 16 + k];
        return;
    }
    g -= 524288;
    if (g < 32768) {
        int cq = g >> 9, rr = g & 511;
        int o = rr >> 2, i = rr & 3;
        fwTp[g] = fuse_w[(size_t)o * 256 + cq * 4 + i];
        return;
    }
    g -= 32768;
    if (g < 262144) {
        int db = g >> 16, r = g & 65535;
        int cq = r >> 11, rr = r & 2047;
        int e = rr >> 2, i = rr & 3;
        ipTp[g] = in_proj[(size_t)db * 65536 + e * 128 + cq * 4 + i];
        return;
    }
    g -= 262144;
    if (g < 262144) {
        int db = g >> 15, r = g & 32767;
        int cq = r >> 9, rr = r & 511;
        int o = rr >> 2, i = rr & 3;
        opTp[g] = out_proj[(size_t)db * 32768 + o * 256 + cq * 4 + i];
        return;
    }
    g -= 262144;
    {
        int db = g >> 14, r = g & 16383;
        int cq = r >> 8, rr = r & 255;
        int e = rr >> 2, i = rr & 3;
        xpTp[g] = (e < 40) ? x_proj[(size_t)db * 10240 + e * 256 + cq * 4 + i] : 0.f;
    }
}

// ---------------------------------------------------------------------------
// convT+silu GEMM. grid (63 jt of 4, 4 nt, B), block 256. Output hT[b][t][o].
// ---------------------------------------------------------------------------
__global__ void __launch_bounds__(256) convt4_k(
        const float* __restrict__ x, const float* __restrict__ W2p,
        const float* __restrict__ bias, float* __restrict__ hT) {
    int j0 = blockIdx.x * 4, nt = blockIdx.y, b = blockIdx.z;
    int po = nt * 256 + threadIdx.x;
    int p = po >> 7, o = po & 127;

    __shared__ float xr[5][264];   // rows j0-1 .. j0+3

    for (int idx = threadIdx.x; idx < 5 * 256; idx += 256) {
        int i = idx >> 8, c = idx & 255;
        int j = j0 - 1 + i;
        xr[i][c] = (j >= 0 && j < LIN_) ? x[((size_t)b * FIN_ + c) * LIN_ + j] : 0.f;
    }
    __syncthreads();

    float acc[4] = {0.f, 0.f, 0.f, 0.f};
    const float4* W4 = (const float4*)W2p;

    for (int ccq = 0; ccq < 64; ++ccq) {
        float4 w1 = W4[(size_t)ccq * 1024 + po];
        float4 w2 = W4[(size_t)(ccq + 64) * 1024 + po];
        float4 xv[5];
        #pragma unroll
        for (int i = 0; i < 5; ++i) xv[i] = *(const float4*)&xr[i][ccq * 4];
        #pragma unroll
        for (int jj = 0; jj < 4; ++jj)
            acc[jj] += dot4(xv[jj + 1], w1) + dot4(xv[jj], w2);
    }
    float bo = bias[o];
    #pragma unroll
    for (int jj = 0; jj < 4; ++jj) {
        int j = j0 + jj;
        if (j <= 250) {
            int t = 8 * j + p;
            hT[((size_t)b * L_ + t) * F_ + o] = silu_f(acc[jj] + bo);
        }
    }
}

// ---------------------------------------------------------------------------
// fuse = silu(fuse_w @ [skip; h] + b); writes xs fwd + flipped bwd.
// grid (251 l-tiles of 8, B), block 256
// ---------------------------------------------------------------------------
__global__ void __launch_bounds__(256) fuse4_k(
        const float* __restrict__ skip, const float* __restrict__ hT,
        const float* __restrict__ fwTp, const float* __restrict__ fb,
        float* __restrict__ xs) {
    int l0 = blockIdx.x * 8, b = blockIdx.y;
    int tid = threadIdx.x;

    __shared__ float ss[8][264];

    for (int idx = tid; idx < 128 * 8; idx += 256) {   // skip part (c<128)
        int c = idx >> 3, ll = idx & 7;
        ss[ll][c] = skip[((size_t)b * F_ + c) * L_ + l0 + ll];
    }
    for (int idx = tid; idx < 8 * 128; idx += 256) {   // h part (c>=128)
        int ll = idx >> 7, c = idx & 127;
        ss[ll][128 + c] = hT[((size_t)b * L_ + l0 + ll) * F_ + c];
    }
    __syncthreads();

    int o = tid & 127, lh = tid >> 7;
    float acc[4] = {0.f, 0.f, 0.f, 0.f};
    const float4* W4 = (const float4*)fwTp;

    for (int cq = 0; cq < 64; ++cq) {
        float4 w = W4[cq * 128 + o];
        #pragma unroll
        for (int rr = 0; rr < 4; ++rr)
            acc[rr] += dot4(*(const float4*)&ss[lh * 4 + rr][cq * 4], w);
    }
    float bo = fb[o];
    #pragma unroll
    for (int rr = 0; rr < 4; ++rr) {
        int l = l0 + lh * 4 + rr;
        float v = silu_f(acc[rr] + bo);
        xs[((size_t)b * L_ + l) * F_ + o] = v;
        xs[(RL_ + (size_t)b * L_ + (L_ - 1 - l)) * F_ + o] = v;
    }
}

// ---------------------------------------------------------------------------
// LayerNorm + in_proj GEMM, packed weights. grid (126, 4 nt, 2 d), block 256
// ---------------------------------------------------------------------------
__global__ void __launch_bounds__(256) ln4_k(
        const float* __restrict__ X, const float* __restrict__ nw,
        const float* __restrict__ nb_, const float* __restrict__ ipTp,
        float* __restrict__ XZ, int blk) {
    int rt = blockIdx.x, nt = blockIdx.y, d = blockIdx.z;
    int n0 = nt * 128;
    size_t rbase = (size_t)rt * 32;
    int tid = threadIdx.x, lane = tid & 63, wid = tid >> 6;
    int db = d * NBLK_ + blk;

    __shared__ float us[32][132];

    int wi0 = db * F_;
    for (int rr = 0; rr < 8; ++rr) {
        int r = wid * 8 + rr;
        size_t row = rbase + r;
        float2 v = make_float2(0.f, 0.f);
        if (row < RL_)
            v = *(const float2*)(X + ((size_t)d * RL_ + row) * F_ + lane * 2);
        float s1 = v.x + v.y, s2 = v.x * v.x + v.y * v.y;
        for (int off = 32; off; off >>= 1) {
            s1 += __shfl_xor(s1, off);
            s2 += __shfl_xor(s2, off);
        }
        float mu = s1 * (1.f / F_);
        float var = s2 * (1.f / F_) - mu * mu;
        float rstd = rsqrtf(var + 1e-5f);
        int c = lane * 2;
        us[r][c]     = (v.x - mu) * rstd * nw[wi0 + c]     + nb_[wi0 + c];
        us[r][c + 1] = (v.y - mu) * rstd * nw[wi0 + c + 1] + nb_[wi0 + c + 1];
    }
    __syncthreads();

    int o = tid & 127, rh = tid >> 7;
    float acc[16];
    #pragma unroll
    for (int i = 0; i < 16; ++i) acc[i] = 0.f;
    const float4* W4 = (const float4*)(ipTp + (size_t)db * 65536);

    for (int cq = 0; cq < 32; ++cq) {
        float4 w = W4[cq * 512 + n0 + o];
        #pragma unroll
        for (int rr = 0; rr < 16; ++rr)
            acc[rr] += dot4(*(const float4*)&us[rh * 16 + rr][cq * 4], w);
    }
    for (int rr = 0; rr < 16; ++rr) {
        size_t row = rbase + rh * 16 + rr;
        if (row < RL_)
            XZ[((size_t)d * RL_ + row) * (2 * DI_) + n0 + o] = acc[rr];
    }
}

// ---------------------------------------------------------------------------
// fused depthwise conv(4)+silu -> xc, then x_proj(40)+dt_proj(256)+softplus
// rows-tile 16; grid (251, 2), block 256
// ---------------------------------------------------------------------------
__global__ void __launch_bounds__(256) dwxdt_k(
        const float* __restrict__ XZ, const float* __restrict__ cw,
        const float* __restrict__ cb, const float* __restrict__ xpTp,
        const float* __restrict__ dtw, const float* __restrict__ dtb,
        float* __restrict__ XC, float* __restrict__ BCM,
        float* __restrict__ DELTA, int blk) {
    int rt = blockIdx.x, d = blockIdx.y;
    int tid = threadIdx.x;
    size_t rbase = (size_t)rt * 16;
    int db = d * NBLK_ + blk;

    __shared__ float xzs[19][264];   // rows rbase-3 .. rbase+15, first half of XZ
    __shared__ float xcs[16][264];
    __shared__ float dts[16][8];

    for (int idx = tid; idx < 19 * 256; idx += 256) {
        int s = idx >> 8;
        int c = idx & 255;
        long g = (long)rbase - 3 + s;
        xzs[s][c] = (g >= 0) ? XZ[((size_t)d * RL_ + g) * (2 * DI_) + c] : 0.f;
    }
    __syncthreads();

    // depthwise conv: thread's channel is fixed (ch = tid)
    {
        int ch = tid;
        int wi = db * DI_ + ch;
        float w0 = cw[(size_t)wi * CV_ + 0], w1 = cw[(size_t)wi * CV_ + 1];
        float w2 = cw[(size_t)wi * CV_ + 2], w3 = cw[(size_t)wi * CV_ + 3];
        float bias = cb[wi];
        #pragma unroll 4
        for (int r = 0; r < 16; ++r) {
            size_t row = rbase + r;
            int b = (row >= L_) ? 1 : 0;
            int l = (int)(row - (size_t)b * L_);
            int s = r + 3;
            float acc = bias + xzs[s][ch] * w3;
            if (l - 1 >= 0) acc += xzs[s - 1][ch] * w2;
            if (l - 2 >= 0) acc += xzs[s - 2][ch] * w1;
            if (l - 3 >= 0) acc += xzs[s - 3][ch] * w0;
            float v = silu_f(acc);
            xcs[r][ch] = v;
            XC[((size_t)d * RL_ + row) * DI_ + ch] = v;
        }
    }
    __syncthreads();

    // x_proj: e = tid&63 (e<40 active), rg = tid>>6 covers 4 rows each
    {
        int e = tid & 63, rg = tid >> 6;
        float acc[4] = {0.f, 0.f, 0.f, 0.f};
        const float4* W4 = (const float4*)(xpTp + (size_t)db * 16384);
        for (int cq = 0; cq < 64; ++cq) {
            float4 w = W4[cq * 64 + e];
            #pragma unroll
            for (int rr = 0; rr < 4; ++rr)
                acc[rr] += dot4(*(const float4*)&xcs[rg * 4 + rr][cq * 4], w);
        }
        if (e < RK_) {
            #pragma unroll
            for (int rr = 0; rr < 4; ++rr) dts[rg * 4 + rr][e] = acc[rr];
        } else if (e < RK_ + 2 * DS_) {
            #pragma unroll
            for (int rr = 0; rr < 4; ++rr) {
                size_t row = rbase + rg * 4 + rr;
                BCM[((size_t)d * RL_ + row) * 32 + (e - RK_)] = acc[rr];
            }
        }
    }
    __syncthreads();

    // dt_proj + softplus
    {
        int ch = tid;
        int wi = db * DI_ + ch;
        float dwv[RK_];
        #pragma unroll
        for (int k = 0; k < RK_; ++k) dwv[k] = dtw[(size_t)wi * RK_ + k];
        float bias = dtb[wi];
        #pragma unroll 4
        for (int rr = 0; rr < 16; ++rr) {
            size_t row = rbase + rr;
            float acc = bias;
            #pragma unroll
            for (int k = 0; k < RK_; ++k) acc += dts[rr][k] * dwv[k];
            DELTA[((size_t)d * RL_ + row) * DI_ + ch] = softplus_f(acc);
        }
    }
}

// ---------------------------------------------------------------------------
// scanA: LDS-staged chunk-local scan. Emits local y, inclusive cum(dt)
// (overwrites DELTA), chunk-final hpart and dtsum.
// grid (32 chgrp, NC_, 2), block 256 = 16 chl x 16 n
// ---------------------------------------------------------------------------
__global__ void __launch_bounds__(256) scanA_k(
        float* __restrict__ DELTA, const float* __restrict__ XC,
        const float* __restrict__ BCM, const float* __restrict__ A_log,
        float* __restrict__ Y, float* __restrict__ hpart,
        float* __restrict__ dsum, int blk) {
    int d = blockIdx.z, cnk = blockIdx.y;
    int chunit0 = blockIdx.x * 16;
    int chl = threadIdx.x >> 4, n = threadIdx.x & 15;
    int b = chunit0 >> 8, ch0 = chunit0 & 255;
    int ch = ch0 + chl;
    int t0 = cnk * CL_;
    int nt = L_ - t0 < CL_ ? L_ - t0 : CL_;

    __shared__ float dt_s[CL_][16];
    __shared__ float u_s[CL_][16];
    __shared__ float bc_s[CL_][32];

    size_t rowbase = (size_t)d * RL_ + (size_t)b * L_ + t0;
    for (int idx = threadIdx.x; idx < CL_ * 16; idx += 256) {
        int t = idx >> 4, c = idx & 15;
        float dv = 0.f, uv = 0.f;
        if (t < nt) {
            dv = DELTA[(rowbase + t) * DI_ + ch0 + c];
            uv = XC[(rowbase + t) * DI_ + ch0 + c];
        }
        dt_s[t][c] = dv; u_s[t][c] = uv;
    }
    for (int idx = threadIdx.x; idx < CL_ * 32; idx += 256) {
        int t = idx >> 5, m = idx & 31;
        bc_s[t][m] = (t < nt) ? BCM[(rowbase + t) * 32 + m] : 0.f;
    }
    __syncthreads();

    float A = -__expf(A_log[((size_t)(d * NBLK_ + blk) * DI_ + ch) * DS_ + n]);
    float h = 0.f, cum = 0.f;
    for (int t = 0; t < nt; ++t) {
        float dt = dt_s[t][chl];
        float u  = u_s[t][chl];
        float Bt = bc_s[t][n];
        float Ct = bc_s[t][16 + n];
        cum += dt;
        h = __expf(dt * A) * h + dt * u * Bt;
        float yp = h * Ct;
        yp += __shfl_xor(yp, 1);
        yp += __shfl_xor(yp, 2);
        yp += __shfl_xor(yp, 4);
        yp += __shfl_xor(yp, 8);
        if (n == 0) {
            Y[(rowbase + t) * DI_ + ch] = yp;
            DELTA[(rowbase + t) * DI_ + ch] = cum;   // inclusive prefix of dt
        }
    }
    size_t cb = (size_t)(d * B_ + b) * NC_ + cnk;
    hpart[cb * (DI_ * DS_) + ch * DS_ + n] = h;
    if (n == 0) dsum[cb * DI_ + ch] = cum;
}

// ---------------------------------------------------------------------------
// scanB: cross-chunk scan of summaries, in-place (hpart -> carry-in per chunk).
// The exp factors are independent of the chain; only a 32-FMA chain remains.
// grid (32, 2), block 256
// ---------------------------------------------------------------------------
__global__ void scanB_k(float* __restrict__ hpart, const float* __restrict__ dsum,
                        const float* __restrict__ A_log, int blk) {
    int d = blockIdx.y;
    int idx = blockIdx.x * 256 + threadIdx.x;   // (b, ch, n)
    int b = idx >> 12, ch = (idx >> 4) & 255, n = idx & 15;
    float A = -__expf(A_log[((size_t)(d * NBLK_ + blk) * DI_ + ch) * DS_ + n]);
    float h = 0.f;
    for (int c = 0; c < NC_; ++c) {
        size_t cb = (size_t)(d * B_ + b) * NC_ + c;
        size_t hi = cb * (DI_ * DS_) + ch * DS_ + n;
        float hc = hpart[hi];
        hpart[hi] = h;                       // carry-in for chunk c
        h = __expf(A * dsum[cb * DI_ + ch]) * h + hc;
    }
}

// ---------------------------------------------------------------------------
// fixD: y[t] += sum_n C[t][n] * hin[n] * exp(A[n]*cum[t]) — register-local
// 16-FMA per (row,ch); no shfl, no divergent writes. A[n], hin[n] in regs.
// grid (32 chgrp, NC_-1, 2), block 256 = 16 chl x 16 tg (4 t each)
// ---------------------------------------------------------------------------
__global__ void __launch_bounds__(256) fixD_k(
        const float* __restrict__ DELTA /*=cum*/, const float* __restrict__ BCM,
        const float* __restrict__ A_log, const float* __restrict__ hcarry,
        float* __restrict__ Y, int blk) {
    int d = blockIdx.z, cnk = blockIdx.y + 1;
    int chunit0 = blockIdx.x * 16;
    int b = chunit0 >> 8, ch0 = chunit0 & 255;
    int chl = threadIdx.x & 15, tg = threadIdx.x >> 4;
    int ch = ch0 + chl;
    int t0 = cnk * CL_;
    int nt = L_ - t0 < CL_ ? L_ - t0 : CL_;

    __shared__ float cum_s[CL_][17];
    __shared__ float c_s[CL_][17];
    __shared__ float hin_s[16][16];

    size_t rowbase = (size_t)d * RL_ + (size_t)b * L_ + t0;
    for (int idx = threadIdx.x; idx < CL_ * 16; idx += 256) {
        int t = idx >> 4, c = idx & 15;
        float cv = 0.f, Cv = 0.f;
        if (t < nt) {
            cv = DELTA[(rowbase + t) * DI_ + ch0 + c];
            Cv = BCM[(rowbase + t) * 32 + 16 + c];
        }
        cum_s[t][c] = cv; c_s[t][c] = Cv;
    }
    {
        size_t cb = ((size_t)(d * B_ + b) * NC_ + cnk) * (DI_ * DS_);
        int cl = threadIdx.x >> 4, n = threadIdx.x & 15;
        hin_s[cl][n] = hcarry[cb + (ch0 + cl) * DS_ + n];
    }
    __syncthreads();

    float An[16], Kn[16];
    const float* Ab = A_log + ((size_t)(d * NBLK_ + blk) * DI_ + ch) * DS_;
    #pragma unroll
    for (int n = 0; n < 16; ++n) {
        An[n] = -__expf(Ab[n]);
        Kn[n] = hin_s[chl][n];
    }
    #pragma unroll
    for (int tt = 0; tt < 4; ++tt) {
        int t = tg * 4 + tt;
        if (t < nt) {
            float cum = cum_s[t][chl];
            float corr = 0.f;
            #pragma unroll
            for (int n = 0; n < 16; ++n)
                corr += c_s[t][n] * Kn[n] * __expf(An[n] * cum);
            Y[(rowbase + t) * DI_ + ch] += corr;
        }
    }
}

// ---------------------------------------------------------------------------
// gate + out_proj GEMM (+ optional residual-in); rows-tile 16, packed opTp
// grid (251, 2), block 256
// ---------------------------------------------------------------------------
__global__ void __launch_bounds__(256) gate4_k(
        const float* __restrict__ Y, const float* __restrict__ XC,
        const float* __restrict__ XZ, const float* __restrict__ Dsk,
        const float* __restrict__ opTp, const float* __restrict__ resid_in,
        float* __restrict__ outp, int blk) {
    int rt = blockIdx.x, d = blockIdx.y;
    int tid = threadIdx.x;
    size_t rbase = (size_t)rt * 16;
    int db = d * NBLK_ + blk;

    __shared__ float yg[16][264];

    {
        int c = tid;
        float Dc = Dsk[(size_t)db * DI_ + c];
        #pragma unroll 4
        for (int r = 0; r < 16; ++r) {
            size_t ri = (size_t)d * RL_ + rbase + r;
            float z = XZ[ri * (2 * DI_) + DI_ + c];
            yg[r][c] = (Y[ri * DI_ + c] + XC[ri * DI_ + c] * Dc) * silu_f(z);
        }
    }
    __syncthreads();

    int o = tid & 127, rh = tid >> 7;
    float acc[8];
    #pragma unroll
    for (int i = 0; i < 8; ++i) acc[i] = 0.f;
    const float4* W4 = (const float4*)(opTp + (size_t)db * 32768);

    for (int cq = 0; cq < 64; ++cq) {
        float4 w = W4[cq * 128 + o];
        #pragma unroll
        for (int rr = 0; rr < 8; ++rr)
            acc[rr] += dot4(*(const float4*)&yg[rh * 8 + rr][cq * 4], w);
    }
    for (int rr = 0; rr < 8; ++rr) {
        size_t row = rbase + rh * 8 + rr;
        size_t ri = (size_t)d * RL_ + row;
        float v = acc[rr];
        if (resid_in) v += resid_in[ri * F_ + o];
        outp[ri * F_ + o] = v;
    }
}

// ---------------------------------------------------------------------------
// combine with LDS transpose for coalesced (b,o,l) writes
// grid (32 l-tiles, B), block 256
// ---------------------------------------------------------------------------
__global__ void combine2_k(const float* __restrict__ cur, const float* __restrict__ res1,
                           float* __restrict__ out) {
    int l0 = blockIdx.x * 64, b = blockIdx.y;
    int tid = threadIdx.x;
    __shared__ float s[64][129];
    for (int idx = tid; idx < 64 * 128; idx += 256) {
        int ll = idx >> 7, o = idx & 127;
        int l = l0 + ll;
        if (l < L_) {
            size_t rf = ((size_t)b * L_ + l) * F_ + o;
            size_t rb = (RL_ + (size_t)b * L_ + (L_ - 1 - l)) * F_ + o;
            s[ll][o] = cur[rf] + res1[rf] + cur[rb] + res1[rb];
        }
    }
    __syncthreads();
    for (int idx = tid; idx < 64 * 128; idx += 256) {
        int o = idx >> 6, ll = idx & 63;
        int l = l0 + ll;
        if (l < L_) out[((size_t)b * F_ + o) * L_ + l] = s[ll][o];
    }
}

// ---------------------------------------------------------------------------
extern "C" void kernel_launch(void* const* d_in, const int* in_sizes, int n_in,
                              void* d_out, int out_size, void* d_ws, size_t ws_size,
                              hipStream_t stream) {
    const float* x        = (const float*)d_in[0];
    const float* skip     = (const float*)d_in[1];
    const float* convT_w  = (const float*)d_in[4];
    const float* convT_b  = (const float*)d_in[5];
    const float* fuse_w   = (const float*)d_in[6];
    const float* fuse_b   = (const float*)d_in[7];
    const float* norm_w   = (const float*)d_in[8];
    const float* norm_b   = (const float*)d_in[9];
    const float* in_proj  = (const float*)d_in[10];
    const float* conv_w   = (const float*)d_in[11];
    const float* conv_b   = (const float*)d_in[12];
    const float* x_proj   = (const float*)d_in[13];
    const float* dt_projw = (const float*)d_in[14];
    const float* dt_projb = (const float*)d_in[15];
    const float* A_log    = (const float*)d_in[16];
    const float* D_skip   = (const float*)d_in[17];
    const float* out_proj = (const float*)d_in[18];
    float* out = (float*)d_out;

    float* w = (float*)d_ws;
    size_t off = 0;
    auto alloc = [&](size_t n) { float* p = w + off; off += n; return p; };
    float* hT      = alloc((size_t)B_ * L_ * F_);       // 514048 (dead after fuse)
    float* W2p     = alloc(524288);                     // dead after convt4
    float* fwTp    = alloc(32768);
    float* ipTp    = alloc(262144);
    float* opTp    = alloc(262144);
    float* xpTp    = alloc(65536);
    float* xs      = alloc(2 * RL_ * F_);
    float* cur     = alloc(2 * RL_ * F_);
    float* res1    = alloc(2 * RL_ * F_);
    float* xz      = alloc(2 * RL_ * (2 * DI_));
    float* xc      = alloc(2 * RL_ * DI_);
    float* dl      = alloc(2 * RL_ * DI_);
    float* bcm     = alloc(2 * RL_ * 32);
    float* yb      = alloc(2 * RL_ * DI_);
    // scan chunk summaries alias hT+W2p (dead by scan time): 557056 <= 1038336
    float* hp   = hT;                 // 2*2*32*4096 = 524288
    float* dsum = hT + 524288;        // 2*2*32*256  = 32768
    (void)ws_size; (void)in_sizes; (void)n_in; (void)out_size;

    prep_k<<<(PREP_N + 255) / 256, 256, 0, stream>>>(convT_w, fuse_w, in_proj, out_proj,
                                                     x_proj, W2p, fwTp, ipTp, opTp, xpTp);
    convt4_k<<<dim3(63, 4, 2), 256, 0, stream>>>(x, W2p, convT_b, hT);
    fuse4_k<<<dim3(251, 2), 256, 0, stream>>>(skip, hT, fwTp, fuse_b, xs);

    for (int blk = 0; blk < NBLK_; ++blk) {
        const float* Xin = (blk == 0) ? xs : res1;
        ln4_k<<<dim3(126, 4, 2), 256, 0, stream>>>(Xin, norm_w, norm_b, ipTp, xz, blk);
        dwxdt_k<<<dim3(251, 2), 256, 0, stream>>>(xz, conv_w, conv_b, xpTp,
                                                  dt_projw, dt_projb, xc, bcm, dl, blk);
        scanA_k<<<dim3(32, NC_, 2), 256, 0, stream>>>(dl, xc, bcm, A_log, yb, hp, dsum, blk);
        scanB_k<<<dim3(32, 2), 256, 0, stream>>>(hp, dsum, A_log, blk);
        fixD_k<<<dim3(32, NC_ - 1, 2), 256, 0, stream>>>(dl, bcm, A_log, hp, yb, blk);
        if (blk == 0)
            gate4_k<<<dim3(251, 2), 256, 0, stream>>>(yb, xc, xz, D_skip, opTp, xs, res1, 0);
        else
            gate4_k<<<dim3(251, 2), 256, 0, stream>>>(yb, xc, xz, D_skip, opTp, nullptr, cur, 1);
    }

    combine2_k<<<dim3(32, 2), 256, 0, stream>>>(cur, res1, out);
}

// Round 6
// 439.269 us; speedup vs baseline: 5.7619x; 1.0340x over previous
//
#include <hip/hip_runtime.h>
#include <hip/hip_bf16.h>
#include <math.h>

// Problem constants
#define B_    2
#define FIN_  256
#define LIN_  250
#define F_    128      // F_OUT
#define K_    16       // KSIZE
#define ST_   8        // STRIDE
#define L_    2008     // L_OUT
#define DI_   256      // D_INNER
#define DS_   16       // D_STATE
#define RK_   8        // DT_RANK
#define CV_   4        // D_CONV
#define NBLK_ 2
#define NC_   64       // scan chunks (chunk 63 is empty: writes identity summary)
#define CL_   32       // chunk length
#define RL_   ((size_t)B_ * L_)   // rows per direction = 4016

__device__ __forceinline__ float silu_f(float x) {
    return x / (1.f + __expf(-x));
}
__device__ __forceinline__ float softplus_f(float x) {
    return (x > 20.f) ? x : log1pf(__expf(x));
}
__device__ __forceinline__ float dot4(float4 a, float4 b) {
    return a.x * b.x + a.y * b.y + a.z * b.z + a.w * b.w;
}

// ---------------------------------------------------------------------------
// prep: packed transposed weights, each as [c/4][out][4] so a thread's 4-c
// weight bundle is ONE coalesced dwordx4.
// ---------------------------------------------------------------------------
#define PREP_N (524288 + 32768 + 262144 + 262144 + 65536)
__global__ void prep_k(const float* __restrict__ convT_w, const float* __restrict__ fuse_w,
                       const float* __restrict__ in_proj, const float* __restrict__ out_proj,
                       const float* __restrict__ x_proj,
                       float* __restrict__ W2p, float* __restrict__ fwTp,
                       float* __restrict__ ipTp, float* __restrict__ opTp,
                       float* __restrict__ xpTp) {
    size_t g = (size_t)blockIdx.x * 256 + threadIdx.x;
    if (g >= PREP_N) return;
    if (g < 524288) {
        int ccq = g >> 12, rr = g & 4095;
        int po = rr >> 2, i = rr & 3;
        int cc = ccq * 4 + i;
        int p = po >> 7, o = po & 127;
        int c = cc & 255, k = (cc < 256) ? p : p + 8;
        W2p[g] = convT_w[(size_t)c * 2048 + o * 16 + k];
        return;
    }
    g -= 524288;
    if (g < 32768) {
        int cq = g >> 9, rr = g & 511;
        int o = rr >> 2, i = rr & 3;
        fwTp[g] = fuse_w[(size_t)o * 256 + cq * 4 + i];
        return;
    }
    g -= 32768;
    if (g < 262144) {
        int db = g >> 16, r = g & 65535;
        int cq = r >> 11, rr = r & 2047;
        int e = rr >> 2, i = rr & 3;
        ipTp[g] = in_proj[(size_t)db * 65536 + e * 128 + cq * 4 + i];
        return;
    }
    g -= 262144;
    if (g < 262144) {
        int db = g >> 15, r = g & 32767;
        int cq = r >> 9, rr = r & 511;
        int o = rr >> 2, i = rr & 3;
        opTp[g] = out_proj[(size_t)db * 32768 + o * 256 + cq * 4 + i];
        return;
    }
    g -= 262144;
    {
        int db = g >> 14, r = g & 16383;
        int cq = r >> 8, rr = r & 255;
        int e = rr >> 2, i = rr & 3;
        xpTp[g] = (e < 40) ? x_proj[(size_t)db * 10240 + e * 256 + cq * 4 + i] : 0.f;
    }
}

// ---------------------------------------------------------------------------
// convT+silu GEMM, 2 outputs/thread. grid (63 jt of 4, 2 nt, B), block 256.
// outs: po = nt*512+tid and po+256 (same o, p and p+2). Output hT[b][t][o].
// ---------------------------------------------------------------------------
__global__ void __launch_bounds__(256) convt5_k(
        const float* __restrict__ x, const float* __restrict__ W2p,
        const float* __restrict__ bias, float* __restrict__ hT) {
    int j0 = blockIdx.x * 4, nt = blockIdx.y, b = blockIdx.z;
    int po = nt * 512 + threadIdx.x;
    int p = po >> 7, o = po & 127;

    __shared__ float xr[5][264];   // rows j0-1 .. j0+3

    for (int idx = threadIdx.x; idx < 5 * 256; idx += 256) {
        int i = idx >> 8, c = idx & 255;
        int j = j0 - 1 + i;
        xr[i][c] = (j >= 0 && j < LIN_) ? x[((size_t)b * FIN_ + c) * LIN_ + j] : 0.f;
    }
    __syncthreads();

    float acca[4] = {0.f, 0.f, 0.f, 0.f};
    float accb[4] = {0.f, 0.f, 0.f, 0.f};
    const float4* W4 = (const float4*)W2p;

    for (int ccq = 0; ccq < 64; ++ccq) {
        float4 wa1 = W4[(size_t)ccq * 1024 + po];
        float4 wb1 = W4[(size_t)ccq * 1024 + po + 256];
        float4 wa2 = W4[(size_t)(ccq + 64) * 1024 + po];
        float4 wb2 = W4[(size_t)(ccq + 64) * 1024 + po + 256];
        float4 xv[5];
        #pragma unroll
        for (int i = 0; i < 5; ++i) xv[i] = *(const float4*)&xr[i][ccq * 4];
        #pragma unroll
        for (int jj = 0; jj < 4; ++jj) {
            acca[jj] += dot4(xv[jj + 1], wa1) + dot4(xv[jj], wa2);
            accb[jj] += dot4(xv[jj + 1], wb1) + dot4(xv[jj], wb2);
        }
    }
    float bo = bias[o];
    #pragma unroll
    for (int jj = 0; jj < 4; ++jj) {
        int j = j0 + jj;
        if (j <= 250) {
            hT[((size_t)b * L_ + 8 * j + p) * F_ + o]     = silu_f(acca[jj] + bo);
            hT[((size_t)b * L_ + 8 * j + p + 2) * F_ + o] = silu_f(accb[jj] + bo);
        }
    }
}

// ---------------------------------------------------------------------------
// fuse = silu(fuse_w @ [skip; h] + b); 2 outs/thread; xs fwd + flipped bwd.
// grid (251 l-tiles of 8, B), block 256 (o2=tid&63, rg=tid>>6 -> 2 l each)
// ---------------------------------------------------------------------------
__global__ void __launch_bounds__(256) fuse5_k(
        const float* __restrict__ skip, const float* __restrict__ hT,
        const float* __restrict__ fwTp, const float* __restrict__ fb,
        float* __restrict__ xs) {
    int l0 = blockIdx.x * 8, b = blockIdx.y;
    int tid = threadIdx.x;

    __shared__ float ss[8][264];

    for (int idx = tid; idx < 128 * 8; idx += 256) {   // skip part (c<128)
        int c = idx >> 3, ll = idx & 7;
        ss[ll][c] = skip[((size_t)b * F_ + c) * L_ + l0 + ll];
    }
    for (int idx = tid; idx < 8 * 128; idx += 256) {   // h part (c>=128)
        int ll = idx >> 7, c = idx & 127;
        ss[ll][128 + c] = hT[((size_t)b * L_ + l0 + ll) * F_ + c];
    }
    __syncthreads();

    int o2 = tid & 63, rg = tid >> 6;
    float acca[2] = {0.f, 0.f}, accb[2] = {0.f, 0.f};
    const float4* W4 = (const float4*)fwTp;

    for (int cq = 0; cq < 64; ++cq) {
        float4 wa = W4[cq * 128 + o2];
        float4 wb = W4[cq * 128 + o2 + 64];
        #pragma unroll
        for (int rr = 0; rr < 2; ++rr) {
            float4 s = *(const float4*)&ss[rg * 2 + rr][cq * 4];
            acca[rr] += dot4(s, wa);
            accb[rr] += dot4(s, wb);
        }
    }
    float ba = fb[o2], bb = fb[o2 + 64];
    #pragma unroll
    for (int rr = 0; rr < 2; ++rr) {
        int l = l0 + rg * 2 + rr;
        float va = silu_f(acca[rr] + ba);
        float vb = silu_f(accb[rr] + bb);
        size_t rf = ((size_t)b * L_ + l) * F_;
        size_t rb = (RL_ + (size_t)b * L_ + (L_ - 1 - l)) * F_;
        xs[rf + o2] = va;       xs[rf + o2 + 64] = vb;
        xs[rb + o2] = va;       xs[rb + o2 + 64] = vb;
    }
}

// ---------------------------------------------------------------------------
// LayerNorm + in_proj GEMM, full N=512 per block (4 outs/thread).
// grid (251 row-tiles of 16, 2 dirs), block 256
// ---------------------------------------------------------------------------
__global__ void __launch_bounds__(256) ln5_k(
        const float* __restrict__ X, const float* __restrict__ nw,
        const float* __restrict__ nb_, const float* __restrict__ ipTp,
        float* __restrict__ XZ, int blk) {
    int rt = blockIdx.x, d = blockIdx.y;
    size_t rbase = (size_t)rt * 16;
    int tid = threadIdx.x, lane = tid & 63, wid = tid >> 6;
    int db = d * NBLK_ + blk;

    __shared__ float us[16][132];

    int wi0 = db * F_;
    #pragma unroll
    for (int rr = 0; rr < 4; ++rr) {
        int r = wid * 4 + rr;
        size_t row = rbase + r;
        float2 v = *(const float2*)(X + ((size_t)d * RL_ + row) * F_ + lane * 2);
        float s1 = v.x + v.y, s2 = v.x * v.x + v.y * v.y;
        for (int off = 32; off; off >>= 1) {
            s1 += __shfl_xor(s1, off);
            s2 += __shfl_xor(s2, off);
        }
        float mu = s1 * (1.f / F_);
        float var = s2 * (1.f / F_) - mu * mu;
        float rstd = rsqrtf(var + 1e-5f);
        int c = lane * 2;
        us[r][c]     = (v.x - mu) * rstd * nw[wi0 + c]     + nb_[wi0 + c];
        us[r][c + 1] = (v.y - mu) * rstd * nw[wi0 + c + 1] + nb_[wi0 + c + 1];
    }
    __syncthreads();

    int o = tid & 127, rh = tid >> 7;
    float acc0[8], acc1[8], acc2[8], acc3[8];
    #pragma unroll
    for (int i = 0; i < 8; ++i) { acc0[i] = acc1[i] = acc2[i] = acc3[i] = 0.f; }
    const float4* W4 = (const float4*)(ipTp + (size_t)db * 65536);

    for (int cq = 0; cq < 32; ++cq) {
        float4 w0 = W4[cq * 512 + o];
        float4 w1 = W4[cq * 512 + o + 128];
        float4 w2 = W4[cq * 512 + o + 256];
        float4 w3 = W4[cq * 512 + o + 384];
        #pragma unroll
        for (int rr = 0; rr < 8; ++rr) {
            float4 u = *(const float4*)&us[rh * 8 + rr][cq * 4];
            acc0[rr] += dot4(u, w0);
            acc1[rr] += dot4(u, w1);
            acc2[rr] += dot4(u, w2);
            acc3[rr] += dot4(u, w3);
        }
    }
    #pragma unroll
    for (int rr = 0; rr < 8; ++rr) {
        size_t row = rbase + rh * 8 + rr;
        float* dst = XZ + ((size_t)d * RL_ + row) * (2 * DI_);
        dst[o]       = acc0[rr];
        dst[o + 128] = acc1[rr];
        dst[o + 256] = acc2[rr];
        dst[o + 384] = acc3[rr];
    }
}

// ---------------------------------------------------------------------------
// fused depthwise conv(4)+silu -> xc, then x_proj(40)+dt_proj(256)+softplus
// rows-tile 16; grid (251, 2), block 256
// ---------------------------------------------------------------------------
__global__ void __launch_bounds__(256) dwxdt_k(
        const float* __restrict__ XZ, const float* __restrict__ cw,
        const float* __restrict__ cb, const float* __restrict__ xpTp,
        const float* __restrict__ dtw, const float* __restrict__ dtb,
        float* __restrict__ XC, float* __restrict__ BCM,
        float* __restrict__ DELTA, int blk) {
    int rt = blockIdx.x, d = blockIdx.y;
    int tid = threadIdx.x;
    size_t rbase = (size_t)rt * 16;
    int db = d * NBLK_ + blk;

    __shared__ float xzs[19][264];   // rows rbase-3 .. rbase+15, first half of XZ
    __shared__ float xcs[16][264];
    __shared__ float dts[16][8];

    for (int idx = tid; idx < 19 * 256; idx += 256) {
        int s = idx >> 8;
        int c = idx & 255;
        long g = (long)rbase - 3 + s;
        xzs[s][c] = (g >= 0) ? XZ[((size_t)d * RL_ + g) * (2 * DI_) + c] : 0.f;
    }
    __syncthreads();

    // depthwise conv: thread's channel is fixed (ch = tid)
    {
        int ch = tid;
        int wi = db * DI_ + ch;
        float w0 = cw[(size_t)wi * CV_ + 0], w1 = cw[(size_t)wi * CV_ + 1];
        float w2 = cw[(size_t)wi * CV_ + 2], w3 = cw[(size_t)wi * CV_ + 3];
        float bias = cb[wi];
        #pragma unroll 4
        for (int r = 0; r < 16; ++r) {
            size_t row = rbase + r;
            int b = (row >= L_) ? 1 : 0;
            int l = (int)(row - (size_t)b * L_);
            int s = r + 3;
            float acc = bias + xzs[s][ch] * w3;
            if (l - 1 >= 0) acc += xzs[s - 1][ch] * w2;
            if (l - 2 >= 0) acc += xzs[s - 2][ch] * w1;
            if (l - 3 >= 0) acc += xzs[s - 3][ch] * w0;
            float v = silu_f(acc);
            xcs[r][ch] = v;
            XC[((size_t)d * RL_ + row) * DI_ + ch] = v;
        }
    }
    __syncthreads();

    // x_proj: e = tid&63 (e<40 active), rg = tid>>6 covers 4 rows each
    {
        int e = tid & 63, rg = tid >> 6;
        float acc[4] = {0.f, 0.f, 0.f, 0.f};
        const float4* W4 = (const float4*)(xpTp + (size_t)db * 16384);
        for (int cq = 0; cq < 64; ++cq) {
            float4 w = W4[cq * 64 + e];
            #pragma unroll
            for (int rr = 0; rr < 4; ++rr)
                acc[rr] += dot4(*(const float4*)&xcs[rg * 4 + rr][cq * 4], w);
        }
        if (e < RK_) {
            #pragma unroll
            for (int rr = 0; rr < 4; ++rr) dts[rg * 4 + rr][e] = acc[rr];
        } else if (e < RK_ + 2 * DS_) {
            #pragma unroll
            for (int rr = 0; rr < 4; ++rr) {
                size_t row = rbase + rg * 4 + rr;
                BCM[((size_t)d * RL_ + row) * 32 + (e - RK_)] = acc[rr];
            }
        }
    }
    __syncthreads();

    // dt_proj + softplus
    {
        int ch = tid;
        int wi = db * DI_ + ch;
        float dwv[RK_];
        #pragma unroll
        for (int k = 0; k < RK_; ++k) dwv[k] = dtw[(size_t)wi * RK_ + k];
        float bias = dtb[wi];
        #pragma unroll 4
        for (int rr = 0; rr < 16; ++rr) {
            size_t row = rbase + rr;
            float acc = bias;
            #pragma unroll
            for (int k = 0; k < RK_; ++k) acc += dts[rr][k] * dwv[k];
            DELTA[((size_t)d * RL_ + row) * DI_ + ch] = softplus_f(acc);
        }
    }
}

// ---------------------------------------------------------------------------
// scanA: LDS-staged chunk-local scan (CL=32). Emits local y, inclusive cum(dt)
// (overwrites DELTA), chunk-final hpart and dtsum. Empty trailing chunk writes
// identity summary (h=0, dsum=0).
// grid (32 chgrp, NC_, 2), block 256 = 16 chl x 16 n
// ---------------------------------------------------------------------------
__global__ void __launch_bounds__(256) scanA_k(
        float* __restrict__ DELTA, const float* __restrict__ XC,
        const float* __restrict__ BCM, const float* __restrict__ A_log,
        float* __restrict__ Y, float* __restrict__ hpart,
        float* __restrict__ dsum, int blk) {
    int d = blockIdx.z, cnk = blockIdx.y;
    int chunit0 = blockIdx.x * 16;
    int chl = threadIdx.x >> 4, n = threadIdx.x & 15;
    int b = chunit0 >> 8, ch0 = chunit0 & 255;
    int ch = ch0 + chl;
    int t0 = cnk * CL_;
    int nt = L_ - t0; if (nt > CL_) nt = CL_;   // may be <= 0 (empty chunk)

    __shared__ float dt_s[CL_][16];
    __shared__ float u_s[CL_][16];
    __shared__ float bc_s[CL_][32];

    size_t rowbase = (size_t)d * RL_ + (size_t)b * L_ + t0;
    for (int idx = threadIdx.x; idx < CL_ * 16; idx += 256) {
        int t = idx >> 4, c = idx & 15;
        float dv = 0.f, uv = 0.f;
        if (t < nt) {
            dv = DELTA[(rowbase + t) * DI_ + ch0 + c];
            uv = XC[(rowbase + t) * DI_ + ch0 + c];
        }
        dt_s[t][c] = dv; u_s[t][c] = uv;
    }
    for (int idx = threadIdx.x; idx < CL_ * 32; idx += 256) {
        int t = idx >> 5, m = idx & 31;
        bc_s[t][m] = (t < nt) ? BCM[(rowbase + t) * 32 + m] : 0.f;
    }
    __syncthreads();

    float A = -__expf(A_log[((size_t)(d * NBLK_ + blk) * DI_ + ch) * DS_ + n]);
    float h = 0.f, cum = 0.f;
    for (int t = 0; t < nt; ++t) {
        float dt = dt_s[t][chl];
        float u  = u_s[t][chl];
        float Bt = bc_s[t][n];
        float Ct = bc_s[t][16 + n];
        cum += dt;
        h = __expf(dt * A) * h + dt * u * Bt;
        float yp = h * Ct;
        yp += __shfl_xor(yp, 1);
        yp += __shfl_xor(yp, 2);
        yp += __shfl_xor(yp, 4);
        yp += __shfl_xor(yp, 8);
        if (n == 0) {
            Y[(rowbase + t) * DI_ + ch] = yp;
            DELTA[(rowbase + t) * DI_ + ch] = cum;   // inclusive prefix of dt
        }
    }
    size_t cb = (size_t)(d * B_ + b) * NC_ + cnk;
    hpart[cb * (DI_ * DS_) + ch * DS_ + n] = h;
    if (n == 0) dsum[cb * DI_ + ch] = cum;
}

// ---------------------------------------------------------------------------
// scanB: cross-chunk scan of summaries, in-place (hpart -> carry-in per chunk).
// grid (32, 2), block 256
// ---------------------------------------------------------------------------
__global__ void scanB_k(float* __restrict__ hpart, const float* __restrict__ dsum,
                        const float* __restrict__ A_log, int blk) {
    int d = blockIdx.y;
    int idx = blockIdx.x * 256 + threadIdx.x;   // (b, ch, n)
    int b = idx >> 12, ch = (idx >> 4) & 255, n = idx & 15;
    float A = -__expf(A_log[((size_t)(d * NBLK_ + blk) * DI_ + ch) * DS_ + n]);
    float h = 0.f;
    for (int c = 0; c < NC_; ++c) {
        size_t cb = (size_t)(d * B_ + b) * NC_ + c;
        size_t hi = cb * (DI_ * DS_) + ch * DS_ + n;
        float hc = hpart[hi];
        hpart[hi] = h;                       // carry-in for chunk c
        h = __expf(A * dsum[cb * DI_ + ch]) * h + hc;
    }
}

// ---------------------------------------------------------------------------
// fixD: y[t] += sum_n C[t][n] * hin[n] * exp(A[n]*cum[t]) — register-local
// 16-FMA per (row,ch); no shfl, no divergent writes.
// grid (32 chgrp, NC_-1, 2), block 256 = 16 chl x 16 tg (2 t each)
// ---------------------------------------------------------------------------
__global__ void __launch_bounds__(256) fixD_k(
        const float* __restrict__ DELTA /*=cum*/, const float* __restrict__ BCM,
        const float* __restrict__ A_log, const float* __restrict__ hcarry,
        float* __restrict__ Y, int blk) {
    int d = blockIdx.z, cnk = blockIdx.y + 1;
    int chunit0 = blockIdx.x * 16;
    int b = chunit0 >> 8, ch0 = chunit0 & 255;
    int chl = threadIdx.x & 15, tg = threadIdx.x >> 4;
    int ch = ch0 + chl;
    int t0 = cnk * CL_;
    int nt = L_ - t0; if (nt > CL_) nt = CL_;   // may be <= 0 (empty chunk)

    __shared__ float cum_s[CL_][17];
    __shared__ float c_s[CL_][17];
    __shared__ float hin_s[16][16];

    size_t rowbase = (size_t)d * RL_ + (size_t)b * L_ + t0;
    for (int idx = threadIdx.x; idx < CL_ * 16; idx += 256) {
        int t = idx >> 4, c = idx & 15;
        float cv = 0.f, Cv = 0.f;
        if (t < nt) {
            cv = DELTA[(rowbase + t) * DI_ + ch0 + c];
            Cv = BCM[(rowbase + t) * 32 + 16 + c];
        }
        cum_s[t][c] = cv; c_s[t][c] = Cv;
    }
    {
        size_t cb = ((size_t)(d * B_ + b) * NC_ + cnk) * (DI_ * DS_);
        int cl = threadIdx.x >> 4, nn = threadIdx.x & 15;
        hin_s[cl][nn] = hcarry[cb + (ch0 + cl) * DS_ + nn];
    }
    __syncthreads();

    float An[16], Kn[16];
    const float* Ab = A_log + ((size_t)(d * NBLK_ + blk) * DI_ + ch) * DS_;
    #pragma unroll
    for (int n = 0; n < 16; ++n) {
        An[n] = -__expf(Ab[n]);
        Kn[n] = hin_s[chl][n];
    }
    #pragma unroll
    for (int tt = 0; tt < 2; ++tt) {
        int t = tg * 2 + tt;
        if (t < nt) {
            float cum = cum_s[t][chl];
            float corr = 0.f;
            #pragma unroll
            for (int n = 0; n < 16; ++n)
                corr += c_s[t][n] * Kn[n] * __expf(An[n] * cum);
            Y[(rowbase + t) * DI_ + ch] += corr;
        }
    }
}

// ---------------------------------------------------------------------------
// gate + out_proj GEMM (+ optional residual-in); 16 rows, 2 outs/thread.
// grid (251, 2), block 256 (o2=tid&63, rg=tid>>6 -> 4 rows each)
// ---------------------------------------------------------------------------
__global__ void __launch_bounds__(256) gate5_k(
        const float* __restrict__ Y, const float* __restrict__ XC,
        const float* __restrict__ XZ, const float* __restrict__ Dsk,
        const float* __restrict__ opTp, const float* __restrict__ resid_in,
        float* __restrict__ outp, int blk) {
    int rt = blockIdx.x, d = blockIdx.y;
    int tid = threadIdx.x;
    size_t rbase = (size_t)rt * 16;
    int db = d * NBLK_ + blk;

    __shared__ float yg[16][264];

    {
        int c = tid;
        float Dc = Dsk[(size_t)db * DI_ + c];
        #pragma unroll 4
        for (int r = 0; r < 16; ++r) {
            size_t ri = (size_t)d * RL_ + rbase + r;
            float z = XZ[ri * (2 * DI_) + DI_ + c];
            yg[r][c] = (Y[ri * DI_ + c] + XC[ri * DI_ + c] * Dc) * silu_f(z);
        }
    }
    __syncthreads();

    int o2 = tid & 63, rg = tid >> 6;
    float acca[4] = {0.f, 0.f, 0.f, 0.f};
    float accb[4] = {0.f, 0.f, 0.f, 0.f};
    const float4* W4 = (const float4*)(opTp + (size_t)db * 32768);

    for (int cq = 0; cq < 64; ++cq) {
        float4 wa = W4[cq * 128 + o2];
        float4 wb = W4[cq * 128 + o2 + 64];
        #pragma unroll
        for (int rr = 0; rr < 4; ++rr) {
            float4 u = *(const float4*)&yg[rg * 4 + rr][cq * 4];
            acca[rr] += dot4(u, wa);
            accb[rr] += dot4(u, wb);
        }
    }
    #pragma unroll
    for (int rr = 0; rr < 4; ++rr) {
        size_t ri = (size_t)d * RL_ + rbase + rg * 4 + rr;
        float va = acca[rr], vb = accb[rr];
        if (resid_in) {
            va += resid_in[ri * F_ + o2];
            vb += resid_in[ri * F_ + o2 + 64];
        }
        outp[ri * F_ + o2]      = va;
        outp[ri * F_ + o2 + 64] = vb;
    }
}

// ---------------------------------------------------------------------------
// combine with LDS transpose for coalesced (b,o,l) writes
// grid (32 l-tiles, B), block 256
// ---------------------------------------------------------------------------
__global__ void combine2_k(const float* __restrict__ cur, const float* __restrict__ res1,
                           float* __restrict__ out) {
    int l0 = blockIdx.x * 64, b = blockIdx.y;
    int tid = threadIdx.x;
    __shared__ float s[64][129];
    for (int idx = tid; idx < 64 * 128; idx += 256) {
        int ll = idx >> 7, o = idx & 127;
        int l = l0 + ll;
        if (l < L_) {
            size_t rf = ((size_t)b * L_ + l) * F_ + o;
            size_t rb = (RL_ + (size_t)b * L_ + (L_ - 1 - l)) * F_ + o;
            s[ll][o] = cur[rf] + res1[rf] + cur[rb] + res1[rb];
        }
    }
    __syncthreads();
    for (int idx = tid; idx < 64 * 128; idx += 256) {
        int o = idx >> 6, ll = idx & 63;
        int l = l0 + ll;
        if (l < L_) out[((size_t)b * F_ + o) * L_ + l] = s[ll][o];
    }
}

// ---------------------------------------------------------------------------
extern "C" void kernel_launch(void* const* d_in, const int* in_sizes, int n_in,
                              void* d_out, int out_size, void* d_ws, size_t ws_size,
                              hipStream_t stream) {
    const float* x        = (const float*)d_in[0];
    const float* skip     = (const float*)d_in[1];
    const float* convT_w  = (const float*)d_in[4];
    const float* convT_b  = (const float*)d_in[5];
    const float* fuse_w   = (const float*)d_in[6];
    const float* fuse_b   = (const float*)d_in[7];
    const float* norm_w   = (const float*)d_in[8];
    const float* norm_b   = (const float*)d_in[9];
    const float* in_proj  = (const float*)d_in[10];
    const float* conv_w   = (const float*)d_in[11];
    const float* conv_b   = (const float*)d_in[12];
    const float* x_proj   = (const float*)d_in[13];
    const float* dt_projw = (const float*)d_in[14];
    const float* dt_projb = (const float*)d_in[15];
    const float* A_log    = (const float*)d_in[16];
    const float* D_skip   = (const float*)d_in[17];
    const float* out_proj = (const float*)d_in[18];
    float* out = (float*)d_out;

    float* w = (float*)d_ws;
    size_t off = 0;
    auto alloc = [&](size_t n) { float* p = w + off; off += n; return p; };
    float* hT      = alloc((size_t)B_ * L_ * F_);       // 514048 (dead after fuse)
    float* W2p     = alloc(524288);                     // dead after convt5
    float* fwTp    = alloc(32768);                      // dead after fuse
    float* ipTp    = alloc(262144);
    float* opTp    = alloc(262144);
    float* xpTp    = alloc(65536);
    float* xs      = alloc(2 * RL_ * F_);
    float* cur     = alloc(2 * RL_ * F_);               // written only at the very end
    float* res1    = alloc(2 * RL_ * F_);
    float* xz      = alloc(2 * RL_ * (2 * DI_));
    float* xc      = alloc(2 * RL_ * DI_);
    float* dl      = alloc(2 * RL_ * DI_);
    float* bcm     = alloc(2 * RL_ * 32);
    float* yb      = alloc(2 * RL_ * DI_);
    // scan chunk summaries alias dead regions:
    //   hp   (2*2*64*4096 = 1048576) -> hT+W2p+fwTp region (1071104 floats)
    //   dsum (2*2*64*256  =   65536) -> cur (dead until final gate5 of blk1)
    float* hp   = hT;
    float* dsum = cur;
    (void)ws_size; (void)in_sizes; (void)n_in; (void)out_size;

    prep_k<<<(PREP_N + 255) / 256, 256, 0, stream>>>(convT_w, fuse_w, in_proj, out_proj,
                                                     x_proj, W2p, fwTp, ipTp, opTp, xpTp);
    convt5_k<<<dim3(63, 2, 2), 256, 0, stream>>>(x, W2p, convT_b, hT);
    fuse5_k<<<dim3(251, 2), 256, 0, stream>>>(skip, hT, fwTp, fuse_b, xs);

    for (int blk = 0; blk < NBLK_; ++blk) {
        const float* Xin = (blk == 0) ? xs : res1;
        ln5_k<<<dim3(251, 2), 256, 0, stream>>>(Xin, norm_w, norm_b, ipTp, xz, blk);
        dwxdt_k<<<dim3(251, 2), 256, 0, stream>>>(xz, conv_w, conv_b, xpTp,
                                                  dt_projw, dt_projb, xc, bcm, dl, blk);
        scanA_k<<<dim3(32, NC_, 2), 256, 0, stream>>>(dl, xc, bcm, A_log, yb, hp, dsum, blk);
        scanB_k<<<dim3(32, 2), 256, 0, stream>>>(hp, dsum, A_log, blk);
        fixD_k<<<dim3(32, NC_ - 1, 2), 256, 0, stream>>>(dl, bcm, A_log, hp, yb, blk);
        if (blk == 0)
            gate5_k<<<dim3(251, 2), 256, 0, stream>>>(yb, xc, xz, D_skip, opTp, xs, res1, 0);
        else
            gate5_k<<<dim3(251, 2), 256, 0, stream>>>(yb, xc, xz, D_skip, opTp, nullptr, cur, 1);
    }

    combine2_k<<<dim3(32, 2), 256, 0, stream>>>(cur, res1, out);
}

// Round 7
// 406.892 us; speedup vs baseline: 6.2204x; 1.0796x over previous
//
#include <hip/hip_runtime.h>
#include <hip/hip_bf16.h>
#include <math.h>

// Problem constants
#define B_    2
#define FIN_  256
#define LIN_  250
#define F_    128      // F_OUT
#define K_    16       // KSIZE
#define ST_   8        // STRIDE
#define L_    2008     // L_OUT
#define DI_   256      // D_INNER
#define DS_   16       // D_STATE
#define RK_   8        // DT_RANK
#define CV_   4        // D_CONV
#define NBLK_ 2
#define NC_   64       // scan chunks (trailing chunk empty: identity summary)
#define CL_   32       // chunk length
#define RL_   ((size_t)B_ * L_)   // rows per direction = 4016 (= 251*16 exactly)

__device__ __forceinline__ float silu_f(float x) {
    return x / (1.f + __expf(-x));
}
__device__ __forceinline__ float softplus_f(float x) {
    return (x > 20.f) ? x : log1pf(__expf(x));
}
__device__ __forceinline__ float dot4(float4 a, float4 b) {
    return a.x * b.x + a.y * b.y + a.z * b.z + a.w * b.w;
}

// ---------------------------------------------------------------------------
// prep: packed transposed weights, each as [c/4][out][4] so a thread's 4-c
// weight bundle is ONE coalesced dwordx4.
// ---------------------------------------------------------------------------
#define PREP_N (524288 + 32768 + 262144 + 262144 + 65536)
__global__ void prep_k(const float* __restrict__ convT_w, const float* __restrict__ fuse_w,
                       const float* __restrict__ in_proj, const float* __restrict__ out_proj,
                       const float* __restrict__ x_proj,
                       float* __restrict__ W2p, float* __restrict__ fwTp,
                       float* __restrict__ ipTp, float* __restrict__ opTp,
                       float* __restrict__ xpTp) {
    size_t g = (size_t)blockIdx.x * 256 + threadIdx.x;
    if (g >= PREP_N) return;
    if (g < 524288) {
        int ccq = g >> 12, rr = g & 4095;
        int po = rr >> 2, i = rr & 3;
        int cc = ccq * 4 + i;
        int p = po >> 7, o = po & 127;
        int c = cc & 255, k = (cc < 256) ? p : p + 8;
        W2p[g] = convT_w[(size_t)c * 2048 + o * 16 + k];
        return;
    }
    g -= 524288;
    if (g < 32768) {
        int cq = g >> 9, rr = g & 511;
        int o = rr >> 2, i = rr & 3;
        fwTp[g] = fuse_w[(size_t)o * 256 + cq * 4 + i];
        return;
    }
    g -= 32768;
    if (g < 262144) {
        int db = g >> 16, r = g & 65535;
        int cq = r >> 11, rr = r & 2047;
        int e = rr >> 2, i = rr & 3;
        ipTp[g] = in_proj[(size_t)db * 65536 + e * 128 + cq * 4 + i];
        return;
    }
    g -= 262144;
    if (g < 262144) {
        int db = g >> 15, r = g & 32767;
        int cq = r >> 9, rr = r & 511;
        int o = rr >> 2, i = rr & 3;
        opTp[g] = out_proj[(size_t)db * 32768 + o * 256 + cq * 4 + i];
        return;
    }
    g -= 262144;
    {
        int db = g >> 14, r = g & 16383;
        int cq = r >> 8, rr = r & 255;
        int e = rr >> 2, i = rr & 3;
        xpTp[g] = (e < 40) ? x_proj[(size_t)db * 10240 + e * 256 + cq * 4 + i] : 0.f;
    }
}

// ---------------------------------------------------------------------------
// convT+silu GEMM, 2 outputs/thread. grid (63 jt of 4, 2 nt, B), block 256.
// ---------------------------------------------------------------------------
__global__ void __launch_bounds__(256) convt5_k(
        const float* __restrict__ x, const float* __restrict__ W2p,
        const float* __restrict__ bias, float* __restrict__ hT) {
    int j0 = blockIdx.x * 4, nt = blockIdx.y, b = blockIdx.z;
    int po = nt * 512 + threadIdx.x;
    int p = po >> 7, o = po & 127;

    __shared__ float xr[5][264];   // rows j0-1 .. j0+3

    for (int idx = threadIdx.x; idx < 5 * 256; idx += 256) {
        int i = idx >> 8, c = idx & 255;
        int j = j0 - 1 + i;
        xr[i][c] = (j >= 0 && j < LIN_) ? x[((size_t)b * FIN_ + c) * LIN_ + j] : 0.f;
    }
    __syncthreads();

    float acca[4] = {0.f, 0.f, 0.f, 0.f};
    float accb[4] = {0.f, 0.f, 0.f, 0.f};
    const float4* W4 = (const float4*)W2p;

    for (int ccq = 0; ccq < 64; ++ccq) {
        float4 wa1 = W4[(size_t)ccq * 1024 + po];
        float4 wb1 = W4[(size_t)ccq * 1024 + po + 256];
        float4 wa2 = W4[(size_t)(ccq + 64) * 1024 + po];
        float4 wb2 = W4[(size_t)(ccq + 64) * 1024 + po + 256];
        float4 xv[5];
        #pragma unroll
        for (int i = 0; i < 5; ++i) xv[i] = *(const float4*)&xr[i][ccq * 4];
        #pragma unroll
        for (int jj = 0; jj < 4; ++jj) {
            acca[jj] += dot4(xv[jj + 1], wa1) + dot4(xv[jj], wa2);
            accb[jj] += dot4(xv[jj + 1], wb1) + dot4(xv[jj], wb2);
        }
    }
    float bo = bias[o];
    #pragma unroll
    for (int jj = 0; jj < 4; ++jj) {
        int j = j0 + jj;
        if (j <= 250) {
            hT[((size_t)b * L_ + 8 * j + p) * F_ + o]     = silu_f(acca[jj] + bo);
            hT[((size_t)b * L_ + 8 * j + p + 2) * F_ + o] = silu_f(accb[jj] + bo);
        }
    }
}

// ---------------------------------------------------------------------------
// fuse = silu(fuse_w @ [skip; h] + b); 2 outs/thread; xs fwd + flipped bwd.
// grid (251 l-tiles of 8, B), block 256
// ---------------------------------------------------------------------------
__global__ void __launch_bounds__(256) fuse5_k(
        const float* __restrict__ skip, const float* __restrict__ hT,
        const float* __restrict__ fwTp, const float* __restrict__ fb,
        float* __restrict__ xs) {
    int l0 = blockIdx.x * 8, b = blockIdx.y;
    int tid = threadIdx.x;

    __shared__ float ss[8][264];

    for (int idx = tid; idx < 128 * 8; idx += 256) {   // skip part (c<128)
        int c = idx >> 3, ll = idx & 7;
        ss[ll][c] = skip[((size_t)b * F_ + c) * L_ + l0 + ll];
    }
    for (int idx = tid; idx < 8 * 128; idx += 256) {   // h part (c>=128)
        int ll = idx >> 7, c = idx & 127;
        ss[ll][128 + c] = hT[((size_t)b * L_ + l0 + ll) * F_ + c];
    }
    __syncthreads();

    int o2 = tid & 63, rg = tid >> 6;
    float acca[2] = {0.f, 0.f}, accb[2] = {0.f, 0.f};
    const float4* W4 = (const float4*)fwTp;

    for (int cq = 0; cq < 64; ++cq) {
        float4 wa = W4[cq * 128 + o2];
        float4 wb = W4[cq * 128 + o2 + 64];
        #pragma unroll
        for (int rr = 0; rr < 2; ++rr) {
            float4 s = *(const float4*)&ss[rg * 2 + rr][cq * 4];
            acca[rr] += dot4(s, wa);
            accb[rr] += dot4(s, wb);
        }
    }
    float ba = fb[o2], bb = fb[o2 + 64];
    #pragma unroll
    for (int rr = 0; rr < 2; ++rr) {
        int l = l0 + rg * 2 + rr;
        float va = silu_f(acca[rr] + ba);
        float vb = silu_f(accb[rr] + bb);
        size_t rf = ((size_t)b * L_ + l) * F_;
        size_t rb = (RL_ + (size_t)b * L_ + (L_ - 1 - l)) * F_;
        xs[rf + o2] = va;       xs[rf + o2 + 64] = vb;
        xs[rb + o2] = va;       xs[rb + o2 + 64] = vb;
    }
}

// ---------------------------------------------------------------------------
// lndw: LN(19 rows w/ halo) -> in_proj x-half (regs, per-channel) -> depthwise
// conv in REGISTERS -> silu -> XC + xcs; z-half in_proj -> XZz; then
// x_proj(40)+dt_proj(256)+softplus. grid (251, 2), block 256.
// ---------------------------------------------------------------------------
__global__ void __launch_bounds__(256) lndw_k(
        const float* __restrict__ X, const float* __restrict__ nw,
        const float* __restrict__ nb_, const float* __restrict__ ipTp,
        const float* __restrict__ cw, const float* __restrict__ cb,
        const float* __restrict__ xpTp, const float* __restrict__ dtw,
        const float* __restrict__ dtb,
        float* __restrict__ XC, float* __restrict__ XZz,
        float* __restrict__ BCM, float* __restrict__ DELTA, int blk) {
    int rt = blockIdx.x, d = blockIdx.y;
    size_t rbase = (size_t)rt * 16;
    int tid = threadIdx.x, lane = tid & 63, wid = tid >> 6;
    int db = d * NBLK_ + blk;
    size_t dRL = (size_t)d * RL_;

    __shared__ float us[19][132];
    __shared__ float xcs[16][264];
    __shared__ float dts[16][8];

    // LN for staged rows rbase-3 .. rbase+15 (invalid rows -> garbage, guarded later)
    int wi0 = db * F_;
    for (int r = wid; r < 19; r += 4) {
        long grow = (long)rbase - 3 + r;
        float2 v = make_float2(0.f, 0.f);
        if (grow >= 0)
            v = *(const float2*)(X + (dRL + (size_t)grow) * F_ + lane * 2);
        float s1 = v.x + v.y, s2 = v.x * v.x + v.y * v.y;
        for (int off = 32; off; off >>= 1) {
            s1 += __shfl_xor(s1, off);
            s2 += __shfl_xor(s2, off);
        }
        float mu = s1 * (1.f / F_);
        float var = s2 * (1.f / F_) - mu * mu;
        float rstd = rsqrtf(var + 1e-5f);
        int c2 = lane * 2;
        us[r][c2]     = (v.x - mu) * rstd * nw[wi0 + c2]     + nb_[wi0 + c2];
        us[r][c2 + 1] = (v.y - mu) * rstd * nw[wi0 + c2 + 1] + nb_[wi0 + c2 + 1];
    }
    __syncthreads();

    int o = tid;   // channel / x-out index, 0..255
    const float4* W4 = (const float4*)(ipTp + (size_t)db * 65536);

    // x-half in_proj for all 19 staged rows (us reads are broadcast)
    float acc[19];
    #pragma unroll
    for (int i = 0; i < 19; ++i) acc[i] = 0.f;
    for (int cq = 0; cq < 32; ++cq) {
        float4 w = W4[cq * 512 + o];
        #pragma unroll
        for (int r = 0; r < 19; ++r)
            acc[r] += dot4(*(const float4*)&us[r][cq * 4], w);
    }

    // depthwise conv + silu, entirely in registers (thread owns channel o)
    {
        int wi = db * DI_ + o;
        float cw0 = cw[(size_t)wi * CV_ + 0], cw1 = cw[(size_t)wi * CV_ + 1];
        float cw2 = cw[(size_t)wi * CV_ + 2], cw3 = cw[(size_t)wi * CV_ + 3];
        float bias = cb[wi];
        #pragma unroll
        for (int r16 = 0; r16 < 16; ++r16) {
            size_t row = rbase + r16;
            int b_r = (row >= L_) ? 1 : 0;
            int l_r = (int)row - b_r * L_;
            int s = r16 + 3;
            float a = bias + acc[s] * cw3;
            if (l_r - 1 >= 0) a += acc[s - 1] * cw2;
            if (l_r - 2 >= 0) a += acc[s - 2] * cw1;
            if (l_r - 3 >= 0) a += acc[s - 3] * cw0;
            float v = silu_f(a);
            xcs[r16][o] = v;
            XC[(dRL + row) * DI_ + o] = v;
        }
    }

    // z-half in_proj for the 16 real rows
    {
        float accz[16];
        #pragma unroll
        for (int i = 0; i < 16; ++i) accz[i] = 0.f;
        for (int cq = 0; cq < 32; ++cq) {
            float4 w = W4[cq * 512 + 256 + o];
            #pragma unroll
            for (int r = 0; r < 16; ++r)
                accz[r] += dot4(*(const float4*)&us[r + 3][cq * 4], w);
        }
        #pragma unroll
        for (int r = 0; r < 16; ++r)
            XZz[(dRL + rbase + r) * DI_ + o] = accz[r];
    }
    __syncthreads();

    // x_proj: e = tid&63 (e<40 active), rg = tid>>6 covers 4 rows each
    {
        int e = tid & 63, rg = tid >> 6;
        float acc2[4] = {0.f, 0.f, 0.f, 0.f};
        const float4* Wx = (const float4*)(xpTp + (size_t)db * 16384);
        for (int cq = 0; cq < 64; ++cq) {
            float4 w = Wx[cq * 64 + e];
            #pragma unroll
            for (int rr = 0; rr < 4; ++rr)
                acc2[rr] += dot4(*(const float4*)&xcs[rg * 4 + rr][cq * 4], w);
        }
        if (e < RK_) {
            #pragma unroll
            for (int rr = 0; rr < 4; ++rr) dts[rg * 4 + rr][e] = acc2[rr];
        } else if (e < RK_ + 2 * DS_) {
            #pragma unroll
            for (int rr = 0; rr < 4; ++rr) {
                size_t row = rbase + rg * 4 + rr;
                BCM[(dRL + row) * 32 + (e - RK_)] = acc2[rr];
            }
        }
    }
    __syncthreads();

    // dt_proj + softplus
    {
        int wi = db * DI_ + o;
        float dwv[RK_];
        #pragma unroll
        for (int k = 0; k < RK_; ++k) dwv[k] = dtw[(size_t)wi * RK_ + k];
        float bias = dtb[wi];
        #pragma unroll 4
        for (int rr = 0; rr < 16; ++rr) {
            size_t row = rbase + rr;
            float a = bias;
            #pragma unroll
            for (int k = 0; k < RK_; ++k) a += dts[rr][k] * dwv[k];
            DELTA[(dRL + row) * DI_ + o] = softplus_f(a);
        }
    }
}

// ---------------------------------------------------------------------------
// scanA: LDS-staged chunk-local scan (CL=32). Emits local y, inclusive cum(dt)
// (overwrites DELTA), chunk-final hpart and dtsum.
// grid (32 chgrp, NC_, 2), block 256 = 16 chl x 16 n
// ---------------------------------------------------------------------------
__global__ void __launch_bounds__(256) scanA_k(
        float* __restrict__ DELTA, const float* __restrict__ XC,
        const float* __restrict__ BCM, const float* __restrict__ A_log,
        float* __restrict__ Y, float* __restrict__ hpart,
        float* __restrict__ dsum, int blk) {
    int d = blockIdx.z, cnk = blockIdx.y;
    int chunit0 = blockIdx.x * 16;
    int chl = threadIdx.x >> 4, n = threadIdx.x & 15;
    int b = chunit0 >> 8, ch0 = chunit0 & 255;
    int ch = ch0 + chl;
    int t0 = cnk * CL_;
    int nt = L_ - t0; if (nt > CL_) nt = CL_;   // may be <= 0 (empty chunk)

    __shared__ float dt_s[CL_][16];
    __shared__ float u_s[CL_][16];
    __shared__ float bc_s[CL_][32];

    size_t rowbase = (size_t)d * RL_ + (size_t)b * L_ + t0;
    for (int idx = threadIdx.x; idx < CL_ * 16; idx += 256) {
        int t = idx >> 4, c = idx & 15;
        float dv = 0.f, uv = 0.f;
        if (t < nt) {
            dv = DELTA[(rowbase + t) * DI_ + ch0 + c];
            uv = XC[(rowbase + t) * DI_ + ch0 + c];
        }
        dt_s[t][c] = dv; u_s[t][c] = uv;
    }
    for (int idx = threadIdx.x; idx < CL_ * 32; idx += 256) {
        int t = idx >> 5, m = idx & 31;
        bc_s[t][m] = (t < nt) ? BCM[(rowbase + t) * 32 + m] : 0.f;
    }
    __syncthreads();

    float A = -__expf(A_log[((size_t)(d * NBLK_ + blk) * DI_ + ch) * DS_ + n]);
    float h = 0.f, cum = 0.f;
    for (int t = 0; t < nt; ++t) {
        float dt = dt_s[t][chl];
        float u  = u_s[t][chl];
        float Bt = bc_s[t][n];
        float Ct = bc_s[t][16 + n];
        cum += dt;
        h = __expf(dt * A) * h + dt * u * Bt;
        float yp = h * Ct;
        yp += __shfl_xor(yp, 1);
        yp += __shfl_xor(yp, 2);
        yp += __shfl_xor(yp, 4);
        yp += __shfl_xor(yp, 8);
        if (n == 0) {
            Y[(rowbase + t) * DI_ + ch] = yp;
            DELTA[(rowbase + t) * DI_ + ch] = cum;   // inclusive prefix of dt
        }
    }
    size_t cb = (size_t)(d * B_ + b) * NC_ + cnk;
    hpart[cb * (DI_ * DS_) + ch * DS_ + n] = h;
    if (n == 0) dsum[cb * DI_ + ch] = cum;
}

// ---------------------------------------------------------------------------
// scanB: cross-chunk scan of summaries, in-place (hpart -> carry-in per chunk).
// grid (32, 2), block 256
// ---------------------------------------------------------------------------
__global__ void scanB_k(float* __restrict__ hpart, const float* __restrict__ dsum,
                        const float* __restrict__ A_log, int blk) {
    int d = blockIdx.y;
    int idx = blockIdx.x * 256 + threadIdx.x;   // (b, ch, n)
    int b = idx >> 12, ch = (idx >> 4) & 255, n = idx & 15;
    float A = -__expf(A_log[((size_t)(d * NBLK_ + blk) * DI_ + ch) * DS_ + n]);
    float h = 0.f;
    for (int c = 0; c < NC_; ++c) {
        size_t cb = (size_t)(d * B_ + b) * NC_ + c;
        size_t hi = cb * (DI_ * DS_) + ch * DS_ + n;
        float hc = hpart[hi];
        hpart[hi] = h;                       // carry-in for chunk c
        h = __expf(A * dsum[cb * DI_ + ch]) * h + hc;
    }
}

// ---------------------------------------------------------------------------
// gateC: correction (was fixD) + gate + out_proj GEMM (+ optional residual).
// Correction: y += sum_n C[t][n]*hin[n]*exp(A[n]*cum[t]) with A,hin in regs.
// A 16-row tile touches at most 2 (b,chunk) pairs -> dual K tables, uniform
// per-row branch. grid (251, 2), block 256.
// ---------------------------------------------------------------------------
__global__ void __launch_bounds__(256) gateC_k(
        const float* __restrict__ Y, const float* __restrict__ XC,
        const float* __restrict__ XZz, const float* __restrict__ DELTA /*=cum*/,
        const float* __restrict__ BCM, const float* __restrict__ A_log,
        const float* __restrict__ hcarry, const float* __restrict__ Dsk,
        const float* __restrict__ opTp, const float* __restrict__ resid_in,
        float* __restrict__ outp, int blk) {
    int rt = blockIdx.x, d = blockIdx.y;
    int tid = threadIdx.x;
    size_t rbase = (size_t)rt * 16;
    int db = d * NBLK_ + blk;
    size_t dRL = (size_t)d * RL_;

    __shared__ float yg[16][264];
    __shared__ float Cs[16][16];

    // stage C values (broadcast-shared across channels)
    {
        int r = tid >> 4, n = tid & 15;
        Cs[r][n] = BCM[(dRL + rbase + r) * 32 + 16 + n];
    }
    __syncthreads();

    {
        int c = tid;   // channel
        float Dc = Dsk[(size_t)db * DI_ + c];

        float An[16];
        const float* Ab = A_log + ((size_t)db * DI_ + c) * DS_;
        #pragma unroll
        for (int n = 0; n < 16; ++n) An[n] = -__expf(Ab[n]);

        // chunk tables for first and last row of tile
        int b0 = (rbase >= L_) ? 1 : 0;
        int l0 = (int)rbase - b0 * L_;
        int ck0 = l0 >> 5;
        int b1 = (rbase + 15 >= L_) ? 1 : 0;
        int l1 = (int)(rbase + 15) - b1 * L_;
        int ck1 = l1 >> 5;
        const float* hp0 = hcarry + ((size_t)(d * B_ + b0) * NC_ + ck0) * (DI_ * DS_) + (size_t)c * DS_;
        const float* hp1 = hcarry + ((size_t)(d * B_ + b1) * NC_ + ck1) * (DI_ * DS_) + (size_t)c * DS_;
        float K0[16], K1[16];
        #pragma unroll
        for (int q = 0; q < 4; ++q) {
            float4 v0 = *(const float4*)(hp0 + q * 4);
            float4 v1 = *(const float4*)(hp1 + q * 4);
            K0[4*q] = v0.x; K0[4*q+1] = v0.y; K0[4*q+2] = v0.z; K0[4*q+3] = v0.w;
            K1[4*q] = v1.x; K1[4*q+1] = v1.y; K1[4*q+2] = v1.z; K1[4*q+3] = v1.w;
        }

        for (int r = 0; r < 16; ++r) {
            size_t row = rbase + r;
            size_t ri = dRL + row;
            int b_r = (row >= L_) ? 1 : 0;
            int l_r = (int)row - b_r * L_;
            int ck_r = l_r >> 5;
            float cum = DELTA[ri * DI_ + c];
            float corr = 0.f;
            if (b_r == b0 && ck_r == ck0) {
                #pragma unroll
                for (int n = 0; n < 16; ++n)
                    corr += Cs[r][n] * K0[n] * __expf(An[n] * cum);
            } else {
                #pragma unroll
                for (int n = 0; n < 16; ++n)
                    corr += Cs[r][n] * K1[n] * __expf(An[n] * cum);
            }
            float yv = Y[ri * DI_ + c] + corr;
            float z  = XZz[ri * DI_ + c];
            yg[r][c] = (yv + XC[ri * DI_ + c] * Dc) * silu_f(z);
        }
    }
    __syncthreads();

    int o2 = tid & 63, rg = tid >> 6;
    float acca[4] = {0.f, 0.f, 0.f, 0.f};
    float accb[4] = {0.f, 0.f, 0.f, 0.f};
    const float4* W4 = (const float4*)(opTp + (size_t)db * 32768);

    for (int cq = 0; cq < 64; ++cq) {
        float4 wa = W4[cq * 128 + o2];
        float4 wb = W4[cq * 128 + o2 + 64];
        #pragma unroll
        for (int rr = 0; rr < 4; ++rr) {
            float4 u = *(const float4*)&yg[rg * 4 + rr][cq * 4];
            acca[rr] += dot4(u, wa);
            accb[rr] += dot4(u, wb);
        }
    }
    #pragma unroll
    for (int rr = 0; rr < 4; ++rr) {
        size_t ri = dRL + rbase + rg * 4 + rr;
        float va = acca[rr], vb = accb[rr];
        if (resid_in) {
            va += resid_in[ri * F_ + o2];
            vb += resid_in[ri * F_ + o2 + 64];
        }
        outp[ri * F_ + o2]      = va;
        outp[ri * F_ + o2 + 64] = vb;
    }
}

// ---------------------------------------------------------------------------
// combine with LDS transpose for coalesced (b,o,l) writes
// grid (32 l-tiles, B), block 256
// ---------------------------------------------------------------------------
__global__ void combine2_k(const float* __restrict__ cur, const float* __restrict__ res1,
                           float* __restrict__ out) {
    int l0 = blockIdx.x * 64, b = blockIdx.y;
    int tid = threadIdx.x;
    __shared__ float s[64][129];
    for (int idx = tid; idx < 64 * 128; idx += 256) {
        int ll = idx >> 7, o = idx & 127;
        int l = l0 + ll;
        if (l < L_) {
            size_t rf = ((size_t)b * L_ + l) * F_ + o;
            size_t rb = (RL_ + (size_t)b * L_ + (L_ - 1 - l)) * F_ + o;
            s[ll][o] = cur[rf] + res1[rf] + cur[rb] + res1[rb];
        }
    }
    __syncthreads();
    for (int idx = tid; idx < 64 * 128; idx += 256) {
        int o = idx >> 6, ll = idx & 63;
        int l = l0 + ll;
        if (l < L_) out[((size_t)b * F_ + o) * L_ + l] = s[ll][o];
    }
}

// ---------------------------------------------------------------------------
extern "C" void kernel_launch(void* const* d_in, const int* in_sizes, int n_in,
                              void* d_out, int out_size, void* d_ws, size_t ws_size,
                              hipStream_t stream) {
    const float* x        = (const float*)d_in[0];
    const float* skip     = (const float*)d_in[1];
    const float* convT_w  = (const float*)d_in[4];
    const float* convT_b  = (const float*)d_in[5];
    const float* fuse_w   = (const float*)d_in[6];
    const float* fuse_b   = (const float*)d_in[7];
    const float* norm_w   = (const float*)d_in[8];
    const float* norm_b   = (const float*)d_in[9];
    const float* in_proj  = (const float*)d_in[10];
    const float* conv_w   = (const float*)d_in[11];
    const float* conv_b   = (const float*)d_in[12];
    const float* x_proj   = (const float*)d_in[13];
    const float* dt_projw = (const float*)d_in[14];
    const float* dt_projb = (const float*)d_in[15];
    const float* A_log    = (const float*)d_in[16];
    const float* D_skip   = (const float*)d_in[17];
    const float* out_proj = (const float*)d_in[18];
    float* out = (float*)d_out;

    float* w = (float*)d_ws;
    size_t off = 0;
    auto alloc = [&](size_t n) { float* p = w + off; off += n; return p; };
    float* hT      = alloc((size_t)B_ * L_ * F_);       // 514048 (dead after fuse5)
    float* W2p     = alloc(524288);                     // dead after convt5
    float* fwTp    = alloc(32768);                      // dead after fuse5
    float* ipTp    = alloc(262144);
    float* opTp    = alloc(262144);
    float* xpTp    = alloc(65536);
    float* xs      = alloc(2 * RL_ * F_);
    float* cur     = alloc(2 * RL_ * F_);               // written only by final gateC
    float* res1    = alloc(2 * RL_ * F_);
    float* xzz     = alloc(2 * RL_ * DI_);              // z-half only
    float* xc      = alloc(2 * RL_ * DI_);
    float* dl      = alloc(2 * RL_ * DI_);
    float* bcm     = alloc(2 * RL_ * 32);
    float* yb      = alloc(2 * RL_ * DI_);
    // scan chunk summaries alias dead regions:
    //   hp   (2*2*64*4096 = 1048576) -> hT+W2p+fwTp (1071104 floats, dead by scan)
    //   dsum (2*2*64*256  =   65536) -> cur (dead until final gateC of blk1,
    //         which runs after scanB(blk1) has consumed dsum)
    float* hp   = hT;
    float* dsum = cur;
    (void)ws_size; (void)in_sizes; (void)n_in; (void)out_size;

    prep_k<<<(PREP_N + 255) / 256, 256, 0, stream>>>(convT_w, fuse_w, in_proj, out_proj,
                                                     x_proj, W2p, fwTp, ipTp, opTp, xpTp);
    convt5_k<<<dim3(63, 2, 2), 256, 0, stream>>>(x, W2p, convT_b, hT);
    fuse5_k<<<dim3(251, 2), 256, 0, stream>>>(skip, hT, fwTp, fuse_b, xs);

    for (int blk = 0; blk < NBLK_; ++blk) {
        const float* Xin = (blk == 0) ? xs : res1;
        lndw_k<<<dim3(251, 2), 256, 0, stream>>>(Xin, norm_w, norm_b, ipTp,
                                                 conv_w, conv_b, xpTp,
                                                 dt_projw, dt_projb,
                                                 xc, xzz, bcm, dl, blk);
        scanA_k<<<dim3(32, NC_, 2), 256, 0, stream>>>(dl, xc, bcm, A_log, yb, hp, dsum, blk);
        scanB_k<<<dim3(32, 2), 256, 0, stream>>>(hp, dsum, A_log, blk);
        if (blk == 0)
            gateC_k<<<dim3(251, 2), 256, 0, stream>>>(yb, xc, xzz, dl, bcm, A_log, hp,
                                                      D_skip, opTp, xs, res1, 0);
        else
            gateC_k<<<dim3(251, 2), 256, 0, stream>>>(yb, xc, xzz, dl, bcm, A_log, hp,
                                                      D_skip, opTp, nullptr, cur, 1);
    }

    combine2_k<<<dim3(32, 2), 256, 0, stream>>>(cur, res1, out);
}

// Round 8
// 400.514 us; speedup vs baseline: 6.3194x; 1.0159x over previous
//
#include <hip/hip_runtime.h>
#include <hip/hip_bf16.h>
#include <math.h>

// Problem constants
#define B_    2
#define FIN_  256
#define LIN_  250
#define F_    128      // F_OUT
#define K_    16       // KSIZE
#define ST_   8        // STRIDE
#define L_    2008     // L_OUT
#define DI_   256      // D_INNER
#define DS_   16       // D_STATE
#define RK_   8        // DT_RANK
#define CV_   4        // D_CONV
#define NBLK_ 2
#define NC_   64       // scan chunks (trailing chunk empty: identity summary)
#define CL_   32       // chunk length
#define RL_   ((size_t)B_ * L_)   // rows per direction = 4016 (= 502*8 exactly)

__device__ __forceinline__ float silu_f(float x) {
    return x / (1.f + __expf(-x));
}
__device__ __forceinline__ float softplus_f(float x) {
    return (x > 20.f) ? x : log1pf(__expf(x));
}
__device__ __forceinline__ float dot4(float4 a, float4 b) {
    return a.x * b.x + a.y * b.y + a.z * b.z + a.w * b.w;
}

// ---------------------------------------------------------------------------
// prep: packed transposed weights, each as [c/4][out][4] so a thread's 4-c
// weight bundle is ONE coalesced dwordx4.
// ---------------------------------------------------------------------------
#define PREP_N (524288 + 32768 + 262144 + 262144 + 65536)
__global__ void prep_k(const float* __restrict__ convT_w, const float* __restrict__ fuse_w,
                       const float* __restrict__ in_proj, const float* __restrict__ out_proj,
                       const float* __restrict__ x_proj,
                       float* __restrict__ W2p, float* __restrict__ fwTp,
                       float* __restrict__ ipTp, float* __restrict__ opTp,
                       float* __restrict__ xpTp) {
    size_t g = (size_t)blockIdx.x * 256 + threadIdx.x;
    if (g >= PREP_N) return;
    if (g < 524288) {
        int ccq = g >> 12, rr = g & 4095;
        int po = rr >> 2, i = rr & 3;
        int cc = ccq * 4 + i;
        int p = po >> 7, o = po & 127;
        int c = cc & 255, k = (cc < 256) ? p : p + 8;
        W2p[g] = convT_w[(size_t)c * 2048 + o * 16 + k];
        return;
    }
    g -= 524288;
    if (g < 32768) {
        int cq = g >> 9, rr = g & 511;
        int o = rr >> 2, i = rr & 3;
        fwTp[g] = fuse_w[(size_t)o * 256 + cq * 4 + i];
        return;
    }
    g -= 32768;
    if (g < 262144) {
        int db = g >> 16, r = g & 65535;
        int cq = r >> 11, rr = r & 2047;
        int e = rr >> 2, i = rr & 3;
        ipTp[g] = in_proj[(size_t)db * 65536 + e * 128 + cq * 4 + i];
        return;
    }
    g -= 262144;
    if (g < 262144) {
        int db = g >> 15, r = g & 32767;
        int cq = r >> 9, rr = r & 511;
        int o = rr >> 2, i = rr & 3;
        opTp[g] = out_proj[(size_t)db * 32768 + o * 256 + cq * 4 + i];
        return;
    }
    g -= 262144;
    {
        int db = g >> 14, r = g & 16383;
        int cq = r >> 8, rr = r & 255;
        int e = rr >> 2, i = rr & 3;
        xpTp[g] = (e < 40) ? x_proj[(size_t)db * 10240 + e * 256 + cq * 4 + i] : 0.f;
    }
}

// ---------------------------------------------------------------------------
// convT+silu GEMM, 2 outputs/thread. grid (63 jt of 4, 2 nt, B), block 256.
// ---------------------------------------------------------------------------
__global__ void __launch_bounds__(256) convt5_k(
        const float* __restrict__ x, const float* __restrict__ W2p,
        const float* __restrict__ bias, float* __restrict__ hT) {
    int j0 = blockIdx.x * 4, nt = blockIdx.y, b = blockIdx.z;
    int po = nt * 512 + threadIdx.x;
    int p = po >> 7, o = po & 127;

    __shared__ float xr[5][264];   // rows j0-1 .. j0+3

    for (int idx = threadIdx.x; idx < 5 * 256; idx += 256) {
        int i = idx >> 8, c = idx & 255;
        int j = j0 - 1 + i;
        xr[i][c] = (j >= 0 && j < LIN_) ? x[((size_t)b * FIN_ + c) * LIN_ + j] : 0.f;
    }
    __syncthreads();

    float acca[4] = {0.f, 0.f, 0.f, 0.f};
    float accb[4] = {0.f, 0.f, 0.f, 0.f};
    const float4* W4 = (const float4*)W2p;

    for (int ccq = 0; ccq < 64; ++ccq) {
        float4 wa1 = W4[(size_t)ccq * 1024 + po];
        float4 wb1 = W4[(size_t)ccq * 1024 + po + 256];
        float4 wa2 = W4[(size_t)(ccq + 64) * 1024 + po];
        float4 wb2 = W4[(size_t)(ccq + 64) * 1024 + po + 256];
        float4 xv[5];
        #pragma unroll
        for (int i = 0; i < 5; ++i) xv[i] = *(const float4*)&xr[i][ccq * 4];
        #pragma unroll
        for (int jj = 0; jj < 4; ++jj) {
            acca[jj] += dot4(xv[jj + 1], wa1) + dot4(xv[jj], wa2);
            accb[jj] += dot4(xv[jj + 1], wb1) + dot4(xv[jj], wb2);
        }
    }
    float bo = bias[o];
    #pragma unroll
    for (int jj = 0; jj < 4; ++jj) {
        int j = j0 + jj;
        if (j <= 250) {
            hT[((size_t)b * L_ + 8 * j + p) * F_ + o]     = silu_f(acca[jj] + bo);
            hT[((size_t)b * L_ + 8 * j + p + 2) * F_ + o] = silu_f(accb[jj] + bo);
        }
    }
}

// ---------------------------------------------------------------------------
// fuse = silu(fuse_w @ [skip; h] + b); 2 outs/thread; xs fwd + flipped bwd.
// grid (251 l-tiles of 8, B), block 256
// ---------------------------------------------------------------------------
__global__ void __launch_bounds__(256) fuse5_k(
        const float* __restrict__ skip, const float* __restrict__ hT,
        const float* __restrict__ fwTp, const float* __restrict__ fb,
        float* __restrict__ xs) {
    int l0 = blockIdx.x * 8, b = blockIdx.y;
    int tid = threadIdx.x;

    __shared__ float ss[8][264];

    for (int idx = tid; idx < 128 * 8; idx += 256) {   // skip part (c<128)
        int c = idx >> 3, ll = idx & 7;
        ss[ll][c] = skip[((size_t)b * F_ + c) * L_ + l0 + ll];
    }
    for (int idx = tid; idx < 8 * 128; idx += 256) {   // h part (c>=128)
        int ll = idx >> 7, c = idx & 127;
        ss[ll][128 + c] = hT[((size_t)b * L_ + l0 + ll) * F_ + c];
    }
    __syncthreads();

    int o2 = tid & 63, rg = tid >> 6;
    float acca[2] = {0.f, 0.f}, accb[2] = {0.f, 0.f};
    const float4* W4 = (const float4*)fwTp;

    for (int cq = 0; cq < 64; ++cq) {
        float4 wa = W4[cq * 128 + o2];
        float4 wb = W4[cq * 128 + o2 + 64];
        #pragma unroll
        for (int rr = 0; rr < 2; ++rr) {
            float4 s = *(const float4*)&ss[rg * 2 + rr][cq * 4];
            acca[rr] += dot4(s, wa);
            accb[rr] += dot4(s, wb);
        }
    }
    float ba = fb[o2], bb = fb[o2 + 64];
    #pragma unroll
    for (int rr = 0; rr < 2; ++rr) {
        int l = l0 + rg * 2 + rr;
        float va = silu_f(acca[rr] + ba);
        float vb = silu_f(accb[rr] + bb);
        size_t rf = ((size_t)b * L_ + l) * F_;
        size_t rb = (RL_ + (size_t)b * L_ + (L_ - 1 - l)) * F_;
        xs[rf + o2] = va;       xs[rf + o2 + 64] = vb;
        xs[rb + o2] = va;       xs[rb + o2 + 64] = vb;
    }
}

// ---------------------------------------------------------------------------
// lndw: rows-tile 8. LN(11 rows w/ halo) -> in_proj x-half (regs) -> depthwise
// conv in REGISTERS -> silu -> XC + xcs; z-half in_proj -> XZz; then
// x_proj(40)+dt_proj(256)+softplus. grid (502, 2), block 256.
// ---------------------------------------------------------------------------
__global__ void __launch_bounds__(256) lndw_k(
        const float* __restrict__ X, const float* __restrict__ nw,
        const float* __restrict__ nb_, const float* __restrict__ ipTp,
        const float* __restrict__ cw, const float* __restrict__ cb,
        const float* __restrict__ xpTp, const float* __restrict__ dtw,
        const float* __restrict__ dtb,
        float* __restrict__ XC, float* __restrict__ XZz,
        float* __restrict__ BCM, float* __restrict__ DELTA, int blk) {
    int rt = blockIdx.x, d = blockIdx.y;
    size_t rbase = (size_t)rt * 8;
    int tid = threadIdx.x, lane = tid & 63, wid = tid >> 6;
    int db = d * NBLK_ + blk;
    size_t dRL = (size_t)d * RL_;

    __shared__ float us[11][132];
    __shared__ float xcs[8][264];
    __shared__ float dts[8][8];

    // LN for staged rows rbase-3 .. rbase+7
    int wi0 = db * F_;
    for (int r = wid; r < 11; r += 4) {
        long grow = (long)rbase - 3 + r;
        float2 v = make_float2(0.f, 0.f);
        if (grow >= 0)
            v = *(const float2*)(X + (dRL + (size_t)grow) * F_ + lane * 2);
        float s1 = v.x + v.y, s2 = v.x * v.x + v.y * v.y;
        for (int off = 32; off; off >>= 1) {
            s1 += __shfl_xor(s1, off);
            s2 += __shfl_xor(s2, off);
        }
        float mu = s1 * (1.f / F_);
        float var = s2 * (1.f / F_) - mu * mu;
        float rstd = rsqrtf(var + 1e-5f);
        int c2 = lane * 2;
        us[r][c2]     = (v.x - mu) * rstd * nw[wi0 + c2]     + nb_[wi0 + c2];
        us[r][c2 + 1] = (v.y - mu) * rstd * nw[wi0 + c2 + 1] + nb_[wi0 + c2 + 1];
    }
    __syncthreads();

    int o = tid;   // channel / x-out index, 0..255
    const float4* W4 = (const float4*)(ipTp + (size_t)db * 65536);

    // x-half in_proj for all 11 staged rows (us reads broadcast)
    float acc[11];
    #pragma unroll
    for (int i = 0; i < 11; ++i) acc[i] = 0.f;
    for (int cq = 0; cq < 32; ++cq) {
        float4 w = W4[cq * 512 + o];
        #pragma unroll
        for (int r = 0; r < 11; ++r)
            acc[r] += dot4(*(const float4*)&us[r][cq * 4], w);
    }

    // depthwise conv + silu, in registers (thread owns channel o)
    {
        int wi = db * DI_ + o;
        float cw0 = cw[(size_t)wi * CV_ + 0], cw1 = cw[(size_t)wi * CV_ + 1];
        float cw2 = cw[(size_t)wi * CV_ + 2], cw3 = cw[(size_t)wi * CV_ + 3];
        float bias = cb[wi];
        #pragma unroll
        for (int r8 = 0; r8 < 8; ++r8) {
            size_t row = rbase + r8;
            int b_r = (row >= L_) ? 1 : 0;
            int l_r = (int)row - b_r * L_;
            int s = r8 + 3;
            float a = bias + acc[s] * cw3;
            if (l_r - 1 >= 0) a += acc[s - 1] * cw2;
            if (l_r - 2 >= 0) a += acc[s - 2] * cw1;
            if (l_r - 3 >= 0) a += acc[s - 3] * cw0;
            float v = silu_f(a);
            xcs[r8][o] = v;
            XC[(dRL + row) * DI_ + o] = v;
        }
    }

    // z-half in_proj for the 8 real rows
    {
        float accz[8];
        #pragma unroll
        for (int i = 0; i < 8; ++i) accz[i] = 0.f;
        for (int cq = 0; cq < 32; ++cq) {
            float4 w = W4[cq * 512 + 256 + o];
            #pragma unroll
            for (int r = 0; r < 8; ++r)
                accz[r] += dot4(*(const float4*)&us[r + 3][cq * 4], w);
        }
        #pragma unroll
        for (int r = 0; r < 8; ++r)
            XZz[(dRL + rbase + r) * DI_ + o] = accz[r];
    }
    __syncthreads();

    // x_proj: e = tid&63 (e<40 active), rg = tid>>6 covers 2 rows each
    {
        int e = tid & 63, rg = tid >> 6;
        float acc2[2] = {0.f, 0.f};
        const float4* Wx = (const float4*)(xpTp + (size_t)db * 16384);
        for (int cq = 0; cq < 64; ++cq) {
            float4 w = Wx[cq * 64 + e];
            #pragma unroll
            for (int rr = 0; rr < 2; ++rr)
                acc2[rr] += dot4(*(const float4*)&xcs[rg * 2 + rr][cq * 4], w);
        }
        if (e < RK_) {
            #pragma unroll
            for (int rr = 0; rr < 2; ++rr) dts[rg * 2 + rr][e] = acc2[rr];
        } else if (e < RK_ + 2 * DS_) {
            #pragma unroll
            for (int rr = 0; rr < 2; ++rr) {
                size_t row = rbase + rg * 2 + rr;
                BCM[(dRL + row) * 32 + (e - RK_)] = acc2[rr];
            }
        }
    }
    __syncthreads();

    // dt_proj + softplus
    {
        int wi = db * DI_ + o;
        float dwv[RK_];
        #pragma unroll
        for (int k = 0; k < RK_; ++k) dwv[k] = dtw[(size_t)wi * RK_ + k];
        float bias = dtb[wi];
        #pragma unroll
        for (int rr = 0; rr < 8; ++rr) {
            size_t row = rbase + rr;
            float a = bias;
            #pragma unroll
            for (int k = 0; k < RK_; ++k) a += dts[rr][k] * dwv[k];
            DELTA[(dRL + row) * DI_ + o] = softplus_f(a);
        }
    }
}

// ---------------------------------------------------------------------------
// scanA: LDS-staged chunk-local scan (CL=32). Emits local y, inclusive cum(dt)
// (overwrites DELTA), chunk-final hpart and dtsum.
// grid (32 chgrp, NC_, 2), block 256 = 16 chl x 16 n
// ---------------------------------------------------------------------------
__global__ void __launch_bounds__(256) scanA_k(
        float* __restrict__ DELTA, const float* __restrict__ XC,
        const float* __restrict__ BCM, const float* __restrict__ A_log,
        float* __restrict__ Y, float* __restrict__ hpart,
        float* __restrict__ dsum, int blk) {
    int d = blockIdx.z, cnk = blockIdx.y;
    int chunit0 = blockIdx.x * 16;
    int chl = threadIdx.x >> 4, n = threadIdx.x & 15;
    int b = chunit0 >> 8, ch0 = chunit0 & 255;
    int ch = ch0 + chl;
    int t0 = cnk * CL_;
    int nt = L_ - t0; if (nt > CL_) nt = CL_;   // may be <= 0 (empty chunk)

    __shared__ float dt_s[CL_][16];
    __shared__ float u_s[CL_][16];
    __shared__ float bc_s[CL_][32];

    size_t rowbase = (size_t)d * RL_ + (size_t)b * L_ + t0;
    for (int idx = threadIdx.x; idx < CL_ * 16; idx += 256) {
        int t = idx >> 4, c = idx & 15;
        float dv = 0.f, uv = 0.f;
        if (t < nt) {
            dv = DELTA[(rowbase + t) * DI_ + ch0 + c];
            uv = XC[(rowbase + t) * DI_ + ch0 + c];
        }
        dt_s[t][c] = dv; u_s[t][c] = uv;
    }
    for (int idx = threadIdx.x; idx < CL_ * 32; idx += 256) {
        int t = idx >> 5, m = idx & 31;
        bc_s[t][m] = (t < nt) ? BCM[(rowbase + t) * 32 + m] : 0.f;
    }
    __syncthreads();

    float A = -__expf(A_log[((size_t)(d * NBLK_ + blk) * DI_ + ch) * DS_ + n]);
    float h = 0.f, cum = 0.f;
    for (int t = 0; t < nt; ++t) {
        float dt = dt_s[t][chl];
        float u  = u_s[t][chl];
        float Bt = bc_s[t][n];
        float Ct = bc_s[t][16 + n];
        cum += dt;
        h = __expf(dt * A) * h + dt * u * Bt;
        float yp = h * Ct;
        yp += __shfl_xor(yp, 1);
        yp += __shfl_xor(yp, 2);
        yp += __shfl_xor(yp, 4);
        yp += __shfl_xor(yp, 8);
        if (n == 0) {
            Y[(rowbase + t) * DI_ + ch] = yp;
            DELTA[(rowbase + t) * DI_ + ch] = cum;   // inclusive prefix of dt
        }
    }
    size_t cb = (size_t)(d * B_ + b) * NC_ + cnk;
    hpart[cb * (DI_ * DS_) + ch * DS_ + n] = h;
    if (n == 0) dsum[cb * DI_ + ch] = cum;
}

// ---------------------------------------------------------------------------
// scanB: cross-chunk scan of summaries, in-place (hpart -> carry-in per chunk).
// grid (32, 2), block 256
// ---------------------------------------------------------------------------
__global__ void scanB_k(float* __restrict__ hpart, const float* __restrict__ dsum,
                        const float* __restrict__ A_log, int blk) {
    int d = blockIdx.y;
    int idx = blockIdx.x * 256 + threadIdx.x;   // (b, ch, n)
    int b = idx >> 12, ch = (idx >> 4) & 255, n = idx & 15;
    float A = -__expf(A_log[((size_t)(d * NBLK_ + blk) * DI_ + ch) * DS_ + n]);
    float h = 0.f;
    for (int c = 0; c < NC_; ++c) {
        size_t cb = (size_t)(d * B_ + b) * NC_ + c;
        size_t hi = cb * (DI_ * DS_) + ch * DS_ + n;
        float hc = hpart[hi];
        hpart[hi] = h;                       // carry-in for chunk c
        h = __expf(A * dsum[cb * DI_ + ch]) * h + hc;
    }
}

// ---------------------------------------------------------------------------
// gateC: correction + gate + out_proj GEMM (+ optional residual), rows-tile 8.
// 8 | 32 and 8 | 2008, so a tile never straddles a chunk or batch boundary:
// single carry table, branch-free. grid (502, 2), block 256.
// ---------------------------------------------------------------------------
__global__ void __launch_bounds__(256) gateC_k(
        const float* __restrict__ Y, const float* __restrict__ XC,
        const float* __restrict__ XZz, const float* __restrict__ DELTA /*=cum*/,
        const float* __restrict__ BCM, const float* __restrict__ A_log,
        const float* __restrict__ hcarry, const float* __restrict__ Dsk,
        const float* __restrict__ opTp, const float* __restrict__ resid_in,
        float* __restrict__ outp, int blk) {
    int rt = blockIdx.x, d = blockIdx.y;
    int tid = threadIdx.x;
    size_t rbase = (size_t)rt * 8;
    int db = d * NBLK_ + blk;
    size_t dRL = (size_t)d * RL_;

    __shared__ float yg[8][264];
    __shared__ float Cs[8][16];

    // stage C values (broadcast-shared across channels)
    if (tid < 128) {
        int r = tid >> 4, n = tid & 15;
        Cs[r][n] = BCM[(dRL + rbase + r) * 32 + 16 + n];
    }
    __syncthreads();

    {
        int c = tid;   // channel
        float Dc = Dsk[(size_t)db * DI_ + c];

        float An[16];
        const float* Ab = A_log + ((size_t)db * DI_ + c) * DS_;
        #pragma unroll
        for (int n = 0; n < 16; ++n) An[n] = -__expf(Ab[n]);

        // single chunk table (tile is entirely inside one (b, chunk))
        int b0 = (rbase >= L_) ? 1 : 0;
        int l0 = (int)rbase - b0 * L_;
        int ck0 = l0 >> 5;
        const float* hp0 = hcarry + ((size_t)(d * B_ + b0) * NC_ + ck0) * (DI_ * DS_) + (size_t)c * DS_;
        float K0[16];
        #pragma unroll
        for (int q = 0; q < 4; ++q) {
            float4 v0 = *(const float4*)(hp0 + q * 4);
            K0[4*q] = v0.x; K0[4*q+1] = v0.y; K0[4*q+2] = v0.z; K0[4*q+3] = v0.w;
        }

        #pragma unroll
        for (int r = 0; r < 8; ++r) {
            size_t ri = dRL + rbase + r;
            float cum = DELTA[ri * DI_ + c];
            float corr = 0.f;
            #pragma unroll
            for (int n = 0; n < 16; ++n)
                corr += Cs[r][n] * K0[n] * __expf(An[n] * cum);
            float yv = Y[ri * DI_ + c] + corr;
            float z  = XZz[ri * DI_ + c];
            yg[r][c] = (yv + XC[ri * DI_ + c] * Dc) * silu_f(z);
        }
    }
    __syncthreads();

    int o2 = tid & 63, rg = tid >> 6;
    float acca[2] = {0.f, 0.f};
    float accb[2] = {0.f, 0.f};
    const float4* W4 = (const float4*)(opTp + (size_t)db * 32768);

    for (int cq = 0; cq < 64; ++cq) {
        float4 wa = W4[cq * 128 + o2];
        float4 wb = W4[cq * 128 + o2 + 64];
        #pragma unroll
        for (int rr = 0; rr < 2; ++rr) {
            float4 u = *(const float4*)&yg[rg * 2 + rr][cq * 4];
            acca[rr] += dot4(u, wa);
            accb[rr] += dot4(u, wb);
        }
    }
    #pragma unroll
    for (int rr = 0; rr < 2; ++rr) {
        size_t ri = dRL + rbase + rg * 2 + rr;
        float va = acca[rr], vb = accb[rr];
        if (resid_in) {
            va += resid_in[ri * F_ + o2];
            vb += resid_in[ri * F_ + o2 + 64];
        }
        outp[ri * F_ + o2]      = va;
        outp[ri * F_ + o2 + 64] = vb;
    }
}

// ---------------------------------------------------------------------------
// combine with LDS transpose for coalesced (b,o,l) writes
// grid (32 l-tiles, B), block 256
// ---------------------------------------------------------------------------
__global__ void combine2_k(const float* __restrict__ cur, const float* __restrict__ res1,
                           float* __restrict__ out) {
    int l0 = blockIdx.x * 64, b = blockIdx.y;
    int tid = threadIdx.x;
    __shared__ float s[64][129];
    for (int idx = tid; idx < 64 * 128; idx += 256) {
        int ll = idx >> 7, o = idx & 127;
        int l = l0 + ll;
        if (l < L_) {
            size_t rf = ((size_t)b * L_ + l) * F_ + o;
            size_t rb = (RL_ + (size_t)b * L_ + (L_ - 1 - l)) * F_ + o;
            s[ll][o] = cur[rf] + res1[rf] + cur[rb] + res1[rb];
        }
    }
    __syncthreads();
    for (int idx = tid; idx < 64 * 128; idx += 256) {
        int o = idx >> 6, ll = idx & 63;
        int l = l0 + ll;
        if (l < L_) out[((size_t)b * F_ + o) * L_ + l] = s[ll][o];
    }
}

// ---------------------------------------------------------------------------
extern "C" void kernel_launch(void* const* d_in, const int* in_sizes, int n_in,
                              void* d_out, int out_size, void* d_ws, size_t ws_size,
                              hipStream_t stream) {
    const float* x        = (const float*)d_in[0];
    const float* skip     = (const float*)d_in[1];
    const float* convT_w  = (const float*)d_in[4];
    const float* convT_b  = (const float*)d_in[5];
    const float* fuse_w   = (const float*)d_in[6];
    const float* fuse_b   = (const float*)d_in[7];
    const float* norm_w   = (const float*)d_in[8];
    const float* norm_b   = (const float*)d_in[9];
    const float* in_proj  = (const float*)d_in[10];
    const float* conv_w   = (const float*)d_in[11];
    const float* conv_b   = (const float*)d_in[12];
    const float* x_proj   = (const float*)d_in[13];
    const float* dt_projw = (const float*)d_in[14];
    const float* dt_projb = (const float*)d_in[15];
    const float* A_log    = (const float*)d_in[16];
    const float* D_skip   = (const float*)d_in[17];
    const float* out_proj = (const float*)d_in[18];
    float* out = (float*)d_out;

    float* w = (float*)d_ws;
    size_t off = 0;
    auto alloc = [&](size_t n) { float* p = w + off; off += n; return p; };
    float* hT      = alloc((size_t)B_ * L_ * F_);       // 514048 (dead after fuse5)
    float* W2p     = alloc(524288);                     // dead after convt5
    float* fwTp    = alloc(32768);                      // dead after fuse5
    float* ipTp    = alloc(262144);
    float* opTp    = alloc(262144);
    float* xpTp    = alloc(65536);
    float* xs      = alloc(2 * RL_ * F_);
    float* cur     = alloc(2 * RL_ * F_);               // written only by final gateC
    float* res1    = alloc(2 * RL_ * F_);
    float* xzz     = alloc(2 * RL_ * DI_);              // z-half only
    float* xc      = alloc(2 * RL_ * DI_);
    float* dl      = alloc(2 * RL_ * DI_);
    float* bcm     = alloc(2 * RL_ * 32);
    float* yb      = alloc(2 * RL_ * DI_);
    // scan chunk summaries alias dead regions:
    //   hp   (2*2*64*4096 = 1048576) -> hT+W2p+fwTp (1071104 floats, dead by scan)
    //   dsum (2*2*64*256  =   65536) -> cur (dead until final gateC of blk1,
    //         which runs after scanB(blk1) has consumed dsum)
    float* hp   = hT;
    float* dsum = cur;
    (void)ws_size; (void)in_sizes; (void)n_in; (void)out_size;

    prep_k<<<(PREP_N + 255) / 256, 256, 0, stream>>>(convT_w, fuse_w, in_proj, out_proj,
                                                     x_proj, W2p, fwTp, ipTp, opTp, xpTp);
    convt5_k<<<dim3(63, 2, 2), 256, 0, stream>>>(x, W2p, convT_b, hT);
    fuse5_k<<<dim3(251, 2), 256, 0, stream>>>(skip, hT, fwTp, fuse_b, xs);

    for (int blk = 0; blk < NBLK_; ++blk) {
        const float* Xin = (blk == 0) ? xs : res1;
        lndw_k<<<dim3(502, 2), 256, 0, stream>>>(Xin, norm_w, norm_b, ipTp,
                                                 conv_w, conv_b, xpTp,
                                                 dt_projw, dt_projb,
                                                 xc, xzz, bcm, dl, blk);
        scanA_k<<<dim3(32, NC_, 2), 256, 0, stream>>>(dl, xc, bcm, A_log, yb, hp, dsum, blk);
        scanB_k<<<dim3(32, 2), 256, 0, stream>>>(hp, dsum, A_log, blk);
        if (blk == 0)
            gateC_k<<<dim3(502, 2), 256, 0, stream>>>(yb, xc, xzz, dl, bcm, A_log, hp,
                                                      D_skip, opTp, xs, res1, 0);
        else
            gateC_k<<<dim3(502, 2), 256, 0, stream>>>(yb, xc, xzz, dl, bcm, A_log, hp,
                                                      D_skip, opTp, nullptr, cur, 1);
    }

    combine2_k<<<dim3(32, 2), 256, 0, stream>>>(cur, res1, out);
}